// Round 8
// baseline (431.682 us; speedup 1.0000x reference)
//
#include <hip/hip_runtime.h>
#include <math.h>

// Problem constants
#define NB 4
#define NS 1024
#define ND 512
#define NE 8
#define NH 1536
#define NT 4096       // NB*NS
#define D6 3072

typedef _Float16 half_t;
typedef _Float16 f16x8 __attribute__((ext_vector_type(8)));
typedef _Float16 f16x4 __attribute__((ext_vector_type(4)));
typedef float    f32x4 __attribute__((ext_vector_type(4)));

#define LDC 136   // epilogue C-tile stride in halfs (272 B, 16B-aligned)
#define LDC2 72   // 64-col epilogue stride in halfs (144 B, 16B-aligned)
#define TM_MAX 71 // max total m-tiles across experts (sum ceil(ne/128) <= 71)

// async global->LDS, 16B per lane, dest = wave-uniform base + lane*16
__device__ __forceinline__ void gld16(const void* g, void* l) {
  __builtin_amdgcn_global_load_lds((const __attribute__((address_space(1))) char*)g,
                                   (__attribute__((address_space(3))) char*)l, 16, 0, 0);
}

// resolve flat tile index -> (expert, m0) from offs[] prefix sums (block-uniform)
__device__ __forceinline__ int resolve_tile(const int* __restrict__ offs, int t,
                                            int& e_out, int& m0_out) {
  int acc = 0, found = 0, ee = 0, mm = 0;
  #pragma unroll
  for (int q = 0; q < NE; ++q) {
    int ne_q = offs[q + 1] - offs[q];
    int te = (ne_q + 127) >> 7;
    if (!found && t < acc + te) { ee = q; mm = (t - acc) << 7; found = 1; }
    acc += te;
  }
  e_out = ee; m0_out = mm;
  return found;
}

// ---------------- K0: mods = silu(c) @ W_ada + b_ada  (B x 6D) ----------------
// split-K: 192 blocks x 64 outputs; each thread 128-d chain; LDS combine.
__global__ __launch_bounds__(256) void k_ada(const float* __restrict__ c,
    const float* __restrict__ Wada, const float* __restrict__ bada,
    float* __restrict__ mods)
{
  __shared__ float sc[ND];
  __shared__ float part[256];
  int tid = threadIdx.x;
  int blk = blockIdx.x;           // 192 blocks: 48 per batch (3072/64)
  int o0 = blk * 64;
  int b = o0 / D6;
  int j0 = o0 - b * D6;
  for (int d = tid; d < ND; d += 256) {
    float v = c[b * ND + d];
    sc[d] = v / (1.f + expf(-v));
  }
  __syncthreads();
  int j = j0 + (tid & 63);
  int kc = tid >> 6;              // 0..3 k-chunk
  float acc = 0.f;
  #pragma unroll 8
  for (int d = kc * 128; d < kc * 128 + 128; ++d)
    acc += sc[d] * Wada[(size_t)d * D6 + j];
  part[tid] = acc;
  __syncthreads();
  if (tid < 64) {
    float r = part[tid] + part[tid + 64] + part[tid + 128] + part[tid + 192]
            + bada[j0 + tid];
    mods[b * D6 + j0 + tid] = r;
  }
}

// ------ LN (+modulate). Outputs: fp32 (opt) and/or h/l fp16 planes (opt). ----
// When Wr != nullptr also emits router logits[row][0..7] = y . Wr + br
__global__ __launch_bounds__(256) void k_lnmod(const float* X, int xstride,
    float* Yf, half_t* Yh, half_t* Yl, int ystride,
    const float* __restrict__ w, const float* __restrict__ b,
    const float* __restrict__ mods, int sh_off, int sc_off,
    const float* __restrict__ Wr, const float* __restrict__ br,
    float* __restrict__ logits)
{
  __shared__ float red[16];
  __shared__ float red2[32];
  int tid = threadIdx.x;
  int row = blockIdx.x;
  int batch = row >> 10;
  const float* xr = X + (size_t)row * xstride;
  float x0 = xr[tid], x1 = xr[tid + 256];
  float s = x0 + x1, q = x0 * x0 + x1 * x1;
  #pragma unroll
  for (int off = 32; off > 0; off >>= 1) { s += __shfl_down(s, off, 64); q += __shfl_down(q, off, 64); }
  if ((tid & 63) == 0) { red[tid >> 6] = s; red[8 + (tid >> 6)] = q; }
  __syncthreads();
  if (tid == 0) {
    float S = red[0] + red[1] + red[2] + red[3];
    float Q = red[8] + red[9] + red[10] + red[11];
    float mean = S * (1.f / (float)ND);
    float var = Q * (1.f / (float)ND) - mean * mean;
    red[0] = mean; red[1] = rsqrtf(var + 1e-5f);
  }
  __syncthreads();
  float mean = red[0], rstd = red[1];
  int d0 = tid, d1 = tid + 256;
  float y0 = (x0 - mean) * rstd * w[d0] + b[d0];
  float y1 = (x1 - mean) * rstd * w[d1] + b[d1];
  if (mods) {
    const float* mb = mods + batch * D6;
    y0 = y0 * (1.f + mb[sc_off + d0]) + mb[sh_off + d0];
    y1 = y1 * (1.f + mb[sc_off + d1]) + mb[sh_off + d1];
  }
  size_t o0 = (size_t)row * ystride + d0, o1 = (size_t)row * ystride + d1;
  if (Yf) { Yf[o0] = y0; Yf[o1] = y1; }
  if (Yh) {
    half_t h0 = (half_t)y0, h1 = (half_t)y1;
    Yh[o0] = h0; Yh[o1] = h1;
    if (Yl) { Yl[o0] = (half_t)(y0 - (float)h0); Yl[o1] = (half_t)(y1 - (float)h1); }
  }
  if (Wr) {
    float p[8];
    float4 wa = *(const float4*)(Wr + d0 * 8);
    float4 wb = *(const float4*)(Wr + d0 * 8 + 4);
    float4 wc = *(const float4*)(Wr + d1 * 8);
    float4 wd = *(const float4*)(Wr + d1 * 8 + 4);
    p[0] = y0 * wa.x + y1 * wc.x; p[1] = y0 * wa.y + y1 * wc.y;
    p[2] = y0 * wa.z + y1 * wc.z; p[3] = y0 * wa.w + y1 * wc.w;
    p[4] = y0 * wb.x + y1 * wd.x; p[5] = y0 * wb.y + y1 * wd.y;
    p[6] = y0 * wb.z + y1 * wd.z; p[7] = y0 * wb.w + y1 * wd.w;
    #pragma unroll
    for (int off = 32; off > 0; off >>= 1)
      #pragma unroll
      for (int e = 0; e < 8; ++e) p[e] += __shfl_down(p[e], off, 64);
    if ((tid & 63) == 0) {
      #pragma unroll
      for (int e = 0; e < 8; ++e) red2[(tid >> 6) * 8 + e] = p[e];
    }
    __syncthreads();
    if (tid < 8)
      logits[(size_t)row * 8 + tid] = red2[tid] + red2[8 + tid] + red2[16 + tid]
                                    + red2[24 + tid] + br[tid];
  }
}

// ------ fused in-place LN of q and k halves of QKV (row stride 1536) ---------
__global__ __launch_bounds__(256) void k_lnqk(float* QKV,
    const float* __restrict__ qw, const float* __restrict__ qb,
    const float* __restrict__ kw, const float* __restrict__ kb)
{
  __shared__ float red[16];
  int tid = threadIdx.x;
  int row = blockIdx.x >> 1;
  int h = blockIdx.x & 1;
  const float* w = h ? kw : qw;
  const float* b = h ? kb : qb;
  float* xr = QKV + (size_t)row * 1536 + h * 512;
  float x0 = xr[tid], x1 = xr[tid + 256];
  float s = x0 + x1, q = x0 * x0 + x1 * x1;
  #pragma unroll
  for (int off = 32; off > 0; off >>= 1) { s += __shfl_down(s, off, 64); q += __shfl_down(q, off, 64); }
  if ((tid & 63) == 0) { red[tid >> 6] = s; red[8 + (tid >> 6)] = q; }
  __syncthreads();
  if (tid == 0) {
    float S = red[0] + red[1] + red[2] + red[3];
    float Q = red[8] + red[9] + red[10] + red[11];
    float mean = S * (1.f / (float)ND);
    float var = Q * (1.f / (float)ND) - mean * mean;
    red[0] = mean; red[1] = rsqrtf(var + 1e-5f);
  }
  __syncthreads();
  float mean = red[0], rstd = red[1];
  xr[tid]       = (x0 - mean) * rstd * w[tid] + b[tid];
  xr[tid + 256] = (x1 - mean) * rstd * w[tid + 256] + b[tid + 256];
}

// ---- transpose+split q,k: QKV[s][z*512..] -> (base + z*4MB)[c][s] h/l -------
__global__ __launch_bounds__(256) void k_tsplit2(const float* __restrict__ QKV,
    half_t* __restrict__ H0, half_t* __restrict__ L0)
{
  __shared__ float tile[32][33];
  int z = blockIdx.z;
  half_t* outH = H0 + (size_t)z * 4194304;
  half_t* outL = L0 + (size_t)z * 4194304;
  int col0 = z * 512;
  int s0 = blockIdx.x * 32, c0 = blockIdx.y * 32;
  int tid = threadIdx.x;
  int r = tid >> 5, c = tid & 31;
  #pragma unroll
  for (int p = 0; p < 4; ++p)
    tile[r + p * 8][c] = QKV[(size_t)(s0 + r + p * 8) * 1536 + col0 + c0 + c];
  __syncthreads();
  #pragma unroll
  for (int p = 0; p < 4; ++p) {
    float v = tile[c][r + p * 8];
    half_t h = (half_t)v;
    size_t o = (size_t)(c0 + r + p * 8) * NT + s0 + c;
    outH[o] = h; outL[o] = (half_t)(v - (float)h);
  }
}

// ---- 4x weight transpose+split into one 2048-row h/l buffer -----------------
__global__ __launch_bounds__(256) void k_wsplit4(const float* __restrict__ Wq,
    const float* __restrict__ Wk, const float* __restrict__ Wv,
    const float* __restrict__ Wo, half_t* __restrict__ outH, half_t* __restrict__ outL)
{
  __shared__ float tile[32][33];
  int z = blockIdx.z;
  const float* W = (z == 0) ? Wq : (z == 1) ? Wk : (z == 2) ? Wv : Wo;
  int rowoff = z * 512;
  int k0 = blockIdx.x * 32, n0 = blockIdx.y * 32;
  int tid = threadIdx.x;
  int r = tid >> 5, c = tid & 31;
  #pragma unroll
  for (int p = 0; p < 4; ++p)
    tile[r + p * 8][c] = W[(size_t)(k0 + r + p * 8) * ND + n0 + c];
  __syncthreads();
  #pragma unroll
  for (int p = 0; p < 4; ++p) {
    float v = tile[c][r + p * 8];
    half_t h = (half_t)v;
    size_t o = (size_t)(rowoff + n0 + r + p * 8) * ND + k0 + c;
    outH[o] = h; outL[o] = (half_t)(v - (float)h);
  }
}

// ---- v split: QKV[s][1024..1535] fp32 -> Vh/Vl [s][512] ---------------------
__global__ __launch_bounds__(256) void k_vsplit(const float* __restrict__ QKV,
    half_t* __restrict__ Vh, half_t* __restrict__ Vl)
{
  int i = blockIdx.x * 256 + threadIdx.x;
  int s = i >> 7, c = (i & 127) * 4;
  float4 v = *(const float4*)(QKV + (size_t)s * 1536 + 1024 + c);
  f16x4 h, l;
  h[0] = (half_t)v.x; l[0] = (half_t)(v.x - (float)h[0]);
  h[1] = (half_t)v.y; l[1] = (half_t)(v.y - (float)h[1]);
  h[2] = (half_t)v.z; l[2] = (half_t)(v.z - (float)h[2]);
  h[3] = (half_t)v.w; l[3] = (half_t)(v.w - (float)h[3]);
  *(f16x4*)(Vh + (size_t)s * ND + c) = h;
  *(f16x4*)(Vl + (size_t)s * ND + c) = l;
}

// ============ split-fp16 MFMA GEMM: C = A_hl(M,K) * B_hl(N,K)^T ==============
// counted-vmcnt pipeline (T4): wait vmcnt(8) at top of iter -> prefetch
// loads stay in flight across barriers and get a full iteration to land.
template<int MODE>
__global__ __launch_bounds__(256, 2) void k_gemm_hl(
    const half_t* __restrict__ Ah, const half_t* __restrict__ Al, long long sAz,
    const half_t* __restrict__ Bh, const half_t* __restrict__ Bl, long long sBz,
    int lda, int ldb, int K,
    float* __restrict__ Cf, half_t* __restrict__ Ch, half_t* __restrict__ Cl,
    long long sCz, int ldc,
    const float* __restrict__ xres, const float* __restrict__ mods)
{
  int z = blockIdx.z;
  int m0 = blockIdx.x * 128, n0 = blockIdx.y * 128;
  // LDS: Ah dbuf [0,16K) | Al [16K,32K) | Bh [32K,48K) | Bl [48K,64K)
  __shared__ __align__(16) char smem[65536];
  half_t* Sh = (half_t*)smem;
  int tid = threadIdx.x;
  int lane = tid & 63, w = tid >> 6;
  int wm = (w >> 1) * 64, wn = (w & 1) * 64;
  int qd = lane >> 4, md = lane & 15;
  int rA0 = tid >> 2;
  int sw = (((tid & 3) ^ ((tid >> 3) & 3)) << 3);   // swizzled k-chunk (halfs)

  const half_t* pAh0 = Ah + z * sAz + (size_t)(m0 + rA0) * lda + sw;
  const half_t* pAh1 = pAh0 + (size_t)64 * lda;
  const half_t* pAl0 = Al + z * sAz + (size_t)(m0 + rA0) * lda + sw;
  const half_t* pAl1 = pAl0 + (size_t)64 * lda;
  const half_t* pBh0 = Bh + z * sBz + (size_t)(n0 + rA0) * ldb + sw;
  const half_t* pBh1 = pBh0 + (size_t)64 * ldb;
  const half_t* pBl0 = Bl + z * sBz + (size_t)(n0 + rA0) * ldb + sw;
  const half_t* pBl1 = pBl0 + (size_t)64 * ldb;

  // wave-uniform LDS dests (lane-linear: dest = base + lane*16)
  char* dAh = smem + w * 1024;
  char* dAl = smem + 16384 + w * 1024;
  char* dBh = smem + 32768 + w * 1024;
  char* dBl = smem + 49152 + w * 1024;

  f32x4 acc[4][4];
  #pragma unroll
  for (int i = 0; i < 4; ++i)
    #pragma unroll
    for (int j = 0; j < 4; ++j)
      #pragma unroll
      for (int p = 0; p < 4; ++p) acc[i][j][p] = 0.f;

  // swizzled ds_read offsets (halfs): phys chunk = qd ^ ((row>>1)&3)
  int swq  = ((qd ^ ((md >> 1) & 3)) << 3);
  int aoff = (wm + md) * 32 + swq;
  int boff = (wn + md) * 32 + swq;

#define GEMM_STAGE(p, kk) do { int kb_ = (kk); int pb_ = (p) * 8192;         \
    gld16(pAh0 + kb_, dAh + pb_); gld16(pAh1 + kb_, dAh + pb_ + 4096);       \
    gld16(pAl0 + kb_, dAl + pb_); gld16(pAl1 + kb_, dAl + pb_ + 4096);       \
    gld16(pBh0 + kb_, dBh + pb_); gld16(pBh1 + kb_, dBh + pb_ + 4096);       \
    gld16(pBl0 + kb_, dBl + pb_); gld16(pBl1 + kb_, dBl + pb_ + 4096); } while (0)

  int iters = K >> 5;
  GEMM_STAGE(0, 0);
  int cur = 0;
  #pragma unroll 1
  for (int it = 0; it < iters; ++it) {
    if (it + 1 < iters) {
      GEMM_STAGE(cur ^ 1, (it + 1) * 32);
      asm volatile("s_waitcnt vmcnt(8)\ns_barrier" ::: "memory");
    } else {
      asm volatile("s_waitcnt vmcnt(0)\ns_barrier" ::: "memory");
    }
    const half_t* Ash = Sh + cur * 4096;
    const half_t* Asl = Sh + 8192  + cur * 4096;
    const half_t* Bsh = Sh + 16384 + cur * 4096;
    const half_t* Bsl = Sh + 24576 + cur * 4096;
    f16x8 ah[4], al[4], bh[4], bl[4];
    #pragma unroll
    for (int i = 0; i < 4; ++i) {
      ah[i] = *(const f16x8*)(Ash + aoff + i * 512);
      al[i] = *(const f16x8*)(Asl + aoff + i * 512);
    }
    #pragma unroll
    for (int j = 0; j < 4; ++j) {
      bh[j] = *(const f16x8*)(Bsh + boff + j * 512);
      bl[j] = *(const f16x8*)(Bsl + boff + j * 512);
    }
    __builtin_amdgcn_s_setprio(1);
    #pragma unroll
    for (int i = 0; i < 4; ++i)
      #pragma unroll
      for (int j = 0; j < 4; ++j) {
        acc[i][j] = __builtin_amdgcn_mfma_f32_16x16x32_f16(ah[i], bh[j], acc[i][j], 0, 0, 0);
        acc[i][j] = __builtin_amdgcn_mfma_f32_16x16x32_f16(ah[i], bl[j], acc[i][j], 0, 0, 0);
        acc[i][j] = __builtin_amdgcn_mfma_f32_16x16x32_f16(al[i], bh[j], acc[i][j], 0, 0, 0);
      }
    __builtin_amdgcn_s_setprio(0);
    asm volatile("s_barrier" ::: "memory");
    cur ^= 1;
  }
#undef GEMM_STAGE

  if (MODE == 1) {
    half_t* Cs = (half_t*)smem;
    __syncthreads();
    #pragma unroll
    for (int i = 0; i < 4; ++i)
      #pragma unroll
      for (int j = 0; j < 4; ++j)
        #pragma unroll
        for (int p = 0; p < 4; ++p)
          Cs[(wm + 16 * i + qd * 4 + p) * LDC + wn + 16 * j + md] = (half_t)acc[i][j][p];
    __syncthreads();
    #pragma unroll
    for (int it2 = 0; it2 < 8; ++it2) {
      int chunk = it2 * 256 + tid;
      int r = chunk >> 4, c8 = (chunk & 15) * 8;
      *(f16x8*)(Ch + z * sCz + (size_t)(m0 + r) * ldc + n0 + c8) = *(const f16x8*)(Cs + r * LDC + c8);
    }
    __syncthreads();
    #pragma unroll
    for (int i = 0; i < 4; ++i)
      #pragma unroll
      for (int j = 0; j < 4; ++j)
        #pragma unroll
        for (int p = 0; p < 4; ++p) {
          float v = acc[i][j][p];
          half_t h = (half_t)v;
          Cs[(wm + 16 * i + qd * 4 + p) * LDC + wn + 16 * j + md] = (half_t)(v - (float)h);
        }
    __syncthreads();
    #pragma unroll
    for (int it2 = 0; it2 < 8; ++it2) {
      int chunk = it2 * 256 + tid;
      int r = chunk >> 4, c8 = (chunk & 15) * 8;
      *(f16x8*)(Cl + z * sCz + (size_t)(m0 + r) * ldc + n0 + c8) = *(const f16x8*)(Cs + r * LDC + c8);
    }
  } else {
    #pragma unroll
    for (int i = 0; i < 4; ++i)
      #pragma unroll
      for (int p = 0; p < 4; ++p) {
        int r = m0 + wm + 16 * i + qd * 4 + p;
        float* cp = Cf + z * sCz + (size_t)r * ldc + n0 + wn + md;
        if (MODE == 2) {
          int batch = r >> 10;
          const float* mb = mods + batch * D6 + 2 * ND;
          const float* xp = xres + (size_t)r * ldc + n0 + wn + md;
          #pragma unroll
          for (int j = 0; j < 4; ++j) {
            int col = wn + md + 16 * j;
            cp[16 * j] = xp[16 * j] + mb[n0 + col] * acc[i][j][p];
          }
        } else {
          #pragma unroll
          for (int j = 0; j < 4; ++j) cp[16 * j] = acc[i][j][p];
        }
      }
  }
}

// ---- softmax over rows of 512, input = 4 split-K partials; P as h/l fp16 ----
__global__ __launch_bounds__(256) void k_softmax512_sum4(const float* __restrict__ SC4,
    half_t* __restrict__ Ph, half_t* __restrict__ Pl)
{
  __shared__ float red[16];
  int tid = threadIdx.x;
  int row = blockIdx.x;             // 2048 = b*512 + d
  int b = row >> 9, d = row & 511;
  const float* r0 = SC4 + ((size_t)(b * 4 + 0) << 18) + (size_t)d * ND;
  const float* r1 = SC4 + ((size_t)(b * 4 + 1) << 18) + (size_t)d * ND;
  const float* r2 = SC4 + ((size_t)(b * 4 + 2) << 18) + (size_t)d * ND;
  const float* r3 = SC4 + ((size_t)(b * 4 + 3) << 18) + (size_t)d * ND;
  float x0 = r0[tid] + r1[tid] + r2[tid] + r3[tid];
  float x1 = r0[tid + 256] + r1[tid + 256] + r2[tid + 256] + r3[tid + 256];
  float m = fmaxf(x0, x1);
  #pragma unroll
  for (int off = 32; off > 0; off >>= 1) m = fmaxf(m, __shfl_down(m, off, 64));
  if ((tid & 63) == 0) red[tid >> 6] = m;
  __syncthreads();
  if (tid == 0) red[0] = fmaxf(fmaxf(red[0], red[1]), fmaxf(red[2], red[3]));
  __syncthreads();
  m = red[0];
  float e0 = expf(x0 - m), e1 = expf(x1 - m);
  float s = e0 + e1;
  #pragma unroll
  for (int off = 32; off > 0; off >>= 1) s += __shfl_down(s, off, 64);
  if ((tid & 63) == 0) red[8 + (tid >> 6)] = s;
  __syncthreads();
  if (tid == 0) red[8] = red[8] + red[9] + red[10] + red[11];
  __syncthreads();
  float inv = 1.f / red[8];
  float p0 = e0 * inv, p1 = e1 * inv;
  size_t base = (size_t)row * ND;
  half_t h0 = (half_t)p0, h1 = (half_t)p1;
  Ph[base + tid] = h0;       Pl[base + tid] = (half_t)(p0 - (float)h0);
  Ph[base + tid + 256] = h1; Pl[base + tid + 256] = (half_t)(p1 - (float)h1);
}

// -------- nrm[b,e] = sqrt(sum_s logits^2) ------------------------------------
__global__ __launch_bounds__(256) void k_colnorm(const float* __restrict__ logits,
    float* __restrict__ nrm)
{
  __shared__ float red[8];
  int tid = threadIdx.x;
  int b = blockIdx.x >> 3, e = blockIdx.x & 7;
  float acc = 0.f;
  for (int s = tid; s < NS; s += 256) {
    float l = logits[((size_t)(b << 10) + s) * NE + e];
    acc += l * l;
  }
  #pragma unroll
  for (int off = 32; off > 0; off >>= 1) acc += __shfl_down(acc, off, 64);
  if ((tid & 63) == 0) red[tid >> 6] = acc;
  __syncthreads();
  if (tid == 0) nrm[b * NE + e] = sqrtf(red[0] + red[1] + red[2] + red[3]);
}

// ======== fused routing: top2 + histogram + scan + compaction ================
// single block, 1024 threads, atomic-free (ballot-based deterministic ranks).
__global__ __launch_bounds__(1024) void k_route(const float* __restrict__ logits,
    const float* __restrict__ nrm, float* __restrict__ probs,
    float* __restrict__ wsel, int* __restrict__ offs_g,
    int* __restrict__ list, int* __restrict__ inv)
{
  __shared__ unsigned char sisel[8192];
  __shared__ int cw[8][16][8];      // per (chunk, wave, expert): count -> excl base
  __shared__ int soffs[9];
  __shared__ float snrm[32];
  int tid = threadIdx.x;
  int lane = tid & 63, wv = tid >> 6;   // 16 waves
  if (tid < 32) snrm[tid] = fmaxf(nrm[tid], 1e-12f);
  __syncthreads();
  // phase 1: per-token normalized softmax + top2
  #pragma unroll 1
  for (int c = 0; c < 4; ++c) {
    int t = c * 1024 + tid;
    int b = t >> 10;
    float p[8];
    float4 l0 = *(const float4*)(logits + (size_t)t * 8);
    float4 l1 = *(const float4*)(logits + (size_t)t * 8 + 4);
    p[0] = l0.x / snrm[b * 8 + 0]; p[1] = l0.y / snrm[b * 8 + 1];
    p[2] = l0.z / snrm[b * 8 + 2]; p[3] = l0.w / snrm[b * 8 + 3];
    p[4] = l1.x / snrm[b * 8 + 4]; p[5] = l1.y / snrm[b * 8 + 5];
    p[6] = l1.z / snrm[b * 8 + 6]; p[7] = l1.w / snrm[b * 8 + 7];
    float mx = p[0];
    #pragma unroll
    for (int e = 1; e < 8; ++e) mx = fmaxf(mx, p[e]);
    float s = 0.f;
    #pragma unroll
    for (int e = 0; e < 8; ++e) { p[e] = expf(p[e] - mx); s += p[e]; }
    float invs = 1.f / s;
    #pragma unroll
    for (int e = 0; e < 8; ++e) { p[e] *= invs; probs[(size_t)t * 8 + e] = p[e]; }
    int i1 = 0;
    #pragma unroll
    for (int e = 1; e < 8; ++e) if (p[e] > p[i1]) i1 = e;
    int i2 = (i1 == 0) ? 1 : 0;
    #pragma unroll
    for (int e = 0; e < 8; ++e) if (e != i1 && p[e] > p[i2]) i2 = e;
    wsel[t * 2] = p[i1]; wsel[t * 2 + 1] = p[i2];
    sisel[t * 2] = (unsigned char)i1; sisel[t * 2 + 1] = (unsigned char)i2;
  }
  __syncthreads();
  // pass A: per (chunk, wave, expert) counts via ballots
  #pragma unroll 1
  for (int c = 0; c < 8; ++c) {
    int em = sisel[c * 1024 + tid];
    #pragma unroll
    for (int e = 0; e < 8; ++e) {
      unsigned long long mask = __ballot(em == e);
      if (lane == 0) cw[c][wv][e] = (int)__popcll(mask);
    }
  }
  __syncthreads();
  // exclusive scan per expert over (chunk, wave); totals -> soffs
  if (tid < 8) {
    int e = tid, run = 0;
    for (int c = 0; c < 8; ++c)
      for (int w2 = 0; w2 < 16; ++w2) { int v = cw[c][w2][e]; cw[c][w2][e] = run; run += v; }
    soffs[e] = run;
  }
  __syncthreads();
  if (tid == 0) {
    int a = 0;
    #pragma unroll
    for (int e = 0; e < 8; ++e) { int v = soffs[e]; soffs[e] = a; a += v; }
    soffs[8] = a;
  }
  __syncthreads();
  if (tid < 9) offs_g[tid] = soffs[tid];
  // pass B: deterministic ranks + emit compacted lists
  #pragma unroll 1
  for (int c = 0; c < 8; ++c) {
    int idx = c * 1024 + tid;
    int em = sisel[idx];
    int rk = 0;
    #pragma unroll
    for (int e = 0; e < 8; ++e) {
      unsigned long long mask = __ballot(em == e);
      if (em == e) rk = (int)__popcll(mask & ((1ull << lane) - 1ull));
    }
    int slot = soffs[em] + cw[c][wv][em] + rk;
    list[slot] = idx >> 1;
    inv[idx] = slot;
  }
}

// -------- aux = sum_{s,e} (1/E - mean_b probs)^2 -----------------------------
__global__ __launch_bounds__(256) void k_aux(const float* __restrict__ probs,
    float* __restrict__ outAux)
{
  __shared__ float red[8];
  int tid = threadIdx.x;
  float acc = 0.f;
  for (int s = tid; s < NS; s += 256) {
    #pragma unroll
    for (int e = 0; e < NE; ++e) {
      float a = probs[(size_t)s * NE + e] + probs[(size_t)(NS + s) * NE + e]
              + probs[(size_t)(2 * NS + s) * NE + e] + probs[(size_t)(3 * NS + s) * NE + e];
      float d = 0.125f - a * 0.25f;
      acc += d * d;
    }
  }
  #pragma unroll
  for (int off = 32; off > 0; off >>= 1) acc += __shfl_down(acc, off, 64);
  if ((tid & 63) == 0) red[tid >> 6] = acc;
  __syncthreads();
  if (tid == 0) *outAux = red[0] + red[1] + red[2] + red[3];
}

// ---- transpose+cast W1 and W3 in one launch: z = sel*8 + e ------------------
__global__ __launch_bounds__(256) void k_tcast13(const float* __restrict__ W1,
    const float* __restrict__ W3, half_t* __restrict__ W1t, half_t* __restrict__ W3t)
{
  __shared__ float tile[32][33];
  int z = blockIdx.z;
  int sel = z >> 3, e = z & 7;
  const float* We = (sel ? W3 : W1) + (size_t)e * ND * NH;
  half_t* Wte = (sel ? W3t : W1t) + (size_t)e * ND * NH;
  int k0 = blockIdx.x * 32, n0 = blockIdx.y * 32;
  int tid = threadIdx.x;
  int r = tid >> 5, c = tid & 31;
  #pragma unroll
  for (int p = 0; p < 4; ++p)
    tile[r + p * 8][c] = We[(size_t)(k0 + r + p * 8) * NH + n0 + c];
  __syncthreads();
  #pragma unroll
  for (int p = 0; p < 4; ++p)
    Wte[(size_t)(n0 + r + p * 8) * ND + k0 + c] = (half_t)tile[c][r + p * 8];
}

// ---- transpose+cast W2[e][NH][ND] -> W2t[e][ND][NH] -------------------------
__global__ __launch_bounds__(256) void k_tcastW2(const float* __restrict__ W,
    half_t* __restrict__ Wt)
{
  __shared__ float tile[32][33];
  const float* We = W + (size_t)blockIdx.z * NH * ND;
  half_t* Wte = Wt + (size_t)blockIdx.z * NH * ND;
  int k0 = blockIdx.x * 32, n0 = blockIdx.y * 32;
  int tid = threadIdx.x;
  int r = tid >> 5, c = tid & 31;
  #pragma unroll
  for (int p = 0; p < 4; ++p)
    tile[r + p * 8][c] = We[(size_t)(k0 + r + p * 8) * ND + n0 + c];
  __syncthreads();
  #pragma unroll
  for (int p = 0; p < 4; ++p)
    Wte[(size_t)(n0 + r + p * 8) * NH + k0 + c] = (half_t)tile[c][r + p * 8];
}

// ============ fused FFN: gate = f16( sin(xm@W1^T) * (xm@W3^T) ) ==============
// R8: tile 128x64, grid 1704 (2x parallelism); A operand direct-to-VGPR
// (double-buffered registers, no LDS, no swizzle needed); B1/B3 via gload_lds
// dbuf; counted vmcnt(6) = 2 gld16 + 4 A-loads per phase. LDS 18.9KB.
__global__ __launch_bounds__(256, 3) void k_ffn_fused(const half_t* __restrict__ xmh,
    const half_t* __restrict__ W1t, const half_t* __restrict__ W3t,
    const int* __restrict__ list, const int* __restrict__ offs,
    half_t* __restrict__ gate)
{
  int bx = blockIdx.x;            // 1704 = 71 tiles * 24 n
  int n0 = (bx % 24) * 64;
  int t  = bx / 24;
  int e, m0;
  if (!resolve_tile(offs, t, e, m0)) return;
  int base = offs[e], ne = offs[e + 1] - base;

  // LDS: B1 dbuf [0,8192) | B3 dbuf [8192,16384) | Cs epilogue [0,18432) | rowt
  __shared__ __align__(16) char smem[18944];
  half_t* Sh = (half_t*)smem;
  int* rowt = (int*)(smem + 18432);
  int tid = threadIdx.x;
  if (tid < 128) {
    int rr = m0 + tid;
    rowt[tid] = (rr < ne) ? list[base + rr] : 0;
  }
  __syncthreads();

  int lane = tid & 63, w = tid >> 6;
  int wm = (w >> 1) * 64, wn = (w & 1) * 32;
  int qd = lane >> 4, md = lane & 15;
  int rB = tid >> 2;                               // 0..63 (B rows)
  int swB = (((tid & 3) ^ ((rB >> 1) & 3)) << 3);  // swizzled k-chunk (halfs)

  const half_t* gB1 = W1t + ((size_t)e * NH + n0 + rB) * ND + swB;
  const half_t* gB3 = W3t + ((size_t)e * NH + n0 + rB) * ND + swB;
  char* dB1 = smem + w * 1024;
  char* dB3 = smem + 8192 + w * 1024;

  // A: direct-to-register gather (rows wm+16i+md), no LDS, no swizzle
  const half_t* pa0 = xmh + (size_t)rowt[wm + md] * ND + qd * 8;
  const half_t* pa1 = xmh + (size_t)rowt[wm + 16 + md] * ND + qd * 8;
  const half_t* pa2 = xmh + (size_t)rowt[wm + 32 + md] * ND + qd * 8;
  const half_t* pa3 = xmh + (size_t)rowt[wm + 48 + md] * ND + qd * 8;

  f32x4 acc1[4][2], acc3[4][2];
  #pragma unroll
  for (int i = 0; i < 4; ++i)
    #pragma unroll
    for (int j = 0; j < 2; ++j)
      #pragma unroll
      for (int p = 0; p < 4; ++p) { acc1[i][j][p] = 0.f; acc3[i][j][p] = 0.f; }

  // swizzled ds_read offsets (halfs): phys chunk = qd ^ ((md>>1)&3)
  int swq  = ((qd ^ ((md >> 1) & 3)) << 3);
  int boff = (wn + md) * 32 + swq;

#define FFN_STAGE_B(p, kk) do { int kb_ = (kk);                              \
    gld16(gB1 + kb_, dB1 + (p) * 4096); gld16(gB3 + kb_, dB3 + (p) * 4096); } while (0)
#define FFN_LOAD_A(ar, kk) do { int ka_ = (kk);                              \
    ar[0] = *(const f16x8*)(pa0 + ka_); ar[1] = *(const f16x8*)(pa1 + ka_);  \
    ar[2] = *(const f16x8*)(pa2 + ka_); ar[3] = *(const f16x8*)(pa3 + ka_); } while (0)
#define FFN_COMPUTE(cur, ar) do {                                            \
    const half_t* B1s = Sh + (cur) * 2048;                                   \
    const half_t* B3s = Sh + 4096 + (cur) * 2048;                            \
    f16x8 b1[2], b3[2];                                                      \
    _Pragma("unroll")                                                        \
    for (int j = 0; j < 2; ++j) {                                            \
      b1[j] = *(const f16x8*)(B1s + boff + j * 512);                         \
      b3[j] = *(const f16x8*)(B3s + boff + j * 512);                         \
    }                                                                        \
    __builtin_amdgcn_s_setprio(1);                                           \
    _Pragma("unroll")                                                        \
    for (int j = 0; j < 2; ++j)                                              \
      _Pragma("unroll")                                                      \
      for (int i = 0; i < 4; ++i) {                                          \
        acc1[i][j] = __builtin_amdgcn_mfma_f32_16x16x32_f16(ar[i], b1[j], acc1[i][j], 0, 0, 0); \
        acc3[i][j] = __builtin_amdgcn_mfma_f32_16x16x32_f16(ar[i], b3[j], acc3[i][j], 0, 0, 0); \
      }                                                                      \
    __builtin_amdgcn_s_setprio(0);                                           \
  } while (0)

  f16x8 a0_[4], a1_[4];
  FFN_STAGE_B(0, 0);
  FFN_LOAD_A(a0_, 0);
  #pragma unroll 1
  for (int it = 0; it < 16; it += 2) {
    // phase A: compute buf0 with a0_, prefetch it+1 into buf1/a1_
    if (it + 1 < 16) {
      FFN_STAGE_B(1, (it + 1) * 32);
      FFN_LOAD_A(a1_, (it + 1) * 32);
      asm volatile("s_waitcnt vmcnt(6)\ns_barrier" ::: "memory");
    } else {
      asm volatile("s_waitcnt vmcnt(0)\ns_barrier" ::: "memory");
    }
    FFN_COMPUTE(0, a0_);
    asm volatile("s_barrier" ::: "memory");
    // phase B: compute buf1 with a1_, prefetch it+2 into buf0/a0_
    if (it + 2 < 16) {
      FFN_STAGE_B(0, (it + 2) * 32);
      FFN_LOAD_A(a0_, (it + 2) * 32);
      asm volatile("s_waitcnt vmcnt(6)\ns_barrier" ::: "memory");
    } else {
      asm volatile("s_waitcnt vmcnt(0)\ns_barrier" ::: "memory");
    }
    FFN_COMPUTE(1, a1_);
    asm volatile("s_barrier" ::: "memory");
  }
#undef FFN_STAGE_B
#undef FFN_LOAD_A
#undef FFN_COMPUTE

  // epilogue: gate = f16(sin(h1) * h3) via LDS re-tile, vectorized store
  half_t* Cs = (half_t*)smem;
  #pragma unroll
  for (int i = 0; i < 4; ++i)
    #pragma unroll
    for (int j = 0; j < 2; ++j)
      #pragma unroll
      for (int p = 0; p < 4; ++p) {
        int rr = wm + 16 * i + qd * 4 + p;
        int cc = wn + 16 * j + md;
        Cs[rr * LDC2 + cc] = (half_t)(__sinf(acc1[i][j][p]) * acc3[i][j][p]);
      }
  __syncthreads();
  #pragma unroll
  for (int it = 0; it < 4; ++it) {
    int chunk = it * 256 + tid;
    int rr = chunk >> 3, c8 = (chunk & 7) * 8;
    if (m0 + rr < ne) {
      *(f16x8*)(gate + (size_t)(base + m0 + rr) * NH + n0 + c8) = *(const f16x8*)(Cs + rr * LDC2 + c8);
    }
  }
}

// ======= MoE stage 2 (atomic-free): P[slot][d] = gate[slot,:] @ W2_e^T =======
// R8: tile 128x64, grid 568 (2x parallelism, was 284 = 1.1 blocks/CU);
// counted vmcnt(3) (2 A + 1 B gld16 per phase). LDS 24KB -> more resident.
__global__ __launch_bounds__(256, 4) void k_moe2_mfma(const half_t* __restrict__ gate,
    const half_t* __restrict__ W2t, const int* __restrict__ offs,
    float* __restrict__ P)
{
  int bx = blockIdx.x;            // 568 = 71 tiles * 8 n
  int n0 = (bx & 7) * 64;
  int t = bx >> 3;
  int e, m0;
  if (!resolve_tile(offs, t, e, m0)) return;
  int base = offs[e], ne = offs[e + 1] - base;

  // LDS: A dbuf [0,16384) | B dbuf [16384,24576)
  __shared__ __align__(16) char smem[24576];
  half_t* Sh = (half_t*)smem;
  int tid = threadIdx.x;
  int lane = tid & 63, w = tid >> 6;
  int wm = (w >> 1) * 64, wn = (w & 1) * 32;
  int qd = lane >> 4, md = lane & 15;
  int rA0 = tid >> 2;
  int sw = (((tid & 3) ^ ((tid >> 3) & 3)) << 3);

  int ar0 = m0 + rA0;      if (ar0 >= ne) ar0 = ne - 1;
  int ar1 = m0 + rA0 + 64; if (ar1 >= ne) ar1 = ne - 1;
  const half_t* gA0 = gate + (size_t)(base + ar0) * NH + sw;
  const half_t* gA1 = gate + (size_t)(base + ar1) * NH + sw;
  const half_t* gB0 = W2t + ((size_t)e * ND + n0 + rA0) * NH + sw;  // rA0 0..63

  char* dA = smem + w * 1024;
  char* dB = smem + 16384 + w * 1024;

  f32x4 acc[4][2];
  #pragma unroll
  for (int i = 0; i < 4; ++i)
    #pragma unroll
    for (int j = 0; j < 2; ++j)
      #pragma unroll
      for (int p = 0; p < 4; ++p) acc[i][j][p] = 0.f;

  int swq  = ((qd ^ ((md >> 1) & 3)) << 3);
  int aoff = (wm + md) * 32 + swq;
  int boff = (wn + md) * 32 + swq;

#define MOE2_STAGE(p, kk) do { int kb_ = (kk);                               \
    gld16(gA0 + kb_, dA + (p) * 8192); gld16(gA1 + kb_, dA + (p) * 8192 + 4096); \
    gld16(gB0 + kb_, dB + (p) * 4096); } while (0)

  MOE2_STAGE(0, 0);
  int cur = 0;
  #pragma unroll 1
  for (int it = 0; it < 48; ++it) {
    if (it + 1 < 48) {
      MOE2_STAGE(cur ^ 1, (it + 1) * 32);
      asm volatile("s_waitcnt vmcnt(3)\ns_barrier" ::: "memory");
    } else {
      asm volatile("s_waitcnt vmcnt(0)\ns_barrier" ::: "memory");
    }
    const half_t* As = Sh + cur * 4096;
    const half_t* Bs = Sh + 8192 + cur * 2048;
    f16x8 a[4], b[2];
    #pragma unroll
    for (int i = 0; i < 4; ++i) a[i] = *(const f16x8*)(As + aoff + i * 512);
    #pragma unroll
    for (int j = 0; j < 2; ++j) b[j] = *(const f16x8*)(Bs + boff + j * 512);
    __builtin_amdgcn_s_setprio(1);
    #pragma unroll
    for (int j = 0; j < 2; ++j)
      #pragma unroll
      for (int i = 0; i < 4; ++i)
        acc[i][j] = __builtin_amdgcn_mfma_f32_16x16x32_f16(a[i], b[j], acc[i][j], 0, 0, 0);
    __builtin_amdgcn_s_setprio(0);
    asm volatile("s_barrier" ::: "memory");
    cur ^= 1;
  }
#undef MOE2_STAGE

  #pragma unroll
  for (int i = 0; i < 4; ++i)
    #pragma unroll
    for (int p = 0; p < 4; ++p) {
      int gr = m0 + wm + 16 * i + qd * 4 + p;
      if (gr < ne) {
        float* pp = P + (size_t)(base + gr) * ND + n0 + wn + md;
        #pragma unroll
        for (int j = 0; j < 2; ++j)
          pp[16 * j] = acc[i][j][p];
      }
    }
}

// ---- reduce: out[t][:] = w1 * P[slot1][:] + w2 * P[slot2][:] ----------------
__global__ __launch_bounds__(256) void k_moe_reduce(const float* __restrict__ P,
    const int* __restrict__ inv, const float* __restrict__ wsel,
    float* __restrict__ out)
{
  int i = blockIdx.x * 256 + threadIdx.x;   // 4096 * 128 float4s
  int t = i >> 7, d4 = i & 127;
  int s1 = inv[t * 2], s2 = inv[t * 2 + 1];
  float w1 = wsel[t * 2], w2 = wsel[t * 2 + 1];
  const float4* P4 = (const float4*)P;
  float4 a = P4[(size_t)s1 * 128 + d4];
  float4 b = P4[(size_t)s2 * 128 + d4];
  float4 o;
  o.x = w1 * a.x + w2 * b.x;
  o.y = w1 * a.y + w2 * b.y;
  o.z = w1 * a.z + w2 * b.z;
  o.w = w1 * a.w + w2 * b.w;
  ((float4*)out)[i] = o;
}

// ---------------- workspace layout (byte offsets, peak ~63.4 MB) -------------
static const size_t BO_MODS  = 0;          // 49152 B fp32 mods
static const size_t BO_HH    = 65536;      // Hh 4 MB   } region B (8 MB)
static const size_t BO_HL2   = 4259840;    // Hl 4 MB   }
static const size_t BO_PH    = 4259840;    // Ph 2 MB (after Hl dead)
static const size_t BO_PL    = 6357056;    // Pl 2 MB
static const size_t BO_WALLH = 8454144;    // 2 MB: q|k|v|o transposed h (2048 rows)
static const size_t BO_WALLL = 10551296;   // 2 MB: l planes
static const size_t BO_QKV   = 12648448;   // fp32 [4096][1536] 25.17 MB (region D)
static const size_t BO_A0H   = 12648448;   // attn0 h 4 MB (after QKV dead)
static const size_t BO_A0L   = 16842752;   // attn0 l 4 MB
static const size_t BO_SC4   = 21037056;   // 16 MB fp32: 16 x [512][512] split-K partials
static const size_t BO_X2    = 21037056;   // fp32 8 MB (after SC4 dead)
static const size_t BO_XM    = 29425664;   // fp32 8 MB (after SC4 dead)
static const size_t BO_QTH   = 37814272;   // qT h 4 MB } region E (16 MB)
static const size_t BO_QTL   = 42008576;
static const size_t BO_KTH   = 46202880;
static const size_t BO_KTL   = 50397184;
static const size_t BO_VH    = 54591488;   // region F (8 MB)
static const size_t BO_VL    = 58785792;
// MoE phase (aliases):
static const size_t BO_W1T   = 37814272;   // 12.58 MB (qT/kT dead after scores)
static const size_t BO_XMH   = 50397184;   // 4 MB (kT_l dead)
static const size_t BO_W3T   = 65536;      // 12.58 MB = region B+C (dead after apply/Wo)
static const size_t BO_GATE  = 12648448;   // 25.17 MB = region D
static const size_t BO_W2T   = 65536;      // 12.58 MB (overwrites W3T after ffn)
static const size_t BO_P     = 37814272;   // 16.78 MB fp32 (W1T+XMH dead after ffn)
// small buffers:
static const size_t BO_LOGI  = 62980096;
static const size_t BO_NRM   = 63111168;
static const size_t BO_PROB  = 63111296;
static const size_t BO_WSEL  = 63242368;
static const size_t BO_INTS  = 63307904;   // ints: isel 8192|cnt 8|cnt2 8|offs 16|list 8192|inv 8192

extern "C" void kernel_launch(void* const* d_in, const int* in_sizes, int n_in,
                              void* d_out, int out_size, void* d_ws, size_t ws_size,
                              hipStream_t stream)
{
  const float* x    = (const float*)d_in[0];
  const float* c    = (const float*)d_in[1];
  const float* Wada = (const float*)d_in[2];
  const float* bada = (const float*)d_in[3];
  const float* Wq   = (const float*)d_in[4];
  const float* Wk   = (const float*)d_in[5];
  const float* Wv   = (const float*)d_in[6];
  const float* Wo   = (const float*)d_in[7];
  const float* qn_w = (const float*)d_in[8];
  const float* qn_b = (const float*)d_in[9];
  const float* kn_w = (const float*)d_in[10];
  const float* kn_b = (const float*)d_in[11];
  const float* an_w = (const float*)d_in[12];
  const float* an_b = (const float*)d_in[13];
  const float* fn_w = (const float*)d_in[14];
  const float* fn_b = (const float*)d_in[15];
  const float* Wr   = (const float*)d_in[16];
  const float* br   = (const float*)d_in[17];
  const float* W1   = (const float*)d_in[18];
  const float* W2   = (const float*)d_in[19];
  const float* W3   = (const float*)d_in[20];
  float* out = (float*)d_out;
  char*  ws8 = (char*)d_ws;
  float* MODS = (float*)(ws8 + BO_MODS);
  half_t* Hh = (half_t*)(ws8 + BO_HH),   *Hl = (half_t*)(ws8 + BO_HL2);
  half_t* Ph = (half_t*)(ws8 + BO_PH),   *Pl = (half_t*)(ws8 + BO_PL);
  half_t* WALLH = (half_t*)(ws8 + BO_WALLH), *WALLL = (half_t*)(ws8 + BO_WALLL);
  half_t* WoTh = WALLH + (size_t)1536 * ND,  *WoTl = WALLL + (size_t)1536 * ND;
  float* QKV = (float*)(ws8 + BO_QKV);
  half_t* A0h = (half_t*)(ws8 + BO_A0H), *A0l = (half_t*)(ws8 + BO_A0L);
  float* SC4 = (float*)(ws8 + BO_SC4);
  float* X2  = (float*)(ws8 + BO_X2);
  float* XM  = (float*)(ws8 + BO_XM);
  half_t* qTh = (half_t*)(ws8 + BO_QTH), *qTl = (half_t*)(ws8 + BO_QTL);
  half_t* kTh = (half_t*)(ws8 + BO_KTH), *kTl = (half_t*)(ws8 + BO_KTL);
  half_t* Vh  = (half_t*)(ws8 + BO_VH),  *Vl  = (half_t*)(ws8 + BO_VL);
  half_t* W1T = (half_t*)(ws8 + BO_W1T);
  half_t* W3T = (half_t*)(ws8 + BO_W3T);
  half_t* W2T = (half_t*)(ws8 + BO_W2T);
  half_t* XMH = (half_t*)(ws8 + BO_XMH);
  half_t* GATEH = (half_t*)(ws8 + BO_GATE);
  float* PBUF = (float*)(ws8 + BO_P);
  float* LOGI = (float*)(ws8 + BO_LOGI);
  float* NRM  = (float*)(ws8 + BO_NRM);
  float* PROB = (float*)(ws8 + BO_PROB);
  float* WSEL = (float*)(ws8 + BO_WSEL);
  int* ib   = (int*)(ws8 + BO_INTS);
  int* offs = ib + 8208;
  int* list = ib + 8224;
  int* inv  = ib + 16416;

  k_ada<<<192, 256, 0, stream>>>(c, Wada, bada, MODS);
  k_wsplit4<<<dim3(16, 16, 4), 256, 0, stream>>>(Wq, Wk, Wv, Wo, WALLH, WALLL);
  // h = modulate(LN(x)) -> h/l planes
  k_lnmod<<<NT, 256, 0, stream>>>(x, ND, nullptr, Hh, Hl, ND, an_w, an_b, MODS, 0, 512,
                                  nullptr, nullptr, nullptr);
  // fused QKV: [4096][1536]
  k_gemm_hl<0><<<dim3(32, 12, 1), 256, 0, stream>>>(Hh, Hl, 0, WALLH, WALLL, 0,
      ND, ND, ND, QKV, nullptr, nullptr, 0, 1536, nullptr, nullptr);
  // fused row-LN of q and k halves (in place)
  k_lnqk<<<2 * NT, 256, 0, stream>>>(QKV, qn_w, qn_b, kn_w, kn_b);
  // transpose+split q,k to [d][s]; split v
  k_tsplit2<<<dim3(128, 16, 2), 256, 0, stream>>>(QKV, qTh, qTl);
  k_vsplit<<<2048, 256, 0, stream>>>(QKV, Vh, Vl);
  // scores: split-K x4 (z = b*4+kh; A/B offset z*256 = b*1024+kh*256)
  k_gemm_hl<0><<<dim3(4, 4, 16), 256, 0, stream>>>(qTh, qTl, 256, kTh, kTl, 256,
      NT, NT, 256, SC4, nullptr, nullptr, 262144, ND, nullptr, nullptr);
  k_softmax512_sum4<<<2048, 256, 0, stream>>>(SC4, Ph, Pl);
  // apply: attn0[s][d] = sum_e v[s,e] P[d,e]
  k_gemm_hl<1><<<dim3(8, 4, 4), 256, 0, stream>>>(Vh, Vl, 524288, Ph, Pl, 262144,
      ND, ND, ND, nullptr, A0h, A0l, 524288, ND, nullptr, nullptr);
  // Wo + residual: X2 = x + g_msa * (attn0 @ Wo)
  k_gemm_hl<2><<<dim3(32, 4, 1), 256, 0, stream>>>(A0h, A0l, 0, WoTh, WoTl, 0,
      ND, ND, ND, X2, nullptr, nullptr, 0, ND, x, MODS);
  // xm = modulate(LN(X2)) -> fp32 (router) + fp16 (ffn); fused router logits
  k_lnmod<<<NT, 256, 0, stream>>>(X2, ND, XM, XMH, nullptr, ND, fn_w, fn_b, MODS, 1536, 2048,
                                  Wr, br, LOGI);
  // routing: colnorm -> fused atomic-free route (top2+scan+fill)
  k_colnorm<<<32, 256, 0, stream>>>(LOGI, NRM);
  k_route<<<1, 1024, 0, stream>>>(LOGI, NRM, PROB, WSEL, offs, list, inv);
  k_aux<<<1, 256, 0, stream>>>(PROB, out + (size_t)NT * ND);
  // MoE: exact-tiled pipelines, atomic-free down-proj, combine
  k_tcast13<<<dim3(16, 48, 16), 256, 0, stream>>>(W1, W3, W1T, W3T);
  k_ffn_fused<<<TM_MAX * 24, 256, 0, stream>>>(XMH, W1T, W3T, list, offs, GATEH);
  k_tcastW2<<<dim3(48, 16, 8), 256, 0, stream>>>(W2, W2T);  // W3T dead now
  k_moe2_mfma<<<TM_MAX * 8, 256, 0, stream>>>(GATEH, W2T, offs, PBUF);
  k_moe_reduce<<<2048, 256, 0, stream>>>(PBUF, inv, WSEL, out);
}

// Round 9
// 396.307 us; speedup vs baseline: 1.0893x; 1.0893x over previous
//
#include <hip/hip_runtime.h>
#include <math.h>

// Problem constants
#define NB 4
#define NS 1024
#define ND 512
#define NE 8
#define NH 1536
#define NT 4096       // NB*NS
#define D6 3072

typedef _Float16 half_t;
typedef _Float16 f16x8 __attribute__((ext_vector_type(8)));
typedef _Float16 f16x4 __attribute__((ext_vector_type(4)));
typedef float    f32x4 __attribute__((ext_vector_type(4)));

#define LDC 136   // epilogue C-tile stride in halfs (272 B, 16B-aligned)
#define TM_MAX 71 // max total m-tiles across experts (sum ceil(ne/128) <= 71)

// async global->LDS, 16B per lane, dest = wave-uniform base + lane*16
__device__ __forceinline__ void gld16(const void* g, void* l) {
  __builtin_amdgcn_global_load_lds((const __attribute__((address_space(1))) char*)g,
                                   (__attribute__((address_space(3))) char*)l, 16, 0, 0);
}

// bijective XCD-chunked swizzle (m204): round-robin blockIdx -> chunked wgid
// so consecutive wgids (which share an A-panel) land on the same XCD's L2.
__device__ __forceinline__ int xcd_chunk(int bid, int nwg) {
  int xcd = bid & 7, ixc = bid >> 3;
  int q = nwg >> 3, r = nwg & 7;
  return (xcd < r ? xcd * (q + 1) : r * (q + 1) + (xcd - r) * q) + ixc;
}

// resolve flat tile index -> (expert, m0) from offs[] prefix sums (block-uniform)
__device__ __forceinline__ int resolve_tile(const int* __restrict__ offs, int t,
                                            int& e_out, int& m0_out) {
  int acc = 0, found = 0, ee = 0, mm = 0;
  #pragma unroll
  for (int q = 0; q < NE; ++q) {
    int ne_q = offs[q + 1] - offs[q];
    int te = (ne_q + 127) >> 7;
    if (!found && t < acc + te) { ee = q; mm = (t - acc) << 7; found = 1; }
    acc += te;
  }
  e_out = ee; m0_out = mm;
  return found;
}

// ---------------- K0: mods = silu(c) @ W_ada + b_ada  (B x 6D) ----------------
// split-K: 192 blocks x 64 outputs; each thread 128-d chain; LDS combine.
__global__ __launch_bounds__(256) void k_ada(const float* __restrict__ c,
    const float* __restrict__ Wada, const float* __restrict__ bada,
    float* __restrict__ mods)
{
  __shared__ float sc[ND];
  __shared__ float part[256];
  int tid = threadIdx.x;
  int blk = blockIdx.x;           // 192 blocks: 48 per batch (3072/64)
  int o0 = blk * 64;
  int b = o0 / D6;
  int j0 = o0 - b * D6;
  for (int d = tid; d < ND; d += 256) {
    float v = c[b * ND + d];
    sc[d] = v / (1.f + expf(-v));
  }
  __syncthreads();
  int j = j0 + (tid & 63);
  int kc = tid >> 6;              // 0..3 k-chunk
  float acc = 0.f;
  #pragma unroll 8
  for (int d = kc * 128; d < kc * 128 + 128; ++d)
    acc += sc[d] * Wada[(size_t)d * D6 + j];
  part[tid] = acc;
  __syncthreads();
  if (tid < 64) {
    float r = part[tid] + part[tid + 64] + part[tid + 128] + part[tid + 192]
            + bada[j0 + tid];
    mods[b * D6 + j0 + tid] = r;
  }
}

// ------ LN (+modulate). Outputs: fp32 (opt) and/or h/l fp16 planes (opt). ----
// When Wr != nullptr also emits router logits[row][0..7] = y . Wr + br
__global__ __launch_bounds__(256) void k_lnmod(const float* X, int xstride,
    float* Yf, half_t* Yh, half_t* Yl, int ystride,
    const float* __restrict__ w, const float* __restrict__ b,
    const float* __restrict__ mods, int sh_off, int sc_off,
    const float* __restrict__ Wr, const float* __restrict__ br,
    float* __restrict__ logits)
{
  __shared__ float red[16];
  __shared__ float red2[32];
  int tid = threadIdx.x;
  int row = blockIdx.x;
  int batch = row >> 10;
  const float* xr = X + (size_t)row * xstride;
  float x0 = xr[tid], x1 = xr[tid + 256];
  float s = x0 + x1, q = x0 * x0 + x1 * x1;
  #pragma unroll
  for (int off = 32; off > 0; off >>= 1) { s += __shfl_down(s, off, 64); q += __shfl_down(q, off, 64); }
  if ((tid & 63) == 0) { red[tid >> 6] = s; red[8 + (tid >> 6)] = q; }
  __syncthreads();
  if (tid == 0) {
    float S = red[0] + red[1] + red[2] + red[3];
    float Q = red[8] + red[9] + red[10] + red[11];
    float mean = S * (1.f / (float)ND);
    float var = Q * (1.f / (float)ND) - mean * mean;
    red[0] = mean; red[1] = rsqrtf(var + 1e-5f);
  }
  __syncthreads();
  float mean = red[0], rstd = red[1];
  int d0 = tid, d1 = tid + 256;
  float y0 = (x0 - mean) * rstd * w[d0] + b[d0];
  float y1 = (x1 - mean) * rstd * w[d1] + b[d1];
  if (mods) {
    const float* mb = mods + batch * D6;
    y0 = y0 * (1.f + mb[sc_off + d0]) + mb[sh_off + d0];
    y1 = y1 * (1.f + mb[sc_off + d1]) + mb[sh_off + d1];
  }
  size_t o0 = (size_t)row * ystride + d0, o1 = (size_t)row * ystride + d1;
  if (Yf) { Yf[o0] = y0; Yf[o1] = y1; }
  if (Yh) {
    half_t h0 = (half_t)y0, h1 = (half_t)y1;
    Yh[o0] = h0; Yh[o1] = h1;
    if (Yl) { Yl[o0] = (half_t)(y0 - (float)h0); Yl[o1] = (half_t)(y1 - (float)h1); }
  }
  if (Wr) {
    float p[8];
    float4 wa = *(const float4*)(Wr + d0 * 8);
    float4 wb = *(const float4*)(Wr + d0 * 8 + 4);
    float4 wc = *(const float4*)(Wr + d1 * 8);
    float4 wd = *(const float4*)(Wr + d1 * 8 + 4);
    p[0] = y0 * wa.x + y1 * wc.x; p[1] = y0 * wa.y + y1 * wc.y;
    p[2] = y0 * wa.z + y1 * wc.z; p[3] = y0 * wa.w + y1 * wc.w;
    p[4] = y0 * wb.x + y1 * wd.x; p[5] = y0 * wb.y + y1 * wd.y;
    p[6] = y0 * wb.z + y1 * wd.z; p[7] = y0 * wb.w + y1 * wd.w;
    #pragma unroll
    for (int off = 32; off > 0; off >>= 1)
      #pragma unroll
      for (int e = 0; e < 8; ++e) p[e] += __shfl_down(p[e], off, 64);
    if ((tid & 63) == 0) {
      #pragma unroll
      for (int e = 0; e < 8; ++e) red2[(tid >> 6) * 8 + e] = p[e];
    }
    __syncthreads();
    if (tid < 8)
      logits[(size_t)row * 8 + tid] = red2[tid] + red2[8 + tid] + red2[16 + tid]
                                    + red2[24 + tid] + br[tid];
  }
}

// ------ fused in-place LN of q and k halves of QKV (row stride 1536) ---------
__global__ __launch_bounds__(256) void k_lnqk(float* QKV,
    const float* __restrict__ qw, const float* __restrict__ qb,
    const float* __restrict__ kw, const float* __restrict__ kb)
{
  __shared__ float red[16];
  int tid = threadIdx.x;
  int row = blockIdx.x >> 1;
  int h = blockIdx.x & 1;
  const float* w = h ? kw : qw;
  const float* b = h ? kb : qb;
  float* xr = QKV + (size_t)row * 1536 + h * 512;
  float x0 = xr[tid], x1 = xr[tid + 256];
  float s = x0 + x1, q = x0 * x0 + x1 * x1;
  #pragma unroll
  for (int off = 32; off > 0; off >>= 1) { s += __shfl_down(s, off, 64); q += __shfl_down(q, off, 64); }
  if ((tid & 63) == 0) { red[tid >> 6] = s; red[8 + (tid >> 6)] = q; }
  __syncthreads();
  if (tid == 0) {
    float S = red[0] + red[1] + red[2] + red[3];
    float Q = red[8] + red[9] + red[10] + red[11];
    float mean = S * (1.f / (float)ND);
    float var = Q * (1.f / (float)ND) - mean * mean;
    red[0] = mean; red[1] = rsqrtf(var + 1e-5f);
  }
  __syncthreads();
  float mean = red[0], rstd = red[1];
  xr[tid]       = (x0 - mean) * rstd * w[tid] + b[tid];
  xr[tid + 256] = (x1 - mean) * rstd * w[tid + 256] + b[tid + 256];
}

// ---- transpose+split q,k: QKV[s][z*512..] -> (base + z*4MB)[c][s] h/l -------
__global__ __launch_bounds__(256) void k_tsplit2(const float* __restrict__ QKV,
    half_t* __restrict__ H0, half_t* __restrict__ L0)
{
  __shared__ float tile[32][33];
  int z = blockIdx.z;
  half_t* outH = H0 + (size_t)z * 4194304;
  half_t* outL = L0 + (size_t)z * 4194304;
  int col0 = z * 512;
  int s0 = blockIdx.x * 32, c0 = blockIdx.y * 32;
  int tid = threadIdx.x;
  int r = tid >> 5, c = tid & 31;
  #pragma unroll
  for (int p = 0; p < 4; ++p)
    tile[r + p * 8][c] = QKV[(size_t)(s0 + r + p * 8) * 1536 + col0 + c0 + c];
  __syncthreads();
  #pragma unroll
  for (int p = 0; p < 4; ++p) {
    float v = tile[c][r + p * 8];
    half_t h = (half_t)v;
    size_t o = (size_t)(c0 + r + p * 8) * NT + s0 + c;
    outH[o] = h; outL[o] = (half_t)(v - (float)h);
  }
}

// ---- 4x weight transpose+split into one 2048-row h/l buffer -----------------
__global__ __launch_bounds__(256) void k_wsplit4(const float* __restrict__ Wq,
    const float* __restrict__ Wk, const float* __restrict__ Wv,
    const float* __restrict__ Wo, half_t* __restrict__ outH, half_t* __restrict__ outL)
{
  __shared__ float tile[32][33];
  int z = blockIdx.z;
  const float* W = (z == 0) ? Wq : (z == 1) ? Wk : (z == 2) ? Wv : Wo;
  int rowoff = z * 512;
  int k0 = blockIdx.x * 32, n0 = blockIdx.y * 32;
  int tid = threadIdx.x;
  int r = tid >> 5, c = tid & 31;
  #pragma unroll
  for (int p = 0; p < 4; ++p)
    tile[r + p * 8][c] = W[(size_t)(k0 + r + p * 8) * ND + n0 + c];
  __syncthreads();
  #pragma unroll
  for (int p = 0; p < 4; ++p) {
    float v = tile[c][r + p * 8];
    half_t h = (half_t)v;
    size_t o = (size_t)(rowoff + n0 + r + p * 8) * ND + k0 + c;
    outH[o] = h; outL[o] = (half_t)(v - (float)h);
  }
}

// ---- v split: QKV[s][1024..1535] fp32 -> Vh/Vl [s][512] ---------------------
__global__ __launch_bounds__(256) void k_vsplit(const float* __restrict__ QKV,
    half_t* __restrict__ Vh, half_t* __restrict__ Vl)
{
  int i = blockIdx.x * 256 + threadIdx.x;
  int s = i >> 7, c = (i & 127) * 4;
  float4 v = *(const float4*)(QKV + (size_t)s * 1536 + 1024 + c);
  f16x4 h, l;
  h[0] = (half_t)v.x; l[0] = (half_t)(v.x - (float)h[0]);
  h[1] = (half_t)v.y; l[1] = (half_t)(v.y - (float)h[1]);
  h[2] = (half_t)v.z; l[2] = (half_t)(v.z - (float)h[2]);
  h[3] = (half_t)v.w; l[3] = (half_t)(v.w - (float)h[3]);
  *(f16x4*)(Vh + (size_t)s * ND + c) = h;
  *(f16x4*)(Vl + (size_t)s * ND + c) = l;
}

// ============ split-fp16 MFMA GEMM: C = A_hl(M,K) * B_hl(N,K)^T ==============
// counted-vmcnt pipeline (T4): wait vmcnt(8) at top of iter -> prefetch
// loads stay in flight across barriers and get a full iteration to land.
template<int MODE>
__global__ __launch_bounds__(256, 2) void k_gemm_hl(
    const half_t* __restrict__ Ah, const half_t* __restrict__ Al, long long sAz,
    const half_t* __restrict__ Bh, const half_t* __restrict__ Bl, long long sBz,
    int lda, int ldb, int K,
    float* __restrict__ Cf, half_t* __restrict__ Ch, half_t* __restrict__ Cl,
    long long sCz, int ldc,
    const float* __restrict__ xres, const float* __restrict__ mods)
{
  int z = blockIdx.z;
  int m0 = blockIdx.x * 128, n0 = blockIdx.y * 128;
  // LDS: Ah dbuf [0,16K) | Al [16K,32K) | Bh [32K,48K) | Bl [48K,64K)
  __shared__ __align__(16) char smem[65536];
  half_t* Sh = (half_t*)smem;
  int tid = threadIdx.x;
  int lane = tid & 63, w = tid >> 6;
  int wm = (w >> 1) * 64, wn = (w & 1) * 64;
  int qd = lane >> 4, md = lane & 15;
  int rA0 = tid >> 2;
  int sw = (((tid & 3) ^ ((tid >> 3) & 3)) << 3);   // swizzled k-chunk (halfs)

  const half_t* pAh0 = Ah + z * sAz + (size_t)(m0 + rA0) * lda + sw;
  const half_t* pAh1 = pAh0 + (size_t)64 * lda;
  const half_t* pAl0 = Al + z * sAz + (size_t)(m0 + rA0) * lda + sw;
  const half_t* pAl1 = pAl0 + (size_t)64 * lda;
  const half_t* pBh0 = Bh + z * sBz + (size_t)(n0 + rA0) * ldb + sw;
  const half_t* pBh1 = pBh0 + (size_t)64 * ldb;
  const half_t* pBl0 = Bl + z * sBz + (size_t)(n0 + rA0) * ldb + sw;
  const half_t* pBl1 = pBl0 + (size_t)64 * ldb;

  // wave-uniform LDS dests (lane-linear: dest = base + lane*16)
  char* dAh = smem + w * 1024;
  char* dAl = smem + 16384 + w * 1024;
  char* dBh = smem + 32768 + w * 1024;
  char* dBl = smem + 49152 + w * 1024;

  f32x4 acc[4][4];
  #pragma unroll
  for (int i = 0; i < 4; ++i)
    #pragma unroll
    for (int j = 0; j < 4; ++j)
      #pragma unroll
      for (int p = 0; p < 4; ++p) acc[i][j][p] = 0.f;

  // swizzled ds_read offsets (halfs): phys chunk = qd ^ ((row>>1)&3)
  int swq  = ((qd ^ ((md >> 1) & 3)) << 3);
  int aoff = (wm + md) * 32 + swq;
  int boff = (wn + md) * 32 + swq;

#define GEMM_STAGE(p, kk) do { int kb_ = (kk); int pb_ = (p) * 8192;         \
    gld16(pAh0 + kb_, dAh + pb_); gld16(pAh1 + kb_, dAh + pb_ + 4096);       \
    gld16(pAl0 + kb_, dAl + pb_); gld16(pAl1 + kb_, dAl + pb_ + 4096);       \
    gld16(pBh0 + kb_, dBh + pb_); gld16(pBh1 + kb_, dBh + pb_ + 4096);       \
    gld16(pBl0 + kb_, dBl + pb_); gld16(pBl1 + kb_, dBl + pb_ + 4096); } while (0)

  int iters = K >> 5;
  GEMM_STAGE(0, 0);
  int cur = 0;
  #pragma unroll 1
  for (int it = 0; it < iters; ++it) {
    if (it + 1 < iters) {
      GEMM_STAGE(cur ^ 1, (it + 1) * 32);
      asm volatile("s_waitcnt vmcnt(8)\ns_barrier" ::: "memory");
    } else {
      asm volatile("s_waitcnt vmcnt(0)\ns_barrier" ::: "memory");
    }
    const half_t* Ash = Sh + cur * 4096;
    const half_t* Asl = Sh + 8192  + cur * 4096;
    const half_t* Bsh = Sh + 16384 + cur * 4096;
    const half_t* Bsl = Sh + 24576 + cur * 4096;
    f16x8 ah[4], al[4], bh[4], bl[4];
    #pragma unroll
    for (int i = 0; i < 4; ++i) {
      ah[i] = *(const f16x8*)(Ash + aoff + i * 512);
      al[i] = *(const f16x8*)(Asl + aoff + i * 512);
    }
    #pragma unroll
    for (int j = 0; j < 4; ++j) {
      bh[j] = *(const f16x8*)(Bsh + boff + j * 512);
      bl[j] = *(const f16x8*)(Bsl + boff + j * 512);
    }
    __builtin_amdgcn_s_setprio(1);
    #pragma unroll
    for (int i = 0; i < 4; ++i)
      #pragma unroll
      for (int j = 0; j < 4; ++j) {
        acc[i][j] = __builtin_amdgcn_mfma_f32_16x16x32_f16(ah[i], bh[j], acc[i][j], 0, 0, 0);
        acc[i][j] = __builtin_amdgcn_mfma_f32_16x16x32_f16(ah[i], bl[j], acc[i][j], 0, 0, 0);
        acc[i][j] = __builtin_amdgcn_mfma_f32_16x16x32_f16(al[i], bh[j], acc[i][j], 0, 0, 0);
      }
    __builtin_amdgcn_s_setprio(0);
    asm volatile("s_barrier" ::: "memory");
    cur ^= 1;
  }
#undef GEMM_STAGE

  if (MODE == 1) {
    half_t* Cs = (half_t*)smem;
    __syncthreads();
    #pragma unroll
    for (int i = 0; i < 4; ++i)
      #pragma unroll
      for (int j = 0; j < 4; ++j)
        #pragma unroll
        for (int p = 0; p < 4; ++p)
          Cs[(wm + 16 * i + qd * 4 + p) * LDC + wn + 16 * j + md] = (half_t)acc[i][j][p];
    __syncthreads();
    #pragma unroll
    for (int it2 = 0; it2 < 8; ++it2) {
      int chunk = it2 * 256 + tid;
      int r = chunk >> 4, c8 = (chunk & 15) * 8;
      *(f16x8*)(Ch + z * sCz + (size_t)(m0 + r) * ldc + n0 + c8) = *(const f16x8*)(Cs + r * LDC + c8);
    }
    __syncthreads();
    #pragma unroll
    for (int i = 0; i < 4; ++i)
      #pragma unroll
      for (int j = 0; j < 4; ++j)
        #pragma unroll
        for (int p = 0; p < 4; ++p) {
          float v = acc[i][j][p];
          half_t h = (half_t)v;
          Cs[(wm + 16 * i + qd * 4 + p) * LDC + wn + 16 * j + md] = (half_t)(v - (float)h);
        }
    __syncthreads();
    #pragma unroll
    for (int it2 = 0; it2 < 8; ++it2) {
      int chunk = it2 * 256 + tid;
      int r = chunk >> 4, c8 = (chunk & 15) * 8;
      *(f16x8*)(Cl + z * sCz + (size_t)(m0 + r) * ldc + n0 + c8) = *(const f16x8*)(Cs + r * LDC + c8);
    }
  } else {
    #pragma unroll
    for (int i = 0; i < 4; ++i)
      #pragma unroll
      for (int p = 0; p < 4; ++p) {
        int r = m0 + wm + 16 * i + qd * 4 + p;
        float* cp = Cf + z * sCz + (size_t)r * ldc + n0 + wn + md;
        if (MODE == 2) {
          int batch = r >> 10;
          const float* mb = mods + batch * D6 + 2 * ND;
          const float* xp = xres + (size_t)r * ldc + n0 + wn + md;
          #pragma unroll
          for (int j = 0; j < 4; ++j) {
            int col = wn + md + 16 * j;
            cp[16 * j] = xp[16 * j] + mb[n0 + col] * acc[i][j][p];
          }
        } else {
          #pragma unroll
          for (int j = 0; j < 4; ++j) cp[16 * j] = acc[i][j][p];
        }
      }
  }
}

// ---- softmax over rows of 512, input = 4 split-K partials; P as h/l fp16 ----
__global__ __launch_bounds__(256) void k_softmax512_sum4(const float* __restrict__ SC4,
    half_t* __restrict__ Ph, half_t* __restrict__ Pl)
{
  __shared__ float red[16];
  int tid = threadIdx.x;
  int row = blockIdx.x;             // 2048 = b*512 + d
  int b = row >> 9, d = row & 511;
  const float* r0 = SC4 + ((size_t)(b * 4 + 0) << 18) + (size_t)d * ND;
  const float* r1 = SC4 + ((size_t)(b * 4 + 1) << 18) + (size_t)d * ND;
  const float* r2 = SC4 + ((size_t)(b * 4 + 2) << 18) + (size_t)d * ND;
  const float* r3 = SC4 + ((size_t)(b * 4 + 3) << 18) + (size_t)d * ND;
  float x0 = r0[tid] + r1[tid] + r2[tid] + r3[tid];
  float x1 = r0[tid + 256] + r1[tid + 256] + r2[tid + 256] + r3[tid + 256];
  float m = fmaxf(x0, x1);
  #pragma unroll
  for (int off = 32; off > 0; off >>= 1) m = fmaxf(m, __shfl_down(m, off, 64));
  if ((tid & 63) == 0) red[tid >> 6] = m;
  __syncthreads();
  if (tid == 0) red[0] = fmaxf(fmaxf(red[0], red[1]), fmaxf(red[2], red[3]));
  __syncthreads();
  m = red[0];
  float e0 = expf(x0 - m), e1 = expf(x1 - m);
  float s = e0 + e1;
  #pragma unroll
  for (int off = 32; off > 0; off >>= 1) s += __shfl_down(s, off, 64);
  if ((tid & 63) == 0) red[8 + (tid >> 6)] = s;
  __syncthreads();
  if (tid == 0) red[8] = red[8] + red[9] + red[10] + red[11];
  __syncthreads();
  float inv = 1.f / red[8];
  float p0 = e0 * inv, p1 = e1 * inv;
  size_t base = (size_t)row * ND;
  half_t h0 = (half_t)p0, h1 = (half_t)p1;
  Ph[base + tid] = h0;       Pl[base + tid] = (half_t)(p0 - (float)h0);
  Ph[base + tid + 256] = h1; Pl[base + tid + 256] = (half_t)(p1 - (float)h1);
}

// -------- nrm[b,e] = sqrt(sum_s logits^2) ------------------------------------
__global__ __launch_bounds__(256) void k_colnorm(const float* __restrict__ logits,
    float* __restrict__ nrm)
{
  __shared__ float red[8];
  int tid = threadIdx.x;
  int b = blockIdx.x >> 3, e = blockIdx.x & 7;
  float acc = 0.f;
  for (int s = tid; s < NS; s += 256) {
    float l = logits[((size_t)(b << 10) + s) * NE + e];
    acc += l * l;
  }
  #pragma unroll
  for (int off = 32; off > 0; off >>= 1) acc += __shfl_down(acc, off, 64);
  if ((tid & 63) == 0) red[tid >> 6] = acc;
  __syncthreads();
  if (tid == 0) nrm[b * NE + e] = sqrtf(red[0] + red[1] + red[2] + red[3]);
}

// ======== fused routing: top2 + histogram + scan + compaction ================
// single block, 1024 threads, atomic-free (ballot-based deterministic ranks).
__global__ __launch_bounds__(1024) void k_route(const float* __restrict__ logits,
    const float* __restrict__ nrm, float* __restrict__ probs,
    float* __restrict__ wsel, int* __restrict__ offs_g,
    int* __restrict__ list, int* __restrict__ inv)
{
  __shared__ unsigned char sisel[8192];
  __shared__ int cw[8][16][8];      // per (chunk, wave, expert): count -> excl base
  __shared__ int soffs[9];
  __shared__ float snrm[32];
  int tid = threadIdx.x;
  int lane = tid & 63, wv = tid >> 6;   // 16 waves
  if (tid < 32) snrm[tid] = fmaxf(nrm[tid], 1e-12f);
  __syncthreads();
  // phase 1: per-token normalized softmax + top2
  #pragma unroll 1
  for (int c = 0; c < 4; ++c) {
    int t = c * 1024 + tid;
    int b = t >> 10;
    float p[8];
    float4 l0 = *(const float4*)(logits + (size_t)t * 8);
    float4 l1 = *(const float4*)(logits + (size_t)t * 8 + 4);
    p[0] = l0.x / snrm[b * 8 + 0]; p[1] = l0.y / snrm[b * 8 + 1];
    p[2] = l0.z / snrm[b * 8 + 2]; p[3] = l0.w / snrm[b * 8 + 3];
    p[4] = l1.x / snrm[b * 8 + 4]; p[5] = l1.y / snrm[b * 8 + 5];
    p[6] = l1.z / snrm[b * 8 + 6]; p[7] = l1.w / snrm[b * 8 + 7];
    float mx = p[0];
    #pragma unroll
    for (int e = 1; e < 8; ++e) mx = fmaxf(mx, p[e]);
    float s = 0.f;
    #pragma unroll
    for (int e = 0; e < 8; ++e) { p[e] = expf(p[e] - mx); s += p[e]; }
    float invs = 1.f / s;
    #pragma unroll
    for (int e = 0; e < 8; ++e) { p[e] *= invs; probs[(size_t)t * 8 + e] = p[e]; }
    int i1 = 0;
    #pragma unroll
    for (int e = 1; e < 8; ++e) if (p[e] > p[i1]) i1 = e;
    int i2 = (i1 == 0) ? 1 : 0;
    #pragma unroll
    for (int e = 0; e < 8; ++e) if (e != i1 && p[e] > p[i2]) i2 = e;
    wsel[t * 2] = p[i1]; wsel[t * 2 + 1] = p[i2];
    sisel[t * 2] = (unsigned char)i1; sisel[t * 2 + 1] = (unsigned char)i2;
  }
  __syncthreads();
  // pass A: per (chunk, wave, expert) counts via ballots
  #pragma unroll 1
  for (int c = 0; c < 8; ++c) {
    int em = sisel[c * 1024 + tid];
    #pragma unroll
    for (int e = 0; e < 8; ++e) {
      unsigned long long mask = __ballot(em == e);
      if (lane == 0) cw[c][wv][e] = (int)__popcll(mask);
    }
  }
  __syncthreads();
  // exclusive scan per expert over (chunk, wave); totals -> soffs
  if (tid < 8) {
    int e = tid, run = 0;
    for (int c = 0; c < 8; ++c)
      for (int w2 = 0; w2 < 16; ++w2) { int v = cw[c][w2][e]; cw[c][w2][e] = run; run += v; }
    soffs[e] = run;
  }
  __syncthreads();
  if (tid == 0) {
    int a = 0;
    #pragma unroll
    for (int e = 0; e < 8; ++e) { int v = soffs[e]; soffs[e] = a; a += v; }
    soffs[8] = a;
  }
  __syncthreads();
  if (tid < 9) offs_g[tid] = soffs[tid];
  // pass B: deterministic ranks + emit compacted lists
  #pragma unroll 1
  for (int c = 0; c < 8; ++c) {
    int idx = c * 1024 + tid;
    int em = sisel[idx];
    int rk = 0;
    #pragma unroll
    for (int e = 0; e < 8; ++e) {
      unsigned long long mask = __ballot(em == e);
      if (em == e) rk = (int)__popcll(mask & ((1ull << lane) - 1ull));
    }
    int slot = soffs[em] + cw[c][wv][em] + rk;
    list[slot] = idx >> 1;
    inv[idx] = slot;
  }
}

// -------- aux = sum_{s,e} (1/E - mean_b probs)^2 -----------------------------
__global__ __launch_bounds__(256) void k_aux(const float* __restrict__ probs,
    float* __restrict__ outAux)
{
  __shared__ float red[8];
  int tid = threadIdx.x;
  float acc = 0.f;
  for (int s = tid; s < NS; s += 256) {
    #pragma unroll
    for (int e = 0; e < NE; ++e) {
      float a = probs[(size_t)s * NE + e] + probs[(size_t)(NS + s) * NE + e]
              + probs[(size_t)(2 * NS + s) * NE + e] + probs[(size_t)(3 * NS + s) * NE + e];
      float d = 0.125f - a * 0.25f;
      acc += d * d;
    }
  }
  #pragma unroll
  for (int off = 32; off > 0; off >>= 1) acc += __shfl_down(acc, off, 64);
  if ((tid & 63) == 0) red[tid >> 6] = acc;
  __syncthreads();
  if (tid == 0) *outAux = red[0] + red[1] + red[2] + red[3];
}

// ---- transpose+cast W1 and W3 in one launch: z = sel*8 + e ------------------
__global__ __launch_bounds__(256) void k_tcast13(const float* __restrict__ W1,
    const float* __restrict__ W3, half_t* __restrict__ W1t, half_t* __restrict__ W3t)
{
  __shared__ float tile[32][33];
  int z = blockIdx.z;
  int sel = z >> 3, e = z & 7;
  const float* We = (sel ? W3 : W1) + (size_t)e * ND * NH;
  half_t* Wte = (sel ? W3t : W1t) + (size_t)e * ND * NH;
  int k0 = blockIdx.x * 32, n0 = blockIdx.y * 32;
  int tid = threadIdx.x;
  int r = tid >> 5, c = tid & 31;
  #pragma unroll
  for (int p = 0; p < 4; ++p)
    tile[r + p * 8][c] = We[(size_t)(k0 + r + p * 8) * NH + n0 + c];
  __syncthreads();
  #pragma unroll
  for (int p = 0; p < 4; ++p)
    Wte[(size_t)(n0 + r + p * 8) * ND + k0 + c] = (half_t)tile[c][r + p * 8];
}

// ---- transpose+cast W2[e][NH][ND] -> W2t[e][ND][NH] -------------------------
__global__ __launch_bounds__(256) void k_tcastW2(const float* __restrict__ W,
    half_t* __restrict__ Wt)
{
  __shared__ float tile[32][33];
  const float* We = W + (size_t)blockIdx.z * NH * ND;
  half_t* Wte = Wt + (size_t)blockIdx.z * NH * ND;
  int k0 = blockIdx.x * 32, n0 = blockIdx.y * 32;
  int tid = threadIdx.x;
  int r = tid >> 5, c = tid & 31;
  #pragma unroll
  for (int p = 0; p < 4; ++p)
    tile[r + p * 8][c] = We[(size_t)(k0 + r + p * 8) * ND + n0 + c];
  __syncthreads();
  #pragma unroll
  for (int p = 0; p < 4; ++p)
    Wte[(size_t)(n0 + r + p * 8) * NH + k0 + c] = (half_t)tile[c][r + p * 8];
}

// ============ fused FFN: gate = f16( sin(xm@W1^T) * (xm@W3^T) ) ==============
// R9: R7-proven 128x128 gload_lds pipeline (counted vmcnt(6) + setprio) +
// bijective XCD-chunked swizzle so the 12 n-blocks sharing an A-panel land
// on the same XCD's L2.
__global__ __launch_bounds__(256, 3) void k_ffn_fused(const half_t* __restrict__ xmh,
    const half_t* __restrict__ W1t, const half_t* __restrict__ W3t,
    const int* __restrict__ list, const int* __restrict__ offs,
    half_t* __restrict__ gate)
{
  int bx = xcd_chunk(blockIdx.x, TM_MAX * 12);   // 852 = 71 tiles * 12 n
  int n0 = (bx % 12) * 128;
  int t  = bx / 12;
  int e, m0;
  if (!resolve_tile(offs, t, e, m0)) return;
  int base = offs[e], ne = offs[e + 1] - base;

  // LDS: A dbuf [0,16384) | B1 dbuf [16384,32768) | B3 dbuf [32768,49152) | rowt
  __shared__ __align__(16) char smem[49664];
  half_t* Sh = (half_t*)smem;
  int* rowt = (int*)(smem + 49152);
  int tid = threadIdx.x;
  if (tid < 128) {
    int rr = m0 + tid;
    rowt[tid] = (rr < ne) ? list[base + rr] : 0;
  }
  __syncthreads();

  int lane = tid & 63, w = tid >> 6;
  int wm = (w >> 1) * 64, wn = (w & 1) * 64;
  int qd = lane >> 4, md = lane & 15;
  int rA0 = tid >> 2;
  int sw = (((tid & 3) ^ ((tid >> 3) & 3)) << 3);   // swizzled k-chunk (halfs)
  int tok0 = rowt[rA0], tok1 = rowt[rA0 + 64];

  const half_t* gA0  = xmh + (size_t)tok0 * ND + sw;
  const half_t* gA1  = xmh + (size_t)tok1 * ND + sw;
  const half_t* gB10 = W1t + ((size_t)e * NH + n0 + rA0) * ND + sw;
  const half_t* gB11 = gB10 + (size_t)64 * ND;
  const half_t* gB30 = W3t + ((size_t)e * NH + n0 + rA0) * ND + sw;
  const half_t* gB31 = gB30 + (size_t)64 * ND;

  // wave-uniform LDS dests
  char* dA  = smem + w * 1024;
  char* dB1 = smem + 16384 + w * 1024;
  char* dB3 = smem + 32768 + w * 1024;

  f32x4 acc1[4][4], acc3[4][4];
  #pragma unroll
  for (int i = 0; i < 4; ++i)
    #pragma unroll
    for (int j = 0; j < 4; ++j)
      #pragma unroll
      for (int p = 0; p < 4; ++p) { acc1[i][j][p] = 0.f; acc3[i][j][p] = 0.f; }

  // swizzled ds_read offsets (halfs): phys chunk = qd ^ ((row>>1)&3)
  int swq  = ((qd ^ ((md >> 1) & 3)) << 3);
  int aoff = (wm + md) * 32 + swq;
  int boff = (wn + md) * 32 + swq;

#define FFN_STAGE(p, kk) do { int kb_ = (kk); int pb_ = (p) * 8192;          \
    gld16(gA0  + kb_, dA  + pb_); gld16(gA1  + kb_, dA  + pb_ + 4096);       \
    gld16(gB10 + kb_, dB1 + pb_); gld16(gB11 + kb_, dB1 + pb_ + 4096);       \
    gld16(gB30 + kb_, dB3 + pb_); gld16(gB31 + kb_, dB3 + pb_ + 4096); } while (0)

  FFN_STAGE(0, 0);
  int cur = 0;
  #pragma unroll 1
  for (int it = 0; it < 16; ++it) {
    if (it + 1 < 16) {
      FFN_STAGE(cur ^ 1, (it + 1) * 32);
      asm volatile("s_waitcnt vmcnt(6)\ns_barrier" ::: "memory");
    } else {
      asm volatile("s_waitcnt vmcnt(0)\ns_barrier" ::: "memory");
    }
    const half_t* As  = Sh + cur * 4096;
    const half_t* B1s = Sh + 8192  + cur * 4096;
    const half_t* B3s = Sh + 16384 + cur * 4096;
    f16x8 a[4];
    #pragma unroll
    for (int i = 0; i < 4; ++i) a[i] = *(const f16x8*)(As + aoff + i * 512);
    __builtin_amdgcn_s_setprio(1);
    #pragma unroll
    for (int j = 0; j < 4; ++j) {
      f16x8 b1 = *(const f16x8*)(B1s + boff + j * 512);
      f16x8 b3 = *(const f16x8*)(B3s + boff + j * 512);
      #pragma unroll
      for (int i = 0; i < 4; ++i) {
        acc1[i][j] = __builtin_amdgcn_mfma_f32_16x16x32_f16(a[i], b1, acc1[i][j], 0, 0, 0);
        acc3[i][j] = __builtin_amdgcn_mfma_f32_16x16x32_f16(a[i], b3, acc3[i][j], 0, 0, 0);
      }
    }
    __builtin_amdgcn_s_setprio(0);
    asm volatile("s_barrier" ::: "memory");
    cur ^= 1;
  }
#undef FFN_STAGE

  // epilogue: gate = f16(sin(h1) * h3) via LDS re-tile, vectorized store
  half_t* Cs = (half_t*)smem;
  #pragma unroll
  for (int i = 0; i < 4; ++i)
    #pragma unroll
    for (int j = 0; j < 4; ++j)
      #pragma unroll
      for (int p = 0; p < 4; ++p) {
        int rr = wm + 16 * i + qd * 4 + p;
        int cc = wn + 16 * j + md;
        Cs[rr * LDC + cc] = (half_t)(__sinf(acc1[i][j][p]) * acc3[i][j][p]);
      }
  __syncthreads();
  #pragma unroll
  for (int it = 0; it < 8; ++it) {
    int chunk = it * 256 + tid;
    int rr = chunk >> 4, c8 = (chunk & 15) * 8;
    if (m0 + rr < ne) {
      *(f16x8*)(gate + (size_t)(base + m0 + rr) * NH + n0 + c8) = *(const f16x8*)(Cs + rr * LDC + c8);
    }
  }
}

// ======= MoE stage 2 (atomic-free): P[slot][d] = gate[slot,:] @ W2_e^T =======
// R9: R7-proven 128x128 pipeline (counted vmcnt(4)) + XCD-chunked swizzle.
__global__ __launch_bounds__(256, 4) void k_moe2_mfma(const half_t* __restrict__ gate,
    const half_t* __restrict__ W2t, const int* __restrict__ offs,
    float* __restrict__ P)
{
  int bx = xcd_chunk(blockIdx.x, TM_MAX * 4);    // 284 = 71 tiles * 4 n
  int n0 = (bx & 3) * 128;
  int t = bx >> 2;
  int e, m0;
  if (!resolve_tile(offs, t, e, m0)) return;
  int base = offs[e], ne = offs[e + 1] - base;

  // LDS: A dbuf [0,16384) | B dbuf [16384,32768)
  __shared__ __align__(16) char smem[32768];
  half_t* Sh = (half_t*)smem;
  int tid = threadIdx.x;
  int lane = tid & 63, w = tid >> 6;
  int wm = (w >> 1) * 64, wn = (w & 1) * 64;
  int qd = lane >> 4, md = lane & 15;
  int rA0 = tid >> 2;
  int sw = (((tid & 3) ^ ((tid >> 3) & 3)) << 3);

  int ar0 = m0 + rA0;      if (ar0 >= ne) ar0 = ne - 1;
  int ar1 = m0 + rA0 + 64; if (ar1 >= ne) ar1 = ne - 1;
  const half_t* gA0 = gate + (size_t)(base + ar0) * NH + sw;
  const half_t* gA1 = gate + (size_t)(base + ar1) * NH + sw;
  const half_t* gB0 = W2t + ((size_t)e * ND + n0 + rA0) * NH + sw;
  const half_t* gB1 = gB0 + (size_t)64 * NH;

  char* dA = smem + w * 1024;
  char* dB = smem + 16384 + w * 1024;

  f32x4 acc[4][4];
  #pragma unroll
  for (int i = 0; i < 4; ++i)
    #pragma unroll
    for (int j = 0; j < 4; ++j)
      #pragma unroll
      for (int p = 0; p < 4; ++p) acc[i][j][p] = 0.f;

  int swq  = ((qd ^ ((md >> 1) & 3)) << 3);
  int aoff = (wm + md) * 32 + swq;
  int boff = (wn + md) * 32 + swq;

#define MOE2_STAGE(p, kk) do { int kb_ = (kk); int pb_ = (p) * 8192;         \
    gld16(gA0 + kb_, dA + pb_); gld16(gA1 + kb_, dA + pb_ + 4096);           \
    gld16(gB0 + kb_, dB + pb_); gld16(gB1 + kb_, dB + pb_ + 4096); } while (0)

  MOE2_STAGE(0, 0);
  int cur = 0;
  #pragma unroll 1
  for (int it = 0; it < 48; ++it) {
    if (it + 1 < 48) {
      MOE2_STAGE(cur ^ 1, (it + 1) * 32);
      asm volatile("s_waitcnt vmcnt(4)\ns_barrier" ::: "memory");
    } else {
      asm volatile("s_waitcnt vmcnt(0)\ns_barrier" ::: "memory");
    }
    const half_t* As = Sh + cur * 4096;
    const half_t* Bs = Sh + 8192 + cur * 4096;
    f16x8 a[4], b[4];
    #pragma unroll
    for (int i = 0; i < 4; ++i) a[i] = *(const f16x8*)(As + aoff + i * 512);
    #pragma unroll
    for (int j = 0; j < 4; ++j) b[j] = *(const f16x8*)(Bs + boff + j * 512);
    __builtin_amdgcn_s_setprio(1);
    #pragma unroll
    for (int j = 0; j < 4; ++j)
      #pragma unroll
      for (int i = 0; i < 4; ++i)
        acc[i][j] = __builtin_amdgcn_mfma_f32_16x16x32_f16(a[i], b[j], acc[i][j], 0, 0, 0);
    __builtin_amdgcn_s_setprio(0);
    asm volatile("s_barrier" ::: "memory");
    cur ^= 1;
  }
#undef MOE2_STAGE

  #pragma unroll
  for (int i = 0; i < 4; ++i)
    #pragma unroll
    for (int p = 0; p < 4; ++p) {
      int gr = m0 + wm + 16 * i + qd * 4 + p;
      if (gr < ne) {
        float* pp = P + (size_t)(base + gr) * ND + n0 + wn + md;
        #pragma unroll
        for (int j = 0; j < 4; ++j)
          pp[16 * j] = acc[i][j][p];
      }
    }
}

// ---- reduce: out[t][:] = w1 * P[slot1][:] + w2 * P[slot2][:] ----------------
__global__ __launch_bounds__(256) void k_moe_reduce(const float* __restrict__ P,
    const int* __restrict__ inv, const float* __restrict__ wsel,
    float* __restrict__ out)
{
  int i = blockIdx.x * 256 + threadIdx.x;   // 4096 * 128 float4s
  int t = i >> 7, d4 = i & 127;
  int s1 = inv[t * 2], s2 = inv[t * 2 + 1];
  float w1 = wsel[t * 2], w2 = wsel[t * 2 + 1];
  const float4* P4 = (const float4*)P;
  float4 a = P4[(size_t)s1 * 128 + d4];
  float4 b = P4[(size_t)s2 * 128 + d4];
  float4 o;
  o.x = w1 * a.x + w2 * b.x;
  o.y = w1 * a.y + w2 * b.y;
  o.z = w1 * a.z + w2 * b.z;
  o.w = w1 * a.w + w2 * b.w;
  ((float4*)out)[i] = o;
}

// ---------------- workspace layout (byte offsets, peak ~63.4 MB) -------------
static const size_t BO_MODS  = 0;          // 49152 B fp32 mods
static const size_t BO_HH    = 65536;      // Hh 4 MB   } region B (8 MB)
static const size_t BO_HL2   = 4259840;    // Hl 4 MB   }
static const size_t BO_PH    = 4259840;    // Ph 2 MB (after Hl dead)
static const size_t BO_PL    = 6357056;    // Pl 2 MB
static const size_t BO_WALLH = 8454144;    // 2 MB: q|k|v|o transposed h (2048 rows)
static const size_t BO_WALLL = 10551296;   // 2 MB: l planes
static const size_t BO_QKV   = 12648448;   // fp32 [4096][1536] 25.17 MB (region D)
static const size_t BO_A0H   = 12648448;   // attn0 h 4 MB (after QKV dead)
static const size_t BO_A0L   = 16842752;   // attn0 l 4 MB
static const size_t BO_SC4   = 21037056;   // 16 MB fp32: 16 x [512][512] split-K partials
static const size_t BO_X2    = 21037056;   // fp32 8 MB (after SC4 dead)
static const size_t BO_XM    = 29425664;   // fp32 8 MB (after SC4 dead)
static const size_t BO_QTH   = 37814272;   // qT h 4 MB } region E (16 MB)
static const size_t BO_QTL   = 42008576;
static const size_t BO_KTH   = 46202880;
static const size_t BO_KTL   = 50397184;
static const size_t BO_VH    = 54591488;   // region F (8 MB)
static const size_t BO_VL    = 58785792;
// MoE phase (aliases):
static const size_t BO_W1T   = 37814272;   // 12.58 MB (qT/kT dead after scores)
static const size_t BO_XMH   = 50397184;   // 4 MB (kT_l dead)
static const size_t BO_W3T   = 65536;      // 12.58 MB = region B+C (dead after apply/Wo)
static const size_t BO_GATE  = 12648448;   // 25.17 MB = region D
static const size_t BO_W2T   = 65536;      // 12.58 MB (overwrites W3T after ffn)
static const size_t BO_P     = 37814272;   // 16.78 MB fp32 (W1T+XMH dead after ffn)
// small buffers:
static const size_t BO_LOGI  = 62980096;
static const size_t BO_NRM   = 63111168;
static const size_t BO_PROB  = 63111296;
static const size_t BO_WSEL  = 63242368;
static const size_t BO_INTS  = 63307904;   // ints: isel 8192|cnt 8|cnt2 8|offs 16|list 8192|inv 8192

extern "C" void kernel_launch(void* const* d_in, const int* in_sizes, int n_in,
                              void* d_out, int out_size, void* d_ws, size_t ws_size,
                              hipStream_t stream)
{
  const float* x    = (const float*)d_in[0];
  const float* c    = (const float*)d_in[1];
  const float* Wada = (const float*)d_in[2];
  const float* bada = (const float*)d_in[3];
  const float* Wq   = (const float*)d_in[4];
  const float* Wk   = (const float*)d_in[5];
  const float* Wv   = (const float*)d_in[6];
  const float* Wo   = (const float*)d_in[7];
  const float* qn_w = (const float*)d_in[8];
  const float* qn_b = (const float*)d_in[9];
  const float* kn_w = (const float*)d_in[10];
  const float* kn_b = (const float*)d_in[11];
  const float* an_w = (const float*)d_in[12];
  const float* an_b = (const float*)d_in[13];
  const float* fn_w = (const float*)d_in[14];
  const float* fn_b = (const float*)d_in[15];
  const float* Wr   = (const float*)d_in[16];
  const float* br   = (const float*)d_in[17];
  const float* W1   = (const float*)d_in[18];
  const float* W2   = (const float*)d_in[19];
  const float* W3   = (const float*)d_in[20];
  float* out = (float*)d_out;
  char*  ws8 = (char*)d_ws;
  float* MODS = (float*)(ws8 + BO_MODS);
  half_t* Hh = (half_t*)(ws8 + BO_HH),   *Hl = (half_t*)(ws8 + BO_HL2);
  half_t* Ph = (half_t*)(ws8 + BO_PH),   *Pl = (half_t*)(ws8 + BO_PL);
  half_t* WALLH = (half_t*)(ws8 + BO_WALLH), *WALLL = (half_t*)(ws8 + BO_WALLL);
  half_t* WoTh = WALLH + (size_t)1536 * ND,  *WoTl = WALLL + (size_t)1536 * ND;
  float* QKV = (float*)(ws8 + BO_QKV);
  half_t* A0h = (half_t*)(ws8 + BO_A0H), *A0l = (half_t*)(ws8 + BO_A0L);
  float* SC4 = (float*)(ws8 + BO_SC4);
  float* X2  = (float*)(ws8 + BO_X2);
  float* XM  = (float*)(ws8 + BO_XM);
  half_t* qTh = (half_t*)(ws8 + BO_QTH), *qTl = (half_t*)(ws8 + BO_QTL);
  half_t* kTh = (half_t*)(ws8 + BO_KTH), *kTl = (half_t*)(ws8 + BO_KTL);
  half_t* Vh  = (half_t*)(ws8 + BO_VH),  *Vl  = (half_t*)(ws8 + BO_VL);
  half_t* W1T = (half_t*)(ws8 + BO_W1T);
  half_t* W3T = (half_t*)(ws8 + BO_W3T);
  half_t* W2T = (half_t*)(ws8 + BO_W2T);
  half_t* XMH = (half_t*)(ws8 + BO_XMH);
  half_t* GATEH = (half_t*)(ws8 + BO_GATE);
  float* PBUF = (float*)(ws8 + BO_P);
  float* LOGI = (float*)(ws8 + BO_LOGI);
  float* NRM  = (float*)(ws8 + BO_NRM);
  float* PROB = (float*)(ws8 + BO_PROB);
  float* WSEL = (float*)(ws8 + BO_WSEL);
  int* ib   = (int*)(ws8 + BO_INTS);
  int* offs = ib + 8208;
  int* list = ib + 8224;
  int* inv  = ib + 16416;

  k_ada<<<192, 256, 0, stream>>>(c, Wada, bada, MODS);
  k_wsplit4<<<dim3(16, 16, 4), 256, 0, stream>>>(Wq, Wk, Wv, Wo, WALLH, WALLL);
  // h = modulate(LN(x)) -> h/l planes
  k_lnmod<<<NT, 256, 0, stream>>>(x, ND, nullptr, Hh, Hl, ND, an_w, an_b, MODS, 0, 512,
                                  nullptr, nullptr, nullptr);
  // fused QKV: [4096][1536]
  k_gemm_hl<0><<<dim3(32, 12, 1), 256, 0, stream>>>(Hh, Hl, 0, WALLH, WALLL, 0,
      ND, ND, ND, QKV, nullptr, nullptr, 0, 1536, nullptr, nullptr);
  // fused row-LN of q and k halves (in place)
  k_lnqk<<<2 * NT, 256, 0, stream>>>(QKV, qn_w, qn_b, kn_w, kn_b);
  // transpose+split q,k to [d][s]; split v
  k_tsplit2<<<dim3(128, 16, 2), 256, 0, stream>>>(QKV, qTh, qTl);
  k_vsplit<<<2048, 256, 0, stream>>>(QKV, Vh, Vl);
  // scores: split-K x4 (z = b*4+kh; A/B offset z*256 = b*1024+kh*256)
  k_gemm_hl<0><<<dim3(4, 4, 16), 256, 0, stream>>>(qTh, qTl, 256, kTh, kTl, 256,
      NT, NT, 256, SC4, nullptr, nullptr, 262144, ND, nullptr, nullptr);
  k_softmax512_sum4<<<2048, 256, 0, stream>>>(SC4, Ph, Pl);
  // apply: attn0[s][d] = sum_e v[s,e] P[d,e]
  k_gemm_hl<1><<<dim3(8, 4, 4), 256, 0, stream>>>(Vh, Vl, 524288, Ph, Pl, 262144,
      ND, ND, ND, nullptr, A0h, A0l, 524288, ND, nullptr, nullptr);
  // Wo + residual: X2 = x + g_msa * (attn0 @ Wo)
  k_gemm_hl<2><<<dim3(32, 4, 1), 256, 0, stream>>>(A0h, A0l, 0, WoTh, WoTl, 0,
      ND, ND, ND, X2, nullptr, nullptr, 0, ND, x, MODS);
  // xm = modulate(LN(X2)) -> fp32 (router) + fp16 (ffn); fused router logits
  k_lnmod<<<NT, 256, 0, stream>>>(X2, ND, XM, XMH, nullptr, ND, fn_w, fn_b, MODS, 1536, 2048,
                                  Wr, br, LOGI);
  // routing: colnorm -> fused atomic-free route (top2+scan+fill)
  k_colnorm<<<32, 256, 0, stream>>>(LOGI, NRM);
  k_route<<<1, 1024, 0, stream>>>(LOGI, NRM, PROB, WSEL, offs, list, inv);
  k_aux<<<1, 256, 0, stream>>>(PROB, out + (size_t)NT * ND);
  // MoE: exact-tiled gload_lds pipelines, atomic-free down-proj, combine
  k_tcast13<<<dim3(16, 48, 16), 256, 0, stream>>>(W1, W3, W1T, W3T);
  k_ffn_fused<<<TM_MAX * 12, 256, 0, stream>>>(XMH, W1T, W3T, list, offs, GATEH);
  k_tcastW2<<<dim3(48, 16, 8), 256, 0, stream>>>(W2, W2T);  // W3T dead now
  k_moe2_mfma<<<TM_MAX * 4, 256, 0, stream>>>(GATEH, W2T, offs, PBUF);
  k_moe_reduce<<<2048, 256, 0, stream>>>(PBUF, inv, WSEL, out);
}

// Round 10
// 385.402 us; speedup vs baseline: 1.1201x; 1.0283x over previous
//
#include <hip/hip_runtime.h>
#include <math.h>

// Problem constants
#define NB 4
#define NS 1024
#define ND 512
#define NE 8
#define NH 1536
#define NT 4096       // NB*NS
#define D6 3072

typedef _Float16 half_t;
typedef _Float16 f16x8 __attribute__((ext_vector_type(8)));
typedef _Float16 f16x4 __attribute__((ext_vector_type(4)));
typedef float    f32x4 __attribute__((ext_vector_type(4)));

#define LDC 136   // epilogue C-tile stride in halfs (272 B, 16B-aligned)
#define TM_MAX 71 // max total m-tiles across experts (sum ceil(ne/128) <= 71)

// async global->LDS, 16B per lane, dest = wave-uniform base + lane*16
__device__ __forceinline__ void gld16(const void* g, void* l) {
  __builtin_amdgcn_global_load_lds((const __attribute__((address_space(1))) char*)g,
                                   (__attribute__((address_space(3))) char*)l, 16, 0, 0);
}

// bijective XCD-chunked swizzle (m204)
__device__ __forceinline__ int xcd_chunk(int bid, int nwg) {
  int xcd = bid & 7, ixc = bid >> 3;
  int q = nwg >> 3, r = nwg & 7;
  return (xcd < r ? xcd * (q + 1) : r * (q + 1) + (xcd - r) * q) + ixc;
}

// resolve flat tile index -> (expert, m0) from offs[] prefix sums (block-uniform)
__device__ __forceinline__ int resolve_tile(const int* __restrict__ offs, int t,
                                            int& e_out, int& m0_out) {
  int acc = 0, found = 0, ee = 0, mm = 0;
  #pragma unroll
  for (int q = 0; q < NE; ++q) {
    int ne_q = offs[q + 1] - offs[q];
    int te = (ne_q + 127) >> 7;
    if (!found && t < acc + te) { ee = q; mm = (t - acc) << 7; found = 1; }
    acc += te;
  }
  e_out = ee; m0_out = mm;
  return found;
}

// ---------------- K0: mods = silu(c) @ W_ada + b_ada  (B x 6D) ----------------
// split-K: 384 blocks x 32 outputs; each thread 64-d chain; LDS combine.
__global__ __launch_bounds__(256) void k_ada(const float* __restrict__ c,
    const float* __restrict__ Wada, const float* __restrict__ bada,
    float* __restrict__ mods)
{
  __shared__ float sc[ND];
  __shared__ float part[256];
  int tid = threadIdx.x;
  int blk = blockIdx.x;           // 384 blocks: 96 per batch (3072/32)
  int o0 = blk * 32;
  int b = o0 / D6;
  int j0 = o0 - b * D6;
  for (int d = tid; d < ND; d += 256) {
    float v = c[b * ND + d];
    sc[d] = v / (1.f + expf(-v));
  }
  __syncthreads();
  int j = j0 + (tid & 31);
  int kc = tid >> 5;              // 0..7 k-chunk
  float acc = 0.f;
  #pragma unroll 8
  for (int d = kc * 64; d < kc * 64 + 64; ++d)
    acc += sc[d] * Wada[(size_t)d * D6 + j];
  part[tid] = acc;
  __syncthreads();
  if (tid < 32) {
    float r = bada[j0 + tid];
    #pragma unroll
    for (int k = 0; k < 8; ++k) r += part[tid + 32 * k];
    mods[b * D6 + j0 + tid] = r;
  }
}

// ------ LN (+modulate). Outputs: fp32 (opt) and/or h/l fp16 planes (opt). ----
// When Wr != nullptr also emits router logits[row][0..7] = y . Wr + br
__global__ __launch_bounds__(256) void k_lnmod(const float* X, int xstride,
    float* Yf, half_t* Yh, half_t* Yl, int ystride,
    const float* __restrict__ w, const float* __restrict__ b,
    const float* __restrict__ mods, int sh_off, int sc_off,
    const float* __restrict__ Wr, const float* __restrict__ br,
    float* __restrict__ logits)
{
  __shared__ float red[16];
  __shared__ float red2[32];
  int tid = threadIdx.x;
  int row = blockIdx.x;
  int batch = row >> 10;
  const float* xr = X + (size_t)row * xstride;
  float x0 = xr[tid], x1 = xr[tid + 256];
  float s = x0 + x1, q = x0 * x0 + x1 * x1;
  #pragma unroll
  for (int off = 32; off > 0; off >>= 1) { s += __shfl_down(s, off, 64); q += __shfl_down(q, off, 64); }
  if ((tid & 63) == 0) { red[tid >> 6] = s; red[8 + (tid >> 6)] = q; }
  __syncthreads();
  if (tid == 0) {
    float S = red[0] + red[1] + red[2] + red[3];
    float Q = red[8] + red[9] + red[10] + red[11];
    float mean = S * (1.f / (float)ND);
    float var = Q * (1.f / (float)ND) - mean * mean;
    red[0] = mean; red[1] = rsqrtf(var + 1e-5f);
  }
  __syncthreads();
  float mean = red[0], rstd = red[1];
  int d0 = tid, d1 = tid + 256;
  float y0 = (x0 - mean) * rstd * w[d0] + b[d0];
  float y1 = (x1 - mean) * rstd * w[d1] + b[d1];
  if (mods) {
    const float* mb = mods + batch * D6;
    y0 = y0 * (1.f + mb[sc_off + d0]) + mb[sh_off + d0];
    y1 = y1 * (1.f + mb[sc_off + d1]) + mb[sh_off + d1];
  }
  size_t o0 = (size_t)row * ystride + d0, o1 = (size_t)row * ystride + d1;
  if (Yf) { Yf[o0] = y0; Yf[o1] = y1; }
  if (Yh) {
    half_t h0 = (half_t)y0, h1 = (half_t)y1;
    Yh[o0] = h0; Yh[o1] = h1;
    if (Yl) { Yl[o0] = (half_t)(y0 - (float)h0); Yl[o1] = (half_t)(y1 - (float)h1); }
  }
  if (Wr) {
    float p[8];
    float4 wa = *(const float4*)(Wr + d0 * 8);
    float4 wb = *(const float4*)(Wr + d0 * 8 + 4);
    float4 wc = *(const float4*)(Wr + d1 * 8);
    float4 wd = *(const float4*)(Wr + d1 * 8 + 4);
    p[0] = y0 * wa.x + y1 * wc.x; p[1] = y0 * wa.y + y1 * wc.y;
    p[2] = y0 * wa.z + y1 * wc.z; p[3] = y0 * wa.w + y1 * wc.w;
    p[4] = y0 * wb.x + y1 * wd.x; p[5] = y0 * wb.y + y1 * wd.y;
    p[6] = y0 * wb.z + y1 * wd.z; p[7] = y0 * wb.w + y1 * wd.w;
    #pragma unroll
    for (int off = 32; off > 0; off >>= 1)
      #pragma unroll
      for (int e = 0; e < 8; ++e) p[e] += __shfl_down(p[e], off, 64);
    if ((tid & 63) == 0) {
      #pragma unroll
      for (int e = 0; e < 8; ++e) red2[(tid >> 6) * 8 + e] = p[e];
    }
    __syncthreads();
    if (tid < 8)
      logits[(size_t)row * 8 + tid] = red2[tid] + red2[8 + tid] + red2[16 + tid]
                                    + red2[24 + tid] + br[tid];
  }
}

// ------ fused in-place LN of q and k halves of QKV (row stride 1536) ---------
__global__ __launch_bounds__(256) void k_lnqk(float* QKV,
    const float* __restrict__ qw, const float* __restrict__ qb,
    const float* __restrict__ kw, const float* __restrict__ kb)
{
  __shared__ float red[16];
  int tid = threadIdx.x;
  int row = blockIdx.x >> 1;
  int h = blockIdx.x & 1;
  const float* w = h ? kw : qw;
  const float* b = h ? kb : qb;
  float* xr = QKV + (size_t)row * 1536 + h * 512;
  float x0 = xr[tid], x1 = xr[tid + 256];
  float s = x0 + x1, q = x0 * x0 + x1 * x1;
  #pragma unroll
  for (int off = 32; off > 0; off >>= 1) { s += __shfl_down(s, off, 64); q += __shfl_down(q, off, 64); }
  if ((tid & 63) == 0) { red[tid >> 6] = s; red[8 + (tid >> 6)] = q; }
  __syncthreads();
  if (tid == 0) {
    float S = red[0] + red[1] + red[2] + red[3];
    float Q = red[8] + red[9] + red[10] + red[11];
    float mean = S * (1.f / (float)ND);
    float var = Q * (1.f / (float)ND) - mean * mean;
    red[0] = mean; red[1] = rsqrtf(var + 1e-5f);
  }
  __syncthreads();
  float mean = red[0], rstd = red[1];
  xr[tid]       = (x0 - mean) * rstd * w[tid] + b[tid];
  xr[tid + 256] = (x1 - mean) * rstd * w[tid + 256] + b[tid + 256];
}

// ---- transpose+split q,k: QKV[s][z*512..] -> (base + z*4MB)[c][s] h/l -------
__global__ __launch_bounds__(256) void k_tsplit2(const float* __restrict__ QKV,
    half_t* __restrict__ H0, half_t* __restrict__ L0)
{
  __shared__ float tile[32][33];
  int z = blockIdx.z;
  half_t* outH = H0 + (size_t)z * 4194304;
  half_t* outL = L0 + (size_t)z * 4194304;
  int col0 = z * 512;
  int s0 = blockIdx.x * 32, c0 = blockIdx.y * 32;
  int tid = threadIdx.x;
  int r = tid >> 5, c = tid & 31;
  #pragma unroll
  for (int p = 0; p < 4; ++p)
    tile[r + p * 8][c] = QKV[(size_t)(s0 + r + p * 8) * 1536 + col0 + c0 + c];
  __syncthreads();
  #pragma unroll
  for (int p = 0; p < 4; ++p) {
    float v = tile[c][r + p * 8];
    half_t h = (half_t)v;
    size_t o = (size_t)(c0 + r + p * 8) * NT + s0 + c;
    outH[o] = h; outL[o] = (half_t)(v - (float)h);
  }
}

// ---- 4x weight transpose+split into one 2048-row h/l buffer -----------------
__global__ __launch_bounds__(256) void k_wsplit4(const float* __restrict__ Wq,
    const float* __restrict__ Wk, const float* __restrict__ Wv,
    const float* __restrict__ Wo, half_t* __restrict__ outH, half_t* __restrict__ outL)
{
  __shared__ float tile[32][33];
  int z = blockIdx.z;
  const float* W = (z == 0) ? Wq : (z == 1) ? Wk : (z == 2) ? Wv : Wo;
  int rowoff = z * 512;
  int k0 = blockIdx.x * 32, n0 = blockIdx.y * 32;
  int tid = threadIdx.x;
  int r = tid >> 5, c = tid & 31;
  #pragma unroll
  for (int p = 0; p < 4; ++p)
    tile[r + p * 8][c] = W[(size_t)(k0 + r + p * 8) * ND + n0 + c];
  __syncthreads();
  #pragma unroll
  for (int p = 0; p < 4; ++p) {
    float v = tile[c][r + p * 8];
    half_t h = (half_t)v;
    size_t o = (size_t)(rowoff + n0 + r + p * 8) * ND + k0 + c;
    outH[o] = h; outL[o] = (half_t)(v - (float)h);
  }
}

// ============ split-fp16 MFMA GEMM: C = A_hl(M,K) * B_hl(N,K)^T ==============
// counted-vmcnt pipeline (T4). MODE 3 = QKV: blocks with n0>=1024 (v columns,
// block-uniform) write Vh/Vl h/l planes directly -> k_vsplit eliminated.
template<int MODE>
__global__ __launch_bounds__(256, 2) void k_gemm_hl(
    const half_t* __restrict__ Ah, const half_t* __restrict__ Al, long long sAz,
    const half_t* __restrict__ Bh, const half_t* __restrict__ Bl, long long sBz,
    int lda, int ldb, int K,
    float* __restrict__ Cf, half_t* __restrict__ Ch, half_t* __restrict__ Cl,
    long long sCz, int ldc,
    const float* __restrict__ xres, const float* __restrict__ mods,
    half_t* __restrict__ vh, half_t* __restrict__ vl)
{
  int z = blockIdx.z;
  int m0 = blockIdx.x * 128, n0 = blockIdx.y * 128;
  // LDS: Ah dbuf [0,16K) | Al [16K,32K) | Bh [32K,48K) | Bl [48K,64K)
  __shared__ __align__(16) char smem[65536];
  half_t* Sh = (half_t*)smem;
  int tid = threadIdx.x;
  int lane = tid & 63, w = tid >> 6;
  int wm = (w >> 1) * 64, wn = (w & 1) * 64;
  int qd = lane >> 4, md = lane & 15;
  int rA0 = tid >> 2;
  int sw = (((tid & 3) ^ ((tid >> 3) & 3)) << 3);   // swizzled k-chunk (halfs)

  const half_t* pAh0 = Ah + z * sAz + (size_t)(m0 + rA0) * lda + sw;
  const half_t* pAh1 = pAh0 + (size_t)64 * lda;
  const half_t* pAl0 = Al + z * sAz + (size_t)(m0 + rA0) * lda + sw;
  const half_t* pAl1 = pAl0 + (size_t)64 * lda;
  const half_t* pBh0 = Bh + z * sBz + (size_t)(n0 + rA0) * ldb + sw;
  const half_t* pBh1 = pBh0 + (size_t)64 * ldb;
  const half_t* pBl0 = Bl + z * sBz + (size_t)(n0 + rA0) * ldb + sw;
  const half_t* pBl1 = pBl0 + (size_t)64 * ldb;

  // wave-uniform LDS dests (lane-linear: dest = base + lane*16)
  char* dAh = smem + w * 1024;
  char* dAl = smem + 16384 + w * 1024;
  char* dBh = smem + 32768 + w * 1024;
  char* dBl = smem + 49152 + w * 1024;

  f32x4 acc[4][4];
  #pragma unroll
  for (int i = 0; i < 4; ++i)
    #pragma unroll
    for (int j = 0; j < 4; ++j)
      #pragma unroll
      for (int p = 0; p < 4; ++p) acc[i][j][p] = 0.f;

  // swizzled ds_read offsets (halfs): phys chunk = qd ^ ((row>>1)&3)
  int swq  = ((qd ^ ((md >> 1) & 3)) << 3);
  int aoff = (wm + md) * 32 + swq;
  int boff = (wn + md) * 32 + swq;

#define GEMM_STAGE(p, kk) do { int kb_ = (kk); int pb_ = (p) * 8192;         \
    gld16(pAh0 + kb_, dAh + pb_); gld16(pAh1 + kb_, dAh + pb_ + 4096);       \
    gld16(pAl0 + kb_, dAl + pb_); gld16(pAl1 + kb_, dAl + pb_ + 4096);       \
    gld16(pBh0 + kb_, dBh + pb_); gld16(pBh1 + kb_, dBh + pb_ + 4096);       \
    gld16(pBl0 + kb_, dBl + pb_); gld16(pBl1 + kb_, dBl + pb_ + 4096); } while (0)

  int iters = K >> 5;
  GEMM_STAGE(0, 0);
  int cur = 0;
  #pragma unroll 1
  for (int it = 0; it < iters; ++it) {
    if (it + 1 < iters) {
      GEMM_STAGE(cur ^ 1, (it + 1) * 32);
      asm volatile("s_waitcnt vmcnt(8)\ns_barrier" ::: "memory");
    } else {
      asm volatile("s_waitcnt vmcnt(0)\ns_barrier" ::: "memory");
    }
    const half_t* Ash = Sh + cur * 4096;
    const half_t* Asl = Sh + 8192  + cur * 4096;
    const half_t* Bsh = Sh + 16384 + cur * 4096;
    const half_t* Bsl = Sh + 24576 + cur * 4096;
    f16x8 ah[4], al[4], bh[4], bl[4];
    #pragma unroll
    for (int i = 0; i < 4; ++i) {
      ah[i] = *(const f16x8*)(Ash + aoff + i * 512);
      al[i] = *(const f16x8*)(Asl + aoff + i * 512);
    }
    #pragma unroll
    for (int j = 0; j < 4; ++j) {
      bh[j] = *(const f16x8*)(Bsh + boff + j * 512);
      bl[j] = *(const f16x8*)(Bsl + boff + j * 512);
    }
    __builtin_amdgcn_s_setprio(1);
    #pragma unroll
    for (int i = 0; i < 4; ++i)
      #pragma unroll
      for (int j = 0; j < 4; ++j) {
        acc[i][j] = __builtin_amdgcn_mfma_f32_16x16x32_f16(ah[i], bh[j], acc[i][j], 0, 0, 0);
        acc[i][j] = __builtin_amdgcn_mfma_f32_16x16x32_f16(ah[i], bl[j], acc[i][j], 0, 0, 0);
        acc[i][j] = __builtin_amdgcn_mfma_f32_16x16x32_f16(al[i], bh[j], acc[i][j], 0, 0, 0);
      }
    __builtin_amdgcn_s_setprio(0);
    asm volatile("s_barrier" ::: "memory");
    cur ^= 1;
  }
#undef GEMM_STAGE

  if (MODE == 1) {
    half_t* Cs = (half_t*)smem;
    __syncthreads();
    #pragma unroll
    for (int i = 0; i < 4; ++i)
      #pragma unroll
      for (int j = 0; j < 4; ++j)
        #pragma unroll
        for (int p = 0; p < 4; ++p)
          Cs[(wm + 16 * i + qd * 4 + p) * LDC + wn + 16 * j + md] = (half_t)acc[i][j][p];
    __syncthreads();
    #pragma unroll
    for (int it2 = 0; it2 < 8; ++it2) {
      int chunk = it2 * 256 + tid;
      int r = chunk >> 4, c8 = (chunk & 15) * 8;
      *(f16x8*)(Ch + z * sCz + (size_t)(m0 + r) * ldc + n0 + c8) = *(const f16x8*)(Cs + r * LDC + c8);
    }
    __syncthreads();
    #pragma unroll
    for (int i = 0; i < 4; ++i)
      #pragma unroll
      for (int j = 0; j < 4; ++j)
        #pragma unroll
        for (int p = 0; p < 4; ++p) {
          float v = acc[i][j][p];
          half_t h = (half_t)v;
          Cs[(wm + 16 * i + qd * 4 + p) * LDC + wn + 16 * j + md] = (half_t)(v - (float)h);
        }
    __syncthreads();
    #pragma unroll
    for (int it2 = 0; it2 < 8; ++it2) {
      int chunk = it2 * 256 + tid;
      int r = chunk >> 4, c8 = (chunk & 15) * 8;
      *(f16x8*)(Cl + z * sCz + (size_t)(m0 + r) * ldc + n0 + c8) = *(const f16x8*)(Cs + r * LDC + c8);
    }
  } else if (MODE == 3 && n0 >= 1024) {
    // v columns: write h/l planes directly (replaces k_vsplit)
    #pragma unroll
    for (int i = 0; i < 4; ++i)
      #pragma unroll
      for (int p = 0; p < 4; ++p) {
        int r = m0 + wm + 16 * i + qd * 4 + p;
        int vc = n0 - 1024 + wn + md;
        half_t* hp = vh + (size_t)r * ND + vc;
        half_t* lp = vl + (size_t)r * ND + vc;
        #pragma unroll
        for (int j = 0; j < 4; ++j) {
          float v = acc[i][j][p];
          half_t h = (half_t)v;
          hp[16 * j] = h;
          lp[16 * j] = (half_t)(v - (float)h);
        }
      }
  } else {
    #pragma unroll
    for (int i = 0; i < 4; ++i)
      #pragma unroll
      for (int p = 0; p < 4; ++p) {
        int r = m0 + wm + 16 * i + qd * 4 + p;
        float* cp = Cf + z * sCz + (size_t)r * ldc + n0 + wn + md;
        if (MODE == 2) {
          int batch = r >> 10;
          const float* mb = mods + batch * D6 + 2 * ND;
          const float* xp = xres + (size_t)r * ldc + n0 + wn + md;
          #pragma unroll
          for (int j = 0; j < 4; ++j) {
            int col = wn + md + 16 * j;
            cp[16 * j] = xp[16 * j] + mb[n0 + col] * acc[i][j][p];
          }
        } else {
          #pragma unroll
          for (int j = 0; j < 4; ++j) cp[16 * j] = acc[i][j][p];
        }
      }
  }
}

// ---- softmax over rows of 512, input = 4 split-K partials; P as h/l fp16 ----
__global__ __launch_bounds__(256) void k_softmax512_sum4(const float* __restrict__ SC4,
    half_t* __restrict__ Ph, half_t* __restrict__ Pl)
{
  __shared__ float red[16];
  int tid = threadIdx.x;
  int row = blockIdx.x;             // 2048 = b*512 + d
  int b = row >> 9, d = row & 511;
  const float* r0 = SC4 + ((size_t)(b * 4 + 0) << 18) + (size_t)d * ND;
  const float* r1 = SC4 + ((size_t)(b * 4 + 1) << 18) + (size_t)d * ND;
  const float* r2 = SC4 + ((size_t)(b * 4 + 2) << 18) + (size_t)d * ND;
  const float* r3 = SC4 + ((size_t)(b * 4 + 3) << 18) + (size_t)d * ND;
  float x0 = r0[tid] + r1[tid] + r2[tid] + r3[tid];
  float x1 = r0[tid + 256] + r1[tid + 256] + r2[tid + 256] + r3[tid + 256];
  float m = fmaxf(x0, x1);
  #pragma unroll
  for (int off = 32; off > 0; off >>= 1) m = fmaxf(m, __shfl_down(m, off, 64));
  if ((tid & 63) == 0) red[tid >> 6] = m;
  __syncthreads();
  if (tid == 0) red[0] = fmaxf(fmaxf(red[0], red[1]), fmaxf(red[2], red[3]));
  __syncthreads();
  m = red[0];
  float e0 = expf(x0 - m), e1 = expf(x1 - m);
  float s = e0 + e1;
  #pragma unroll
  for (int off = 32; off > 0; off >>= 1) s += __shfl_down(s, off, 64);
  if ((tid & 63) == 0) red[8 + (tid >> 6)] = s;
  __syncthreads();
  if (tid == 0) red[8] = red[8] + red[9] + red[10] + red[11];
  __syncthreads();
  float inv = 1.f / red[8];
  float p0 = e0 * inv, p1 = e1 * inv;
  size_t base = (size_t)row * ND;
  half_t h0 = (half_t)p0, h1 = (half_t)p1;
  Ph[base + tid] = h0;       Pl[base + tid] = (half_t)(p0 - (float)h0);
  Ph[base + tid + 256] = h1; Pl[base + tid + 256] = (half_t)(p1 - (float)h1);
}

// -------- nrm[b,e] = sqrt(sum_s logits^2) ------------------------------------
__global__ __launch_bounds__(256) void k_colnorm(const float* __restrict__ logits,
    float* __restrict__ nrm)
{
  __shared__ float red[8];
  int tid = threadIdx.x;
  int b = blockIdx.x >> 3, e = blockIdx.x & 7;
  float acc = 0.f;
  for (int s = tid; s < NS; s += 256) {
    float l = logits[((size_t)(b << 10) + s) * NE + e];
    acc += l * l;
  }
  #pragma unroll
  for (int off = 32; off > 0; off >>= 1) acc += __shfl_down(acc, off, 64);
  if ((tid & 63) == 0) red[tid >> 6] = acc;
  __syncthreads();
  if (tid == 0) nrm[b * NE + e] = sqrtf(red[0] + red[1] + red[2] + red[3]);
}

// ======== fused routing: top2 + histogram + scan + compaction ================
// single block, 1024 threads, atomic-free (ballot-based deterministic ranks).
__global__ __launch_bounds__(1024) void k_route(const float* __restrict__ logits,
    const float* __restrict__ nrm, float* __restrict__ probs,
    float* __restrict__ wsel, int* __restrict__ offs_g,
    int* __restrict__ list, int* __restrict__ inv)
{
  __shared__ unsigned char sisel[8192];
  __shared__ int cw[8][16][8];      // per (chunk, wave, expert): count -> excl base
  __shared__ int soffs[9];
  __shared__ float snrm[32];
  int tid = threadIdx.x;
  int lane = tid & 63, wv = tid >> 6;   // 16 waves
  if (tid < 32) snrm[tid] = fmaxf(nrm[tid], 1e-12f);
  __syncthreads();
  // phase 1: per-token normalized softmax + top2
  #pragma unroll 1
  for (int c = 0; c < 4; ++c) {
    int t = c * 1024 + tid;
    int b = t >> 10;
    float p[8];
    float4 l0 = *(const float4*)(logits + (size_t)t * 8);
    float4 l1 = *(const float4*)(logits + (size_t)t * 8 + 4);
    p[0] = l0.x / snrm[b * 8 + 0]; p[1] = l0.y / snrm[b * 8 + 1];
    p[2] = l0.z / snrm[b * 8 + 2]; p[3] = l0.w / snrm[b * 8 + 3];
    p[4] = l1.x / snrm[b * 8 + 4]; p[5] = l1.y / snrm[b * 8 + 5];
    p[6] = l1.z / snrm[b * 8 + 6]; p[7] = l1.w / snrm[b * 8 + 7];
    float mx = p[0];
    #pragma unroll
    for (int e = 1; e < 8; ++e) mx = fmaxf(mx, p[e]);
    float s = 0.f;
    #pragma unroll
    for (int e = 0; e < 8; ++e) { p[e] = expf(p[e] - mx); s += p[e]; }
    float invs = 1.f / s;
    #pragma unroll
    for (int e = 0; e < 8; ++e) { p[e] *= invs; probs[(size_t)t * 8 + e] = p[e]; }
    int i1 = 0;
    #pragma unroll
    for (int e = 1; e < 8; ++e) if (p[e] > p[i1]) i1 = e;
    int i2 = (i1 == 0) ? 1 : 0;
    #pragma unroll
    for (int e = 0; e < 8; ++e) if (e != i1 && p[e] > p[i2]) i2 = e;
    wsel[t * 2] = p[i1]; wsel[t * 2 + 1] = p[i2];
    sisel[t * 2] = (unsigned char)i1; sisel[t * 2 + 1] = (unsigned char)i2;
  }
  __syncthreads();
  // pass A: per (chunk, wave, expert) counts via ballots
  #pragma unroll 1
  for (int c = 0; c < 8; ++c) {
    int em = sisel[c * 1024 + tid];
    #pragma unroll
    for (int e = 0; e < 8; ++e) {
      unsigned long long mask = __ballot(em == e);
      if (lane == 0) cw[c][wv][e] = (int)__popcll(mask);
    }
  }
  __syncthreads();
  // exclusive scan per expert over (chunk, wave); totals -> soffs
  if (tid < 8) {
    int e = tid, run = 0;
    for (int c = 0; c < 8; ++c)
      for (int w2 = 0; w2 < 16; ++w2) { int v = cw[c][w2][e]; cw[c][w2][e] = run; run += v; }
    soffs[e] = run;
  }
  __syncthreads();
  if (tid == 0) {
    int a = 0;
    #pragma unroll
    for (int e = 0; e < 8; ++e) { int v = soffs[e]; soffs[e] = a; a += v; }
    soffs[8] = a;
  }
  __syncthreads();
  if (tid < 9) offs_g[tid] = soffs[tid];
  // pass B: deterministic ranks + emit compacted lists
  #pragma unroll 1
  for (int c = 0; c < 8; ++c) {
    int idx = c * 1024 + tid;
    int em = sisel[idx];
    int rk = 0;
    #pragma unroll
    for (int e = 0; e < 8; ++e) {
      unsigned long long mask = __ballot(em == e);
      if (em == e) rk = (int)__popcll(mask & ((1ull << lane) - 1ull));
    }
    int slot = soffs[em] + cw[c][wv][em] + rk;
    list[slot] = idx >> 1;
    inv[idx] = slot;
  }
}

// -------- aux = sum_{s,e} (1/E - mean_b probs)^2 -----------------------------
__global__ __launch_bounds__(256) void k_aux(const float* __restrict__ probs,
    float* __restrict__ outAux)
{
  __shared__ float red[8];
  int tid = threadIdx.x;
  float acc = 0.f;
  for (int s = tid; s < NS; s += 256) {
    #pragma unroll
    for (int e = 0; e < NE; ++e) {
      float a = probs[(size_t)s * NE + e] + probs[(size_t)(NS + s) * NE + e]
              + probs[(size_t)(2 * NS + s) * NE + e] + probs[(size_t)(3 * NS + s) * NE + e];
      float d = 0.125f - a * 0.25f;
      acc += d * d;
    }
  }
  #pragma unroll
  for (int off = 32; off > 0; off >>= 1) acc += __shfl_down(acc, off, 64);
  if ((tid & 63) == 0) red[tid >> 6] = acc;
  __syncthreads();
  if (tid == 0) *outAux = red[0] + red[1] + red[2] + red[3];
}

// ---- transpose+cast W1/W3, 64x64 tiles, float4 loads + f16x4 stores ---------
// z = sel*8 + e; input We[ND][NH], output Wte[NH][ND].
__global__ __launch_bounds__(256) void k_tcast13(const float* __restrict__ W1,
    const float* __restrict__ W3, half_t* __restrict__ W1t, half_t* __restrict__ W3t)
{
  __shared__ float tile[64][68];
  int z = blockIdx.z;
  int sel = z >> 3, e = z & 7;
  const float* We = (sel ? W3 : W1) + (size_t)e * ND * NH;
  half_t* Wte = (sel ? W3t : W1t) + (size_t)e * ND * NH;
  int k0 = blockIdx.x * 64, n0 = blockIdx.y * 64;   // grid (8, 24, 16)
  int tid = threadIdx.x;
  int r = tid >> 4, c4 = tid & 15;
  #pragma unroll
  for (int p = 0; p < 4; ++p) {
    int row = r + p * 16;
    float4 v = *(const float4*)(We + (size_t)(k0 + row) * NH + n0 + c4 * 4);
    tile[row][c4 * 4 + 0] = v.x; tile[row][c4 * 4 + 1] = v.y;
    tile[row][c4 * 4 + 2] = v.z; tile[row][c4 * 4 + 3] = v.w;
  }
  __syncthreads();
  #pragma unroll
  for (int p = 0; p < 4; ++p) {
    int orow = r + p * 16;
    f16x4 h;
    #pragma unroll
    for (int i = 0; i < 4; ++i) h[i] = (half_t)tile[c4 * 4 + i][orow];
    *(f16x4*)(Wte + (size_t)(n0 + orow) * ND + k0 + c4 * 4) = h;
  }
}

// ---- transpose+cast W2[e][NH][ND] -> W2t[e][ND][NH], 64x64 vectorized -------
__global__ __launch_bounds__(256) void k_tcastW2(const float* __restrict__ W,
    half_t* __restrict__ Wt)
{
  __shared__ float tile[64][68];
  const float* We = W + (size_t)blockIdx.z * NH * ND;
  half_t* Wte = Wt + (size_t)blockIdx.z * NH * ND;
  int k0 = blockIdx.x * 64, n0 = blockIdx.y * 64;   // grid (24, 8, 8)
  int tid = threadIdx.x;
  int r = tid >> 4, c4 = tid & 15;
  #pragma unroll
  for (int p = 0; p < 4; ++p) {
    int row = r + p * 16;
    float4 v = *(const float4*)(We + (size_t)(k0 + row) * ND + n0 + c4 * 4);
    tile[row][c4 * 4 + 0] = v.x; tile[row][c4 * 4 + 1] = v.y;
    tile[row][c4 * 4 + 2] = v.z; tile[row][c4 * 4 + 3] = v.w;
  }
  __syncthreads();
  #pragma unroll
  for (int p = 0; p < 4; ++p) {
    int orow = r + p * 16;
    f16x4 h;
    #pragma unroll
    for (int i = 0; i < 4; ++i) h[i] = (half_t)tile[c4 * 4 + i][orow];
    *(f16x4*)(Wte + (size_t)(n0 + orow) * NH + k0 + c4 * 4) = h;
  }
}

// ============ fused FFN: gate = f16( sin(xm@W1^T) * (xm@W3^T) ) ==============
// 128x128 gload_lds pipeline (counted vmcnt(6) + setprio) + XCD-chunked swizzle.
__global__ __launch_bounds__(256, 3) void k_ffn_fused(const half_t* __restrict__ xmh,
    const half_t* __restrict__ W1t, const half_t* __restrict__ W3t,
    const int* __restrict__ list, const int* __restrict__ offs,
    half_t* __restrict__ gate)
{
  int bx = xcd_chunk(blockIdx.x, TM_MAX * 12);   // 852 = 71 tiles * 12 n
  int n0 = (bx % 12) * 128;
  int t  = bx / 12;
  int e, m0;
  if (!resolve_tile(offs, t, e, m0)) return;
  int base = offs[e], ne = offs[e + 1] - base;

  // LDS: A dbuf [0,16384) | B1 dbuf [16384,32768) | B3 dbuf [32768,49152) | rowt
  __shared__ __align__(16) char smem[49664];
  half_t* Sh = (half_t*)smem;
  int* rowt = (int*)(smem + 49152);
  int tid = threadIdx.x;
  if (tid < 128) {
    int rr = m0 + tid;
    rowt[tid] = (rr < ne) ? list[base + rr] : 0;
  }
  __syncthreads();

  int lane = tid & 63, w = tid >> 6;
  int wm = (w >> 1) * 64, wn = (w & 1) * 64;
  int qd = lane >> 4, md = lane & 15;
  int rA0 = tid >> 2;
  int sw = (((tid & 3) ^ ((tid >> 3) & 3)) << 3);   // swizzled k-chunk (halfs)
  int tok0 = rowt[rA0], tok1 = rowt[rA0 + 64];

  const half_t* gA0  = xmh + (size_t)tok0 * ND + sw;
  const half_t* gA1  = xmh + (size_t)tok1 * ND + sw;
  const half_t* gB10 = W1t + ((size_t)e * NH + n0 + rA0) * ND + sw;
  const half_t* gB11 = gB10 + (size_t)64 * ND;
  const half_t* gB30 = W3t + ((size_t)e * NH + n0 + rA0) * ND + sw;
  const half_t* gB31 = gB30 + (size_t)64 * ND;

  // wave-uniform LDS dests
  char* dA  = smem + w * 1024;
  char* dB1 = smem + 16384 + w * 1024;
  char* dB3 = smem + 32768 + w * 1024;

  f32x4 acc1[4][4], acc3[4][4];
  #pragma unroll
  for (int i = 0; i < 4; ++i)
    #pragma unroll
    for (int j = 0; j < 4; ++j)
      #pragma unroll
      for (int p = 0; p < 4; ++p) { acc1[i][j][p] = 0.f; acc3[i][j][p] = 0.f; }

  // swizzled ds_read offsets (halfs): phys chunk = qd ^ ((row>>1)&3)
  int swq  = ((qd ^ ((md >> 1) & 3)) << 3);
  int aoff = (wm + md) * 32 + swq;
  int boff = (wn + md) * 32 + swq;

#define FFN_STAGE(p, kk) do { int kb_ = (kk); int pb_ = (p) * 8192;          \
    gld16(gA0  + kb_, dA  + pb_); gld16(gA1  + kb_, dA  + pb_ + 4096);       \
    gld16(gB10 + kb_, dB1 + pb_); gld16(gB11 + kb_, dB1 + pb_ + 4096);       \
    gld16(gB30 + kb_, dB3 + pb_); gld16(gB31 + kb_, dB3 + pb_ + 4096); } while (0)

  FFN_STAGE(0, 0);
  int cur = 0;
  #pragma unroll 1
  for (int it = 0; it < 16; ++it) {
    if (it + 1 < 16) {
      FFN_STAGE(cur ^ 1, (it + 1) * 32);
      asm volatile("s_waitcnt vmcnt(6)\ns_barrier" ::: "memory");
    } else {
      asm volatile("s_waitcnt vmcnt(0)\ns_barrier" ::: "memory");
    }
    const half_t* As  = Sh + cur * 4096;
    const half_t* B1s = Sh + 8192  + cur * 4096;
    const half_t* B3s = Sh + 16384 + cur * 4096;
    f16x8 a[4];
    #pragma unroll
    for (int i = 0; i < 4; ++i) a[i] = *(const f16x8*)(As + aoff + i * 512);
    __builtin_amdgcn_s_setprio(1);
    #pragma unroll
    for (int j = 0; j < 4; ++j) {
      f16x8 b1 = *(const f16x8*)(B1s + boff + j * 512);
      f16x8 b3 = *(const f16x8*)(B3s + boff + j * 512);
      #pragma unroll
      for (int i = 0; i < 4; ++i) {
        acc1[i][j] = __builtin_amdgcn_mfma_f32_16x16x32_f16(a[i], b1, acc1[i][j], 0, 0, 0);
        acc3[i][j] = __builtin_amdgcn_mfma_f32_16x16x32_f16(a[i], b3, acc3[i][j], 0, 0, 0);
      }
    }
    __builtin_amdgcn_s_setprio(0);
    asm volatile("s_barrier" ::: "memory");
    cur ^= 1;
  }
#undef FFN_STAGE

  // epilogue: gate = f16(sin(h1) * h3) via LDS re-tile, vectorized store
  half_t* Cs = (half_t*)smem;
  #pragma unroll
  for (int i = 0; i < 4; ++i)
    #pragma unroll
    for (int j = 0; j < 4; ++j)
      #pragma unroll
      for (int p = 0; p < 4; ++p) {
        int rr = wm + 16 * i + qd * 4 + p;
        int cc = wn + 16 * j + md;
        Cs[rr * LDC + cc] = (half_t)(__sinf(acc1[i][j][p]) * acc3[i][j][p]);
      }
  __syncthreads();
  #pragma unroll
  for (int it = 0; it < 8; ++it) {
    int chunk = it * 256 + tid;
    int rr = chunk >> 4, c8 = (chunk & 15) * 8;
    if (m0 + rr < ne) {
      *(f16x8*)(gate + (size_t)(base + m0 + rr) * NH + n0 + c8) = *(const f16x8*)(Cs + rr * LDC + c8);
    }
  }
}

// ======= MoE stage 2 (atomic-free): P[slot][d] = gate[slot,:] @ W2_e^T =======
__global__ __launch_bounds__(256, 4) void k_moe2_mfma(const half_t* __restrict__ gate,
    const half_t* __restrict__ W2t, const int* __restrict__ offs,
    float* __restrict__ P)
{
  int bx = xcd_chunk(blockIdx.x, TM_MAX * 4);    // 284 = 71 tiles * 4 n
  int n0 = (bx & 3) * 128;
  int t = bx >> 2;
  int e, m0;
  if (!resolve_tile(offs, t, e, m0)) return;
  int base = offs[e], ne = offs[e + 1] - base;

  // LDS: A dbuf [0,16384) | B dbuf [16384,32768)
  __shared__ __align__(16) char smem[32768];
  half_t* Sh = (half_t*)smem;
  int tid = threadIdx.x;
  int lane = tid & 63, w = tid >> 6;
  int wm = (w >> 1) * 64, wn = (w & 1) * 64;
  int qd = lane >> 4, md = lane & 15;
  int rA0 = tid >> 2;
  int sw = (((tid & 3) ^ ((tid >> 3) & 3)) << 3);

  int ar0 = m0 + rA0;      if (ar0 >= ne) ar0 = ne - 1;
  int ar1 = m0 + rA0 + 64; if (ar1 >= ne) ar1 = ne - 1;
  const half_t* gA0 = gate + (size_t)(base + ar0) * NH + sw;
  const half_t* gA1 = gate + (size_t)(base + ar1) * NH + sw;
  const half_t* gB0 = W2t + ((size_t)e * ND + n0 + rA0) * NH + sw;
  const half_t* gB1 = gB0 + (size_t)64 * NH;

  char* dA = smem + w * 1024;
  char* dB = smem + 16384 + w * 1024;

  f32x4 acc[4][4];
  #pragma unroll
  for (int i = 0; i < 4; ++i)
    #pragma unroll
    for (int j = 0; j < 4; ++j)
      #pragma unroll
      for (int p = 0; p < 4; ++p) acc[i][j][p] = 0.f;

  int swq  = ((qd ^ ((md >> 1) & 3)) << 3);
  int aoff = (wm + md) * 32 + swq;
  int boff = (wn + md) * 32 + swq;

#define MOE2_STAGE(p, kk) do { int kb_ = (kk); int pb_ = (p) * 8192;         \
    gld16(gA0 + kb_, dA + pb_); gld16(gA1 + kb_, dA + pb_ + 4096);           \
    gld16(gB0 + kb_, dB + pb_); gld16(gB1 + kb_, dB + pb_ + 4096); } while (0)

  MOE2_STAGE(0, 0);
  int cur = 0;
  #pragma unroll 1
  for (int it = 0; it < 48; ++it) {
    if (it + 1 < 48) {
      MOE2_STAGE(cur ^ 1, (it + 1) * 32);
      asm volatile("s_waitcnt vmcnt(4)\ns_barrier" ::: "memory");
    } else {
      asm volatile("s_waitcnt vmcnt(0)\ns_barrier" ::: "memory");
    }
    const half_t* As = Sh + cur * 4096;
    const half_t* Bs = Sh + 8192 + cur * 4096;
    f16x8 a[4], b[4];
    #pragma unroll
    for (int i = 0; i < 4; ++i) a[i] = *(const f16x8*)(As + aoff + i * 512);
    #pragma unroll
    for (int j = 0; j < 4; ++j) b[j] = *(const f16x8*)(Bs + boff + j * 512);
    __builtin_amdgcn_s_setprio(1);
    #pragma unroll
    for (int j = 0; j < 4; ++j)
      #pragma unroll
      for (int i = 0; i < 4; ++i)
        acc[i][j] = __builtin_amdgcn_mfma_f32_16x16x32_f16(a[i], b[j], acc[i][j], 0, 0, 0);
    __builtin_amdgcn_s_setprio(0);
    asm volatile("s_barrier" ::: "memory");
    cur ^= 1;
  }
#undef MOE2_STAGE

  #pragma unroll
  for (int i = 0; i < 4; ++i)
    #pragma unroll
    for (int p = 0; p < 4; ++p) {
      int gr = m0 + wm + 16 * i + qd * 4 + p;
      if (gr < ne) {
        float* pp = P + (size_t)(base + gr) * ND + n0 + wn + md;
        #pragma unroll
        for (int j = 0; j < 4; ++j)
          pp[16 * j] = acc[i][j][p];
      }
    }
}

// ---- reduce: out[t][:] = w1 * P[slot1][:] + w2 * P[slot2][:] ----------------
__global__ __launch_bounds__(256) void k_moe_reduce(const float* __restrict__ P,
    const int* __restrict__ inv, const float* __restrict__ wsel,
    float* __restrict__ out)
{
  int i = blockIdx.x * 256 + threadIdx.x;   // 4096 * 128 float4s
  int t = i >> 7, d4 = i & 127;
  int s1 = inv[t * 2], s2 = inv[t * 2 + 1];
  float w1 = wsel[t * 2], w2 = wsel[t * 2 + 1];
  const float4* P4 = (const float4*)P;
  float4 a = P4[(size_t)s1 * 128 + d4];
  float4 b = P4[(size_t)s2 * 128 + d4];
  float4 o;
  o.x = w1 * a.x + w2 * b.x;
  o.y = w1 * a.y + w2 * b.y;
  o.z = w1 * a.z + w2 * b.z;
  o.w = w1 * a.w + w2 * b.w;
  ((float4*)out)[i] = o;
}

// ---------------- workspace layout (byte offsets, peak ~63.4 MB) -------------
static const size_t BO_MODS  = 0;          // 49152 B fp32 mods
static const size_t BO_HH    = 65536;      // Hh 4 MB   } region B (8 MB)
static const size_t BO_HL2   = 4259840;    // Hl 4 MB   }
static const size_t BO_PH    = 4259840;    // Ph 2 MB (after Hl dead)
static const size_t BO_PL    = 6357056;    // Pl 2 MB
static const size_t BO_WALLH = 8454144;    // 2 MB: q|k|v|o transposed h (2048 rows)
static const size_t BO_WALLL = 10551296;   // 2 MB: l planes
static const size_t BO_QKV   = 12648448;   // fp32 [4096][1536] 25.17 MB (region D)
static const size_t BO_A0H   = 12648448;   // attn0 h 4 MB (after QKV dead)
static const size_t BO_A0L   = 16842752;   // attn0 l 4 MB
static const size_t BO_SC4   = 21037056;   // 16 MB fp32: 16 x [512][512] split-K partials
static const size_t BO_X2    = 21037056;   // fp32 8 MB (after SC4 dead)
static const size_t BO_XM    = 29425664;   // fp32 8 MB (after SC4 dead)
static const size_t BO_QTH   = 37814272;   // qT h 4 MB } region E (16 MB)
static const size_t BO_QTL   = 42008576;
static const size_t BO_KTH   = 46202880;
static const size_t BO_KTL   = 50397184;
static const size_t BO_VH    = 54591488;   // region F (8 MB)
static const size_t BO_VL    = 58785792;
// MoE phase (aliases):
static const size_t BO_W1T   = 37814272;   // 12.58 MB (qT/kT dead after scores)
static const size_t BO_XMH   = 50397184;   // 4 MB (kT_l dead)
static const size_t BO_W3T   = 65536;      // 12.58 MB = region B+C (dead after apply/Wo)
static const size_t BO_GATE  = 12648448;   // 25.17 MB = region D
static const size_t BO_W2T   = 65536;      // 12.58 MB (overwrites W3T after ffn)
static const size_t BO_P     = 37814272;   // 16.78 MB fp32 (W1T+XMH dead after ffn)
// small buffers:
static const size_t BO_LOGI  = 62980096;
static const size_t BO_NRM   = 63111168;
static const size_t BO_PROB  = 63111296;
static const size_t BO_WSEL  = 63242368;
static const size_t BO_INTS  = 63307904;   // ints: isel 8192|cnt 8|cnt2 8|offs 16|list 8192|inv 8192

extern "C" void kernel_launch(void* const* d_in, const int* in_sizes, int n_in,
                              void* d_out, int out_size, void* d_ws, size_t ws_size,
                              hipStream_t stream)
{
  const float* x    = (const float*)d_in[0];
  const float* c    = (const float*)d_in[1];
  const float* Wada = (const float*)d_in[2];
  const float* bada = (const float*)d_in[3];
  const float* Wq   = (const float*)d_in[4];
  const float* Wk   = (const float*)d_in[5];
  const float* Wv   = (const float*)d_in[6];
  const float* Wo   = (const float*)d_in[7];
  const float* qn_w = (const float*)d_in[8];
  const float* qn_b = (const float*)d_in[9];
  const float* kn_w = (const float*)d_in[10];
  const float* kn_b = (const float*)d_in[11];
  const float* an_w = (const float*)d_in[12];
  const float* an_b = (const float*)d_in[13];
  const float* fn_w = (const float*)d_in[14];
  const float* fn_b = (const float*)d_in[15];
  const float* Wr   = (const float*)d_in[16];
  const float* br   = (const float*)d_in[17];
  const float* W1   = (const float*)d_in[18];
  const float* W2   = (const float*)d_in[19];
  const float* W3   = (const float*)d_in[20];
  float* out = (float*)d_out;
  char*  ws8 = (char*)d_ws;
  float* MODS = (float*)(ws8 + BO_MODS);
  half_t* Hh = (half_t*)(ws8 + BO_HH),   *Hl = (half_t*)(ws8 + BO_HL2);
  half_t* Ph = (half_t*)(ws8 + BO_PH),   *Pl = (half_t*)(ws8 + BO_PL);
  half_t* WALLH = (half_t*)(ws8 + BO_WALLH), *WALLL = (half_t*)(ws8 + BO_WALLL);
  half_t* WoTh = WALLH + (size_t)1536 * ND,  *WoTl = WALLL + (size_t)1536 * ND;
  float* QKV = (float*)(ws8 + BO_QKV);
  half_t* A0h = (half_t*)(ws8 + BO_A0H), *A0l = (half_t*)(ws8 + BO_A0L);
  float* SC4 = (float*)(ws8 + BO_SC4);
  float* X2  = (float*)(ws8 + BO_X2);
  float* XM  = (float*)(ws8 + BO_XM);
  half_t* qTh = (half_t*)(ws8 + BO_QTH), *qTl = (half_t*)(ws8 + BO_QTL);
  half_t* kTh = (half_t*)(ws8 + BO_KTH), *kTl = (half_t*)(ws8 + BO_KTL);
  half_t* Vh  = (half_t*)(ws8 + BO_VH),  *Vl  = (half_t*)(ws8 + BO_VL);
  half_t* W1T = (half_t*)(ws8 + BO_W1T);
  half_t* W3T = (half_t*)(ws8 + BO_W3T);
  half_t* W2T = (half_t*)(ws8 + BO_W2T);
  half_t* XMH = (half_t*)(ws8 + BO_XMH);
  half_t* GATEH = (half_t*)(ws8 + BO_GATE);
  float* PBUF = (float*)(ws8 + BO_P);
  float* LOGI = (float*)(ws8 + BO_LOGI);
  float* NRM  = (float*)(ws8 + BO_NRM);
  float* PROB = (float*)(ws8 + BO_PROB);
  float* WSEL = (float*)(ws8 + BO_WSEL);
  int* ib   = (int*)(ws8 + BO_INTS);
  int* offs = ib + 8208;
  int* list = ib + 8224;
  int* inv  = ib + 16416;

  k_ada<<<384, 256, 0, stream>>>(c, Wada, bada, MODS);
  k_wsplit4<<<dim3(16, 16, 4), 256, 0, stream>>>(Wq, Wk, Wv, Wo, WALLH, WALLL);
  // h = modulate(LN(x)) -> h/l planes
  k_lnmod<<<NT, 256, 0, stream>>>(x, ND, nullptr, Hh, Hl, ND, an_w, an_b, MODS, 0, 512,
                                  nullptr, nullptr, nullptr);
  // fused QKV: [4096][1536]; v columns written directly as Vh/Vl (MODE 3)
  k_gemm_hl<3><<<dim3(32, 12, 1), 256, 0, stream>>>(Hh, Hl, 0, WALLH, WALLL, 0,
      ND, ND, ND, QKV, nullptr, nullptr, 0, 1536, nullptr, nullptr, Vh, Vl);
  // fused row-LN of q and k halves (in place)
  k_lnqk<<<2 * NT, 256, 0, stream>>>(QKV, qn_w, qn_b, kn_w, kn_b);
  // transpose+split q,k to [d][s]
  k_tsplit2<<<dim3(128, 16, 2), 256, 0, stream>>>(QKV, qTh, qTl);
  // scores: split-K x4 (z = b*4+kh; A/B offset z*256 = b*1024+kh*256)
  k_gemm_hl<0><<<dim3(4, 4, 16), 256, 0, stream>>>(qTh, qTl, 256, kTh, kTl, 256,
      NT, NT, 256, SC4, nullptr, nullptr, 262144, ND, nullptr, nullptr, nullptr, nullptr);
  k_softmax512_sum4<<<2048, 256, 0, stream>>>(SC4, Ph, Pl);
  // apply: attn0[s][d] = sum_e v[s,e] P[d,e]
  k_gemm_hl<1><<<dim3(8, 4, 4), 256, 0, stream>>>(Vh, Vl, 524288, Ph, Pl, 262144,
      ND, ND, ND, nullptr, A0h, A0l, 524288, ND, nullptr, nullptr, nullptr, nullptr);
  // Wo + residual: X2 = x + g_msa * (attn0 @ Wo)
  k_gemm_hl<2><<<dim3(32, 4, 1), 256, 0, stream>>>(A0h, A0l, 0, WoTh, WoTl, 0,
      ND, ND, ND, X2, nullptr, nullptr, 0, ND, x, MODS, nullptr, nullptr);
  // xm = modulate(LN(X2)) -> fp32 (router) + fp16 (ffn); fused router logits
  k_lnmod<<<NT, 256, 0, stream>>>(X2, ND, XM, XMH, nullptr, ND, fn_w, fn_b, MODS, 1536, 2048,
                                  Wr, br, LOGI);
  // routing: colnorm -> fused atomic-free route (top2+scan+fill)
  k_colnorm<<<32, 256, 0, stream>>>(LOGI, NRM);
  k_route<<<1, 1024, 0, stream>>>(LOGI, NRM, PROB, WSEL, offs, list, inv);
  k_aux<<<1, 256, 0, stream>>>(PROB, out + (size_t)NT * ND);
  // MoE: exact-tiled gload_lds pipelines, atomic-free down-proj, combine
  k_tcast13<<<dim3(8, 24, 16), 256, 0, stream>>>(W1, W3, W1T, W3T);
  k_ffn_fused<<<TM_MAX * 12, 256, 0, stream>>>(XMH, W1T, W3T, list, offs, GATEH);
  k_tcastW2<<<dim3(24, 8, 8), 256, 0, stream>>>(W2, W2T);  // W3T dead now
  k_moe2_mfma<<<TM_MAX * 4, 256, 0, stream>>>(GATEH, W2T, offs, PBUF);
  k_moe_reduce<<<2048, 256, 0, stream>>>(PBUF, inv, WSEL, out);
}

// Round 11
// 378.851 us; speedup vs baseline: 1.1395x; 1.0173x over previous
//
#include <hip/hip_runtime.h>
#include <math.h>

// Problem constants
#define NB 4
#define NS 1024
#define ND 512
#define NE 8
#define NH 1536
#define NT 4096       // NB*NS
#define D6 3072

typedef _Float16 half_t;
typedef _Float16 f16x8 __attribute__((ext_vector_type(8)));
typedef _Float16 f16x4 __attribute__((ext_vector_type(4)));
typedef float    f32x4 __attribute__((ext_vector_type(4)));

#define LDC 136   // epilogue C-tile stride in halfs (272 B, 16B-aligned)
#define TM_MAX 71 // max total m-tiles across experts (sum ceil(ne/128) <= 71)

// async global->LDS, 16B per lane, dest = wave-uniform base + lane*16
__device__ __forceinline__ void gld16(const void* g, void* l) {
  __builtin_amdgcn_global_load_lds((const __attribute__((address_space(1))) char*)g,
                                   (__attribute__((address_space(3))) char*)l, 16, 0, 0);
}

// bijective XCD-chunked swizzle (m204)
__device__ __forceinline__ int xcd_chunk(int bid, int nwg) {
  int xcd = bid & 7, ixc = bid >> 3;
  int q = nwg >> 3, r = nwg & 7;
  return (xcd < r ? xcd * (q + 1) : r * (q + 1) + (xcd - r) * q) + ixc;
}

// resolve flat tile index -> (expert, m0) from offs[] prefix sums (block-uniform)
__device__ __forceinline__ int resolve_tile(const int* __restrict__ offs, int t,
                                            int& e_out, int& m0_out) {
  int acc = 0, found = 0, ee = 0, mm = 0;
  #pragma unroll
  for (int q = 0; q < NE; ++q) {
    int ne_q = offs[q + 1] - offs[q];
    int te = (ne_q + 127) >> 7;
    if (!found && t < acc + te) { ee = q; mm = (t - acc) << 7; found = 1; }
    acc += te;
  }
  e_out = ee; m0_out = mm;
  return found;
}

// ---------------- K0: mods = silu(c) @ W_ada + b_ada  (B x 6D) ----------------
// split-K: 384 blocks x 32 outputs; each thread 64-d chain; LDS combine.
__global__ __launch_bounds__(256) void k_ada(const float* __restrict__ c,
    const float* __restrict__ Wada, const float* __restrict__ bada,
    float* __restrict__ mods)
{
  __shared__ float sc[ND];
  __shared__ float part[256];
  int tid = threadIdx.x;
  int blk = blockIdx.x;           // 384 blocks: 96 per batch (3072/32)
  int o0 = blk * 32;
  int b = o0 / D6;
  int j0 = o0 - b * D6;
  for (int d = tid; d < ND; d += 256) {
    float v = c[b * ND + d];
    sc[d] = v / (1.f + expf(-v));
  }
  __syncthreads();
  int j = j0 + (tid & 31);
  int kc = tid >> 5;              // 0..7 k-chunk
  float acc = 0.f;
  #pragma unroll 8
  for (int d = kc * 64; d < kc * 64 + 64; ++d)
    acc += sc[d] * Wada[(size_t)d * D6 + j];
  part[tid] = acc;
  __syncthreads();
  if (tid < 32) {
    float r = bada[j0 + tid];
    #pragma unroll
    for (int k = 0; k < 8; ++k) r += part[tid + 32 * k];
    mods[b * D6 + j0 + tid] = r;
  }
}

// ------ LN (+modulate). Outputs: fp32 (opt) and/or h/l fp16 planes (opt). ----
// When Wr != nullptr also emits router logits[row][0..7] = y . Wr + br
__global__ __launch_bounds__(256) void k_lnmod(const float* X, int xstride,
    float* Yf, half_t* Yh, half_t* Yl, int ystride,
    const float* __restrict__ w, const float* __restrict__ b,
    const float* __restrict__ mods, int sh_off, int sc_off,
    const float* __restrict__ Wr, const float* __restrict__ br,
    float* __restrict__ logits)
{
  __shared__ float red[16];
  __shared__ float red2[32];
  int tid = threadIdx.x;
  int row = blockIdx.x;
  int batch = row >> 10;
  const float* xr = X + (size_t)row * xstride;
  float x0 = xr[tid], x1 = xr[tid + 256];
  float s = x0 + x1, q = x0 * x0 + x1 * x1;
  #pragma unroll
  for (int off = 32; off > 0; off >>= 1) { s += __shfl_down(s, off, 64); q += __shfl_down(q, off, 64); }
  if ((tid & 63) == 0) { red[tid >> 6] = s; red[8 + (tid >> 6)] = q; }
  __syncthreads();
  if (tid == 0) {
    float S = red[0] + red[1] + red[2] + red[3];
    float Q = red[8] + red[9] + red[10] + red[11];
    float mean = S * (1.f / (float)ND);
    float var = Q * (1.f / (float)ND) - mean * mean;
    red[0] = mean; red[1] = rsqrtf(var + 1e-5f);
  }
  __syncthreads();
  float mean = red[0], rstd = red[1];
  int d0 = tid, d1 = tid + 256;
  float y0 = (x0 - mean) * rstd * w[d0] + b[d0];
  float y1 = (x1 - mean) * rstd * w[d1] + b[d1];
  if (mods) {
    const float* mb = mods + batch * D6;
    y0 = y0 * (1.f + mb[sc_off + d0]) + mb[sh_off + d0];
    y1 = y1 * (1.f + mb[sc_off + d1]) + mb[sh_off + d1];
  }
  size_t o0 = (size_t)row * ystride + d0, o1 = (size_t)row * ystride + d1;
  if (Yf) { Yf[o0] = y0; Yf[o1] = y1; }
  if (Yh) {
    half_t h0 = (half_t)y0, h1 = (half_t)y1;
    Yh[o0] = h0; Yh[o1] = h1;
    if (Yl) { Yl[o0] = (half_t)(y0 - (float)h0); Yl[o1] = (half_t)(y1 - (float)h1); }
  }
  if (Wr) {
    float p[8];
    float4 wa = *(const float4*)(Wr + d0 * 8);
    float4 wb = *(const float4*)(Wr + d0 * 8 + 4);
    float4 wc = *(const float4*)(Wr + d1 * 8);
    float4 wd = *(const float4*)(Wr + d1 * 8 + 4);
    p[0] = y0 * wa.x + y1 * wc.x; p[1] = y0 * wa.y + y1 * wc.y;
    p[2] = y0 * wa.z + y1 * wc.z; p[3] = y0 * wa.w + y1 * wc.w;
    p[4] = y0 * wb.x + y1 * wd.x; p[5] = y0 * wb.y + y1 * wd.y;
    p[6] = y0 * wb.z + y1 * wd.z; p[7] = y0 * wb.w + y1 * wd.w;
    #pragma unroll
    for (int off = 32; off > 0; off >>= 1)
      #pragma unroll
      for (int e = 0; e < 8; ++e) p[e] += __shfl_down(p[e], off, 64);
    if ((tid & 63) == 0) {
      #pragma unroll
      for (int e = 0; e < 8; ++e) red2[(tid >> 6) * 8 + e] = p[e];
    }
    __syncthreads();
    if (tid < 8)
      logits[(size_t)row * 8 + tid] = red2[tid] + red2[8 + tid] + red2[16 + tid]
                                    + red2[24 + tid] + br[tid];
  }
}

// ---- fused LN + transpose + split of q,k halves of QKV ----------------------
// grid (128, 2): x = 32-row s-tile, y = half (0=q, 1=k). Computes row stats
// in-block, then normalizes during the transpose read -> eliminates k_lnqk's
// 16MB normalized write-back and one 8192-block launch.
__global__ __launch_bounds__(256) void k_lnt(const float* __restrict__ QKV,
    const float* __restrict__ qw, const float* __restrict__ qb,
    const float* __restrict__ kw, const float* __restrict__ kb,
    half_t* __restrict__ H0, half_t* __restrict__ L0)
{
  __shared__ float stats[32][2];
  __shared__ float tile[32][33];
  int h = blockIdx.y;
  int s0 = blockIdx.x * 32;
  const float* w = h ? kw : qw;
  const float* b = h ? kb : qb;
  half_t* outH = H0 + (size_t)h * 4194304;
  half_t* outL = L0 + (size_t)h * 4194304;
  int col0 = h * 512;
  int tid = threadIdx.x;
  // phase 1: row stats (8 threads/row, 64 cols each, shfl-8 reduce)
  {
    int r = tid >> 3, c8 = tid & 7;
    const float* xr = QKV + (size_t)(s0 + r) * 1536 + col0 + c8 * 64;
    float s = 0.f, q = 0.f;
    #pragma unroll
    for (int i = 0; i < 16; ++i) {
      float4 v = *(const float4*)(xr + i * 4);
      s += v.x + v.y + v.z + v.w;
      q += v.x * v.x + v.y * v.y + v.z * v.z + v.w * v.w;
    }
    #pragma unroll
    for (int off = 4; off > 0; off >>= 1) {
      s += __shfl_down(s, off, 8);
      q += __shfl_down(q, off, 8);
    }
    if (c8 == 0) {
      float mean = s * (1.f / 512.f);
      float var = q * (1.f / 512.f) - mean * mean;
      stats[r][0] = mean;
      stats[r][1] = rsqrtf(var + 1e-5f);
    }
  }
  __syncthreads();
  // phase 2: 16 col-tiles of 32, normalize + transpose + h/l split
  int r = tid >> 5, c = tid & 31;
  #pragma unroll 1
  for (int ct = 0; ct < 16; ++ct) {
    int cb = ct * 32;
    #pragma unroll
    for (int p = 0; p < 4; ++p) {
      int rr = r + p * 8;
      float v = QKV[(size_t)(s0 + rr) * 1536 + col0 + cb + c];
      tile[rr][c] = (v - stats[rr][0]) * stats[rr][1] * w[cb + c] + b[cb + c];
    }
    __syncthreads();
    #pragma unroll
    for (int p = 0; p < 4; ++p) {
      int rr = r + p * 8;
      float v = tile[c][rr];
      half_t hh = (half_t)v;
      size_t o = (size_t)(cb + rr) * NT + s0 + c;
      outH[o] = hh;
      outL[o] = (half_t)(v - (float)hh);
    }
    __syncthreads();
  }
}

// ---- 4x weight transpose+split into one 2048-row h/l buffer -----------------
__global__ __launch_bounds__(256) void k_wsplit4(const float* __restrict__ Wq,
    const float* __restrict__ Wk, const float* __restrict__ Wv,
    const float* __restrict__ Wo, half_t* __restrict__ outH, half_t* __restrict__ outL)
{
  __shared__ float tile[32][33];
  int z = blockIdx.z;
  const float* W = (z == 0) ? Wq : (z == 1) ? Wk : (z == 2) ? Wv : Wo;
  int rowoff = z * 512;
  int k0 = blockIdx.x * 32, n0 = blockIdx.y * 32;
  int tid = threadIdx.x;
  int r = tid >> 5, c = tid & 31;
  #pragma unroll
  for (int p = 0; p < 4; ++p)
    tile[r + p * 8][c] = W[(size_t)(k0 + r + p * 8) * ND + n0 + c];
  __syncthreads();
  #pragma unroll
  for (int p = 0; p < 4; ++p) {
    float v = tile[c][r + p * 8];
    half_t h = (half_t)v;
    size_t o = (size_t)(rowoff + n0 + r + p * 8) * ND + k0 + c;
    outH[o] = h; outL[o] = (half_t)(v - (float)h);
  }
}

// ============ split-fp16 MFMA GEMM: C = A_hl(M,K) * B_hl(N,K)^T ==============
// counted-vmcnt pipeline (T4). MODE 3 = QKV: blocks with n0>=1024 (v columns,
// block-uniform) write Vh/Vl h/l planes directly.
template<int MODE>
__global__ __launch_bounds__(256, 2) void k_gemm_hl(
    const half_t* __restrict__ Ah, const half_t* __restrict__ Al, long long sAz,
    const half_t* __restrict__ Bh, const half_t* __restrict__ Bl, long long sBz,
    int lda, int ldb, int K,
    float* __restrict__ Cf, half_t* __restrict__ Ch, half_t* __restrict__ Cl,
    long long sCz, int ldc,
    const float* __restrict__ xres, const float* __restrict__ mods,
    half_t* __restrict__ vh, half_t* __restrict__ vl)
{
  int z = blockIdx.z;
  int m0 = blockIdx.x * 128, n0 = blockIdx.y * 128;
  // LDS: Ah dbuf [0,16K) | Al [16K,32K) | Bh [32K,48K) | Bl [48K,64K)
  __shared__ __align__(16) char smem[65536];
  half_t* Sh = (half_t*)smem;
  int tid = threadIdx.x;
  int lane = tid & 63, w = tid >> 6;
  int wm = (w >> 1) * 64, wn = (w & 1) * 64;
  int qd = lane >> 4, md = lane & 15;
  int rA0 = tid >> 2;
  int sw = (((tid & 3) ^ ((tid >> 3) & 3)) << 3);   // swizzled k-chunk (halfs)

  const half_t* pAh0 = Ah + z * sAz + (size_t)(m0 + rA0) * lda + sw;
  const half_t* pAh1 = pAh0 + (size_t)64 * lda;
  const half_t* pAl0 = Al + z * sAz + (size_t)(m0 + rA0) * lda + sw;
  const half_t* pAl1 = pAl0 + (size_t)64 * lda;
  const half_t* pBh0 = Bh + z * sBz + (size_t)(n0 + rA0) * ldb + sw;
  const half_t* pBh1 = pBh0 + (size_t)64 * ldb;
  const half_t* pBl0 = Bl + z * sBz + (size_t)(n0 + rA0) * ldb + sw;
  const half_t* pBl1 = pBl0 + (size_t)64 * ldb;

  // wave-uniform LDS dests (lane-linear: dest = base + lane*16)
  char* dAh = smem + w * 1024;
  char* dAl = smem + 16384 + w * 1024;
  char* dBh = smem + 32768 + w * 1024;
  char* dBl = smem + 49152 + w * 1024;

  f32x4 acc[4][4];
  #pragma unroll
  for (int i = 0; i < 4; ++i)
    #pragma unroll
    for (int j = 0; j < 4; ++j)
      #pragma unroll
      for (int p = 0; p < 4; ++p) acc[i][j][p] = 0.f;

  // swizzled ds_read offsets (halfs): phys chunk = qd ^ ((row>>1)&3)
  int swq  = ((qd ^ ((md >> 1) & 3)) << 3);
  int aoff = (wm + md) * 32 + swq;
  int boff = (wn + md) * 32 + swq;

#define GEMM_STAGE(p, kk) do { int kb_ = (kk); int pb_ = (p) * 8192;         \
    gld16(pAh0 + kb_, dAh + pb_); gld16(pAh1 + kb_, dAh + pb_ + 4096);       \
    gld16(pAl0 + kb_, dAl + pb_); gld16(pAl1 + kb_, dAl + pb_ + 4096);       \
    gld16(pBh0 + kb_, dBh + pb_); gld16(pBh1 + kb_, dBh + pb_ + 4096);       \
    gld16(pBl0 + kb_, dBl + pb_); gld16(pBl1 + kb_, dBl + pb_ + 4096); } while (0)

  int iters = K >> 5;
  GEMM_STAGE(0, 0);
  int cur = 0;
  #pragma unroll 1
  for (int it = 0; it < iters; ++it) {
    if (it + 1 < iters) {
      GEMM_STAGE(cur ^ 1, (it + 1) * 32);
      asm volatile("s_waitcnt vmcnt(8)\ns_barrier" ::: "memory");
    } else {
      asm volatile("s_waitcnt vmcnt(0)\ns_barrier" ::: "memory");
    }
    const half_t* Ash = Sh + cur * 4096;
    const half_t* Asl = Sh + 8192  + cur * 4096;
    const half_t* Bsh = Sh + 16384 + cur * 4096;
    const half_t* Bsl = Sh + 24576 + cur * 4096;
    f16x8 ah[4], al[4], bh[4], bl[4];
    #pragma unroll
    for (int i = 0; i < 4; ++i) {
      ah[i] = *(const f16x8*)(Ash + aoff + i * 512);
      al[i] = *(const f16x8*)(Asl + aoff + i * 512);
    }
    #pragma unroll
    for (int j = 0; j < 4; ++j) {
      bh[j] = *(const f16x8*)(Bsh + boff + j * 512);
      bl[j] = *(const f16x8*)(Bsl + boff + j * 512);
    }
    __builtin_amdgcn_s_setprio(1);
    #pragma unroll
    for (int i = 0; i < 4; ++i)
      #pragma unroll
      for (int j = 0; j < 4; ++j) {
        acc[i][j] = __builtin_amdgcn_mfma_f32_16x16x32_f16(ah[i], bh[j], acc[i][j], 0, 0, 0);
        acc[i][j] = __builtin_amdgcn_mfma_f32_16x16x32_f16(ah[i], bl[j], acc[i][j], 0, 0, 0);
        acc[i][j] = __builtin_amdgcn_mfma_f32_16x16x32_f16(al[i], bh[j], acc[i][j], 0, 0, 0);
      }
    __builtin_amdgcn_s_setprio(0);
    asm volatile("s_barrier" ::: "memory");
    cur ^= 1;
  }
#undef GEMM_STAGE

  if (MODE == 1) {
    half_t* Cs = (half_t*)smem;
    __syncthreads();
    #pragma unroll
    for (int i = 0; i < 4; ++i)
      #pragma unroll
      for (int j = 0; j < 4; ++j)
        #pragma unroll
        for (int p = 0; p < 4; ++p)
          Cs[(wm + 16 * i + qd * 4 + p) * LDC + wn + 16 * j + md] = (half_t)acc[i][j][p];
    __syncthreads();
    #pragma unroll
    for (int it2 = 0; it2 < 8; ++it2) {
      int chunk = it2 * 256 + tid;
      int r = chunk >> 4, c8 = (chunk & 15) * 8;
      *(f16x8*)(Ch + z * sCz + (size_t)(m0 + r) * ldc + n0 + c8) = *(const f16x8*)(Cs + r * LDC + c8);
    }
    __syncthreads();
    #pragma unroll
    for (int i = 0; i < 4; ++i)
      #pragma unroll
      for (int j = 0; j < 4; ++j)
        #pragma unroll
        for (int p = 0; p < 4; ++p) {
          float v = acc[i][j][p];
          half_t h = (half_t)v;
          Cs[(wm + 16 * i + qd * 4 + p) * LDC + wn + 16 * j + md] = (half_t)(v - (float)h);
        }
    __syncthreads();
    #pragma unroll
    for (int it2 = 0; it2 < 8; ++it2) {
      int chunk = it2 * 256 + tid;
      int r = chunk >> 4, c8 = (chunk & 15) * 8;
      *(f16x8*)(Cl + z * sCz + (size_t)(m0 + r) * ldc + n0 + c8) = *(const f16x8*)(Cs + r * LDC + c8);
    }
  } else if (MODE == 3 && n0 >= 1024) {
    // v columns: write h/l planes directly (replaces k_vsplit)
    #pragma unroll
    for (int i = 0; i < 4; ++i)
      #pragma unroll
      for (int p = 0; p < 4; ++p) {
        int r = m0 + wm + 16 * i + qd * 4 + p;
        int vc = n0 - 1024 + wn + md;
        half_t* hp = vh + (size_t)r * ND + vc;
        half_t* lp = vl + (size_t)r * ND + vc;
        #pragma unroll
        for (int j = 0; j < 4; ++j) {
          float v = acc[i][j][p];
          half_t h = (half_t)v;
          hp[16 * j] = h;
          lp[16 * j] = (half_t)(v - (float)h);
        }
      }
  } else {
    #pragma unroll
    for (int i = 0; i < 4; ++i)
      #pragma unroll
      for (int p = 0; p < 4; ++p) {
        int r = m0 + wm + 16 * i + qd * 4 + p;
        float* cp = Cf + z * sCz + (size_t)r * ldc + n0 + wn + md;
        if (MODE == 2) {
          int batch = r >> 10;
          const float* mb = mods + batch * D6 + 2 * ND;
          const float* xp = xres + (size_t)r * ldc + n0 + wn + md;
          #pragma unroll
          for (int j = 0; j < 4; ++j) {
            int col = wn + md + 16 * j;
            cp[16 * j] = xp[16 * j] + mb[n0 + col] * acc[i][j][p];
          }
        } else {
          #pragma unroll
          for (int j = 0; j < 4; ++j) cp[16 * j] = acc[i][j][p];
        }
      }
  }
}

// ---- softmax over rows of 512, input = 4 split-K partials; P as h/l fp16 ----
__global__ __launch_bounds__(256) void k_softmax512_sum4(const float* __restrict__ SC4,
    half_t* __restrict__ Ph, half_t* __restrict__ Pl)
{
  __shared__ float red[16];
  int tid = threadIdx.x;
  int row = blockIdx.x;             // 2048 = b*512 + d
  int b = row >> 9, d = row & 511;
  const float* r0 = SC4 + ((size_t)(b * 4 + 0) << 18) + (size_t)d * ND;
  const float* r1 = SC4 + ((size_t)(b * 4 + 1) << 18) + (size_t)d * ND;
  const float* r2 = SC4 + ((size_t)(b * 4 + 2) << 18) + (size_t)d * ND;
  const float* r3 = SC4 + ((size_t)(b * 4 + 3) << 18) + (size_t)d * ND;
  float x0 = r0[tid] + r1[tid] + r2[tid] + r3[tid];
  float x1 = r0[tid + 256] + r1[tid + 256] + r2[tid + 256] + r3[tid + 256];
  float m = fmaxf(x0, x1);
  #pragma unroll
  for (int off = 32; off > 0; off >>= 1) m = fmaxf(m, __shfl_down(m, off, 64));
  if ((tid & 63) == 0) red[tid >> 6] = m;
  __syncthreads();
  if (tid == 0) red[0] = fmaxf(fmaxf(red[0], red[1]), fmaxf(red[2], red[3]));
  __syncthreads();
  m = red[0];
  float e0 = expf(x0 - m), e1 = expf(x1 - m);
  float s = e0 + e1;
  #pragma unroll
  for (int off = 32; off > 0; off >>= 1) s += __shfl_down(s, off, 64);
  if ((tid & 63) == 0) red[8 + (tid >> 6)] = s;
  __syncthreads();
  if (tid == 0) red[8] = red[8] + red[9] + red[10] + red[11];
  __syncthreads();
  float inv = 1.f / red[8];
  float p0 = e0 * inv, p1 = e1 * inv;
  size_t base = (size_t)row * ND;
  half_t h0 = (half_t)p0, h1 = (half_t)p1;
  Ph[base + tid] = h0;       Pl[base + tid] = (half_t)(p0 - (float)h0);
  Ph[base + tid + 256] = h1; Pl[base + tid + 256] = (half_t)(p1 - (float)h1);
}

// -------- nrm[b,e] = sqrt(sum_s logits^2) ------------------------------------
__global__ __launch_bounds__(256) void k_colnorm(const float* __restrict__ logits,
    float* __restrict__ nrm)
{
  __shared__ float red[8];
  int tid = threadIdx.x;
  int b = blockIdx.x >> 3, e = blockIdx.x & 7;
  float acc = 0.f;
  for (int s = tid; s < NS; s += 256) {
    float l = logits[((size_t)(b << 10) + s) * NE + e];
    acc += l * l;
  }
  #pragma unroll
  for (int off = 32; off > 0; off >>= 1) acc += __shfl_down(acc, off, 64);
  if ((tid & 63) == 0) red[tid >> 6] = acc;
  __syncthreads();
  if (tid == 0) nrm[b * NE + e] = sqrtf(red[0] + red[1] + red[2] + red[3]);
}

// ======== fused routing: top2 + histogram + scan + compaction + aux ==========
// single block, 1024 threads, atomic-free. Chunk c == batch b, tid == s, so
// each thread holds p[e] for all 4 batches at its s -> aux computed inline
// (k_aux kernel and the probs buffer are both eliminated).
__global__ __launch_bounds__(1024) void k_route(const float* __restrict__ logits,
    const float* __restrict__ nrm,
    float* __restrict__ wsel, int* __restrict__ offs_g,
    int* __restrict__ list, int* __restrict__ inv,
    float* __restrict__ outAux)
{
  __shared__ unsigned char sisel[8192];
  __shared__ int cw[8][16][8];      // per (chunk, wave, expert): count -> excl base
  __shared__ int soffs[9];
  __shared__ float snrm[32];
  __shared__ float auxred[16];
  int tid = threadIdx.x;
  int lane = tid & 63, wv = tid >> 6;   // 16 waves
  if (tid < 32) snrm[tid] = fmaxf(nrm[tid], 1e-12f);
  __syncthreads();
  float asum[8];
  #pragma unroll
  for (int e = 0; e < 8; ++e) asum[e] = 0.f;
  // phase 1: per-token normalized softmax + top2 (+aux accumulation)
  #pragma unroll 1
  for (int c = 0; c < 4; ++c) {
    int t = c * 1024 + tid;
    int b = t >> 10;
    float p[8];
    float4 l0 = *(const float4*)(logits + (size_t)t * 8);
    float4 l1 = *(const float4*)(logits + (size_t)t * 8 + 4);
    p[0] = l0.x / snrm[b * 8 + 0]; p[1] = l0.y / snrm[b * 8 + 1];
    p[2] = l0.z / snrm[b * 8 + 2]; p[3] = l0.w / snrm[b * 8 + 3];
    p[4] = l1.x / snrm[b * 8 + 4]; p[5] = l1.y / snrm[b * 8 + 5];
    p[6] = l1.z / snrm[b * 8 + 6]; p[7] = l1.w / snrm[b * 8 + 7];
    float mx = p[0];
    #pragma unroll
    for (int e = 1; e < 8; ++e) mx = fmaxf(mx, p[e]);
    float s = 0.f;
    #pragma unroll
    for (int e = 0; e < 8; ++e) { p[e] = expf(p[e] - mx); s += p[e]; }
    float invs = 1.f / s;
    #pragma unroll
    for (int e = 0; e < 8; ++e) { p[e] *= invs; asum[e] += p[e]; }
    int i1 = 0;
    #pragma unroll
    for (int e = 1; e < 8; ++e) if (p[e] > p[i1]) i1 = e;
    int i2 = (i1 == 0) ? 1 : 0;
    #pragma unroll
    for (int e = 0; e < 8; ++e) if (e != i1 && p[e] > p[i2]) i2 = e;
    wsel[t * 2] = p[i1]; wsel[t * 2 + 1] = p[i2];
    sisel[t * 2] = (unsigned char)i1; sisel[t * 2 + 1] = (unsigned char)i2;
  }
  // aux: this thread's s contributes sum_e (1/8 - mean_b p)^2
  float aloc = 0.f;
  #pragma unroll
  for (int e = 0; e < 8; ++e) {
    float d = 0.125f - asum[e] * 0.25f;
    aloc += d * d;
  }
  #pragma unroll
  for (int off = 32; off > 0; off >>= 1) aloc += __shfl_down(aloc, off, 64);
  if (lane == 0) auxred[wv] = aloc;
  __syncthreads();
  if (tid == 0) {
    float a = 0.f;
    #pragma unroll
    for (int k = 0; k < 16; ++k) a += auxred[k];
    *outAux = a;
  }
  // pass A: per (chunk, wave, expert) counts via ballots
  #pragma unroll 1
  for (int c = 0; c < 8; ++c) {
    int em = sisel[c * 1024 + tid];
    #pragma unroll
    for (int e = 0; e < 8; ++e) {
      unsigned long long mask = __ballot(em == e);
      if (lane == 0) cw[c][wv][e] = (int)__popcll(mask);
    }
  }
  __syncthreads();
  // exclusive scan per expert over (chunk, wave); totals -> soffs
  if (tid < 8) {
    int e = tid, run = 0;
    for (int c = 0; c < 8; ++c)
      for (int w2 = 0; w2 < 16; ++w2) { int v = cw[c][w2][e]; cw[c][w2][e] = run; run += v; }
    soffs[e] = run;
  }
  __syncthreads();
  if (tid == 0) {
    int a = 0;
    #pragma unroll
    for (int e = 0; e < 8; ++e) { int v = soffs[e]; soffs[e] = a; a += v; }
    soffs[8] = a;
  }
  __syncthreads();
  if (tid < 9) offs_g[tid] = soffs[tid];
  // pass B: deterministic ranks + emit compacted lists
  #pragma unroll 1
  for (int c = 0; c < 8; ++c) {
    int idx = c * 1024 + tid;
    int em = sisel[idx];
    int rk = 0;
    #pragma unroll
    for (int e = 0; e < 8; ++e) {
      unsigned long long mask = __ballot(em == e);
      if (em == e) rk = (int)__popcll(mask & ((1ull << lane) - 1ull));
    }
    int slot = soffs[em] + cw[c][wv][em] + rk;
    list[slot] = idx >> 1;
    inv[idx] = slot;
  }
}

// ---- transpose+cast W1/W3, 64x64 tiles, float4 loads + f16x4 stores ---------
__global__ __launch_bounds__(256) void k_tcast13(const float* __restrict__ W1,
    const float* __restrict__ W3, half_t* __restrict__ W1t, half_t* __restrict__ W3t)
{
  __shared__ float tile[64][68];
  int z = blockIdx.z;
  int sel = z >> 3, e = z & 7;
  const float* We = (sel ? W3 : W1) + (size_t)e * ND * NH;
  half_t* Wte = (sel ? W3t : W1t) + (size_t)e * ND * NH;
  int k0 = blockIdx.x * 64, n0 = blockIdx.y * 64;   // grid (8, 24, 16)
  int tid = threadIdx.x;
  int r = tid >> 4, c4 = tid & 15;
  #pragma unroll
  for (int p = 0; p < 4; ++p) {
    int row = r + p * 16;
    float4 v = *(const float4*)(We + (size_t)(k0 + row) * NH + n0 + c4 * 4);
    tile[row][c4 * 4 + 0] = v.x; tile[row][c4 * 4 + 1] = v.y;
    tile[row][c4 * 4 + 2] = v.z; tile[row][c4 * 4 + 3] = v.w;
  }
  __syncthreads();
  #pragma unroll
  for (int p = 0; p < 4; ++p) {
    int orow = r + p * 16;
    f16x4 h;
    #pragma unroll
    for (int i = 0; i < 4; ++i) h[i] = (half_t)tile[c4 * 4 + i][orow];
    *(f16x4*)(Wte + (size_t)(n0 + orow) * ND + k0 + c4 * 4) = h;
  }
}

// ---- transpose+cast W2[e][NH][ND] -> W2t[e][ND][NH], 64x64 vectorized -------
__global__ __launch_bounds__(256) void k_tcastW2(const float* __restrict__ W,
    half_t* __restrict__ Wt)
{
  __shared__ float tile[64][68];
  const float* We = W + (size_t)blockIdx.z * NH * ND;
  half_t* Wte = Wt + (size_t)blockIdx.z * NH * ND;
  int k0 = blockIdx.x * 64, n0 = blockIdx.y * 64;   // grid (24, 8, 8)
  int tid = threadIdx.x;
  int r = tid >> 4, c4 = tid & 15;
  #pragma unroll
  for (int p = 0; p < 4; ++p) {
    int row = r + p * 16;
    float4 v = *(const float4*)(We + (size_t)(k0 + row) * ND + n0 + c4 * 4);
    tile[row][c4 * 4 + 0] = v.x; tile[row][c4 * 4 + 1] = v.y;
    tile[row][c4 * 4 + 2] = v.z; tile[row][c4 * 4 + 3] = v.w;
  }
  __syncthreads();
  #pragma unroll
  for (int p = 0; p < 4; ++p) {
    int orow = r + p * 16;
    f16x4 h;
    #pragma unroll
    for (int i = 0; i < 4; ++i) h[i] = (half_t)tile[c4 * 4 + i][orow];
    *(f16x4*)(Wte + (size_t)(n0 + orow) * NH + k0 + c4 * 4) = h;
  }
}

// ============ fused FFN: gate = f16( sin(xm@W1^T) * (xm@W3^T) ) ==============
// 128x128 gload_lds pipeline (counted vmcnt(6) + setprio) + XCD-chunked swizzle.
__global__ __launch_bounds__(256, 3) void k_ffn_fused(const half_t* __restrict__ xmh,
    const half_t* __restrict__ W1t, const half_t* __restrict__ W3t,
    const int* __restrict__ list, const int* __restrict__ offs,
    half_t* __restrict__ gate)
{
  int bx = xcd_chunk(blockIdx.x, TM_MAX * 12);   // 852 = 71 tiles * 12 n
  int n0 = (bx % 12) * 128;
  int t  = bx / 12;
  int e, m0;
  if (!resolve_tile(offs, t, e, m0)) return;
  int base = offs[e], ne = offs[e + 1] - base;

  // LDS: A dbuf [0,16384) | B1 dbuf [16384,32768) | B3 dbuf [32768,49152) | rowt
  __shared__ __align__(16) char smem[49664];
  half_t* Sh = (half_t*)smem;
  int* rowt = (int*)(smem + 49152);
  int tid = threadIdx.x;
  if (tid < 128) {
    int rr = m0 + tid;
    rowt[tid] = (rr < ne) ? list[base + rr] : 0;
  }
  __syncthreads();

  int lane = tid & 63, w = tid >> 6;
  int wm = (w >> 1) * 64, wn = (w & 1) * 64;
  int qd = lane >> 4, md = lane & 15;
  int rA0 = tid >> 2;
  int sw = (((tid & 3) ^ ((tid >> 3) & 3)) << 3);   // swizzled k-chunk (halfs)
  int tok0 = rowt[rA0], tok1 = rowt[rA0 + 64];

  const half_t* gA0  = xmh + (size_t)tok0 * ND + sw;
  const half_t* gA1  = xmh + (size_t)tok1 * ND + sw;
  const half_t* gB10 = W1t + ((size_t)e * NH + n0 + rA0) * ND + sw;
  const half_t* gB11 = gB10 + (size_t)64 * ND;
  const half_t* gB30 = W3t + ((size_t)e * NH + n0 + rA0) * ND + sw;
  const half_t* gB31 = gB30 + (size_t)64 * ND;

  // wave-uniform LDS dests
  char* dA  = smem + w * 1024;
  char* dB1 = smem + 16384 + w * 1024;
  char* dB3 = smem + 32768 + w * 1024;

  f32x4 acc1[4][4], acc3[4][4];
  #pragma unroll
  for (int i = 0; i < 4; ++i)
    #pragma unroll
    for (int j = 0; j < 4; ++j)
      #pragma unroll
      for (int p = 0; p < 4; ++p) { acc1[i][j][p] = 0.f; acc3[i][j][p] = 0.f; }

  // swizzled ds_read offsets (halfs): phys chunk = qd ^ ((row>>1)&3)
  int swq  = ((qd ^ ((md >> 1) & 3)) << 3);
  int aoff = (wm + md) * 32 + swq;
  int boff = (wn + md) * 32 + swq;

#define FFN_STAGE(p, kk) do { int kb_ = (kk); int pb_ = (p) * 8192;          \
    gld16(gA0  + kb_, dA  + pb_); gld16(gA1  + kb_, dA  + pb_ + 4096);       \
    gld16(gB10 + kb_, dB1 + pb_); gld16(gB11 + kb_, dB1 + pb_ + 4096);       \
    gld16(gB30 + kb_, dB3 + pb_); gld16(gB31 + kb_, dB3 + pb_ + 4096); } while (0)

  FFN_STAGE(0, 0);
  int cur = 0;
  #pragma unroll 1
  for (int it = 0; it < 16; ++it) {
    if (it + 1 < 16) {
      FFN_STAGE(cur ^ 1, (it + 1) * 32);
      asm volatile("s_waitcnt vmcnt(6)\ns_barrier" ::: "memory");
    } else {
      asm volatile("s_waitcnt vmcnt(0)\ns_barrier" ::: "memory");
    }
    const half_t* As  = Sh + cur * 4096;
    const half_t* B1s = Sh + 8192  + cur * 4096;
    const half_t* B3s = Sh + 16384 + cur * 4096;
    f16x8 a[4];
    #pragma unroll
    for (int i = 0; i < 4; ++i) a[i] = *(const f16x8*)(As + aoff + i * 512);
    __builtin_amdgcn_s_setprio(1);
    #pragma unroll
    for (int j = 0; j < 4; ++j) {
      f16x8 b1 = *(const f16x8*)(B1s + boff + j * 512);
      f16x8 b3 = *(const f16x8*)(B3s + boff + j * 512);
      #pragma unroll
      for (int i = 0; i < 4; ++i) {
        acc1[i][j] = __builtin_amdgcn_mfma_f32_16x16x32_f16(a[i], b1, acc1[i][j], 0, 0, 0);
        acc3[i][j] = __builtin_amdgcn_mfma_f32_16x16x32_f16(a[i], b3, acc3[i][j], 0, 0, 0);
      }
    }
    __builtin_amdgcn_s_setprio(0);
    asm volatile("s_barrier" ::: "memory");
    cur ^= 1;
  }
#undef FFN_STAGE

  // epilogue: gate = f16(sin(h1) * h3) via LDS re-tile, vectorized store
  half_t* Cs = (half_t*)smem;
  #pragma unroll
  for (int i = 0; i < 4; ++i)
    #pragma unroll
    for (int j = 0; j < 4; ++j)
      #pragma unroll
      for (int p = 0; p < 4; ++p) {
        int rr = wm + 16 * i + qd * 4 + p;
        int cc = wn + 16 * j + md;
        Cs[rr * LDC + cc] = (half_t)(__sinf(acc1[i][j][p]) * acc3[i][j][p]);
      }
  __syncthreads();
  #pragma unroll
  for (int it = 0; it < 8; ++it) {
    int chunk = it * 256 + tid;
    int rr = chunk >> 4, c8 = (chunk & 15) * 8;
    if (m0 + rr < ne) {
      *(f16x8*)(gate + (size_t)(base + m0 + rr) * NH + n0 + c8) = *(const f16x8*)(Cs + rr * LDC + c8);
    }
  }
}

// ======= MoE stage 2 (atomic-free): P[slot][d] = gate[slot,:] @ W2_e^T =======
__global__ __launch_bounds__(256, 4) void k_moe2_mfma(const half_t* __restrict__ gate,
    const half_t* __restrict__ W2t, const int* __restrict__ offs,
    float* __restrict__ P)
{
  int bx = xcd_chunk(blockIdx.x, TM_MAX * 4);    // 284 = 71 tiles * 4 n
  int n0 = (bx & 3) * 128;
  int t = bx >> 2;
  int e, m0;
  if (!resolve_tile(offs, t, e, m0)) return;
  int base = offs[e], ne = offs[e + 1] - base;

  // LDS: A dbuf [0,16384) | B dbuf [16384,32768)
  __shared__ __align__(16) char smem[32768];
  half_t* Sh = (half_t*)smem;
  int tid = threadIdx.x;
  int lane = tid & 63, w = tid >> 6;
  int wm = (w >> 1) * 64, wn = (w & 1) * 64;
  int qd = lane >> 4, md = lane & 15;
  int rA0 = tid >> 2;
  int sw = (((tid & 3) ^ ((tid >> 3) & 3)) << 3);

  int ar0 = m0 + rA0;      if (ar0 >= ne) ar0 = ne - 1;
  int ar1 = m0 + rA0 + 64; if (ar1 >= ne) ar1 = ne - 1;
  const half_t* gA0 = gate + (size_t)(base + ar0) * NH + sw;
  const half_t* gA1 = gate + (size_t)(base + ar1) * NH + sw;
  const half_t* gB0 = W2t + ((size_t)e * ND + n0 + rA0) * NH + sw;
  const half_t* gB1 = gB0 + (size_t)64 * NH;

  char* dA = smem + w * 1024;
  char* dB = smem + 16384 + w * 1024;

  f32x4 acc[4][4];
  #pragma unroll
  for (int i = 0; i < 4; ++i)
    #pragma unroll
    for (int j = 0; j < 4; ++j)
      #pragma unroll
      for (int p = 0; p < 4; ++p) acc[i][j][p] = 0.f;

  int swq  = ((qd ^ ((md >> 1) & 3)) << 3);
  int aoff = (wm + md) * 32 + swq;
  int boff = (wn + md) * 32 + swq;

#define MOE2_STAGE(p, kk) do { int kb_ = (kk); int pb_ = (p) * 8192;         \
    gld16(gA0 + kb_, dA + pb_); gld16(gA1 + kb_, dA + pb_ + 4096);           \
    gld16(gB0 + kb_, dB + pb_); gld16(gB1 + kb_, dB + pb_ + 4096); } while (0)

  MOE2_STAGE(0, 0);
  int cur = 0;
  #pragma unroll 1
  for (int it = 0; it < 48; ++it) {
    if (it + 1 < 48) {
      MOE2_STAGE(cur ^ 1, (it + 1) * 32);
      asm volatile("s_waitcnt vmcnt(4)\ns_barrier" ::: "memory");
    } else {
      asm volatile("s_waitcnt vmcnt(0)\ns_barrier" ::: "memory");
    }
    const half_t* As = Sh + cur * 4096;
    const half_t* Bs = Sh + 8192 + cur * 4096;
    f16x8 a[4], b[4];
    #pragma unroll
    for (int i = 0; i < 4; ++i) a[i] = *(const f16x8*)(As + aoff + i * 512);
    #pragma unroll
    for (int j = 0; j < 4; ++j) b[j] = *(const f16x8*)(Bs + boff + j * 512);
    __builtin_amdgcn_s_setprio(1);
    #pragma unroll
    for (int j = 0; j < 4; ++j)
      #pragma unroll
      for (int i = 0; i < 4; ++i)
        acc[i][j] = __builtin_amdgcn_mfma_f32_16x16x32_f16(a[i], b[j], acc[i][j], 0, 0, 0);
    __builtin_amdgcn_s_setprio(0);
    asm volatile("s_barrier" ::: "memory");
    cur ^= 1;
  }
#undef MOE2_STAGE

  #pragma unroll
  for (int i = 0; i < 4; ++i)
    #pragma unroll
    for (int p = 0; p < 4; ++p) {
      int gr = m0 + wm + 16 * i + qd * 4 + p;
      if (gr < ne) {
        float* pp = P + (size_t)(base + gr) * ND + n0 + wn + md;
        #pragma unroll
        for (int j = 0; j < 4; ++j)
          pp[16 * j] = acc[i][j][p];
      }
    }
}

// ---- reduce: out[t][:] = w1 * P[slot1][:] + w2 * P[slot2][:] ----------------
__global__ __launch_bounds__(256) void k_moe_reduce(const float* __restrict__ P,
    const int* __restrict__ inv, const float* __restrict__ wsel,
    float* __restrict__ out)
{
  int i = blockIdx.x * 256 + threadIdx.x;   // 4096 * 128 float4s
  int t = i >> 7, d4 = i & 127;
  int s1 = inv[t * 2], s2 = inv[t * 2 + 1];
  float w1 = wsel[t * 2], w2 = wsel[t * 2 + 1];
  const float4* P4 = (const float4*)P;
  float4 a = P4[(size_t)s1 * 128 + d4];
  float4 b = P4[(size_t)s2 * 128 + d4];
  float4 o;
  o.x = w1 * a.x + w2 * b.x;
  o.y = w1 * a.y + w2 * b.y;
  o.z = w1 * a.z + w2 * b.z;
  o.w = w1 * a.w + w2 * b.w;
  ((float4*)out)[i] = o;
}

// ---------------- workspace layout (byte offsets, peak ~63.4 MB) -------------
static const size_t BO_MODS  = 0;          // 49152 B fp32 mods
static const size_t BO_HH    = 65536;      // Hh 4 MB   } region B (8 MB)
static const size_t BO_HL2   = 4259840;    // Hl 4 MB   }
static const size_t BO_PH    = 4259840;    // Ph 2 MB (after Hl dead)
static const size_t BO_PL    = 6357056;    // Pl 2 MB
static const size_t BO_WALLH = 8454144;    // 2 MB: q|k|v|o transposed h (2048 rows)
static const size_t BO_WALLL = 10551296;   // 2 MB: l planes
static const size_t BO_QKV   = 12648448;   // fp32 [4096][1536] 25.17 MB (region D)
static const size_t BO_A0H   = 12648448;   // attn0 h 4 MB (after QKV dead)
static const size_t BO_A0L   = 16842752;   // attn0 l 4 MB
static const size_t BO_SC4   = 21037056;   // 16 MB fp32: 16 x [512][512] split-K partials
static const size_t BO_X2    = 21037056;   // fp32 8 MB (after SC4 dead)
static const size_t BO_XM    = 29425664;   // (dead: fp32 xm no longer written)
static const size_t BO_QTH   = 37814272;   // qT h 4 MB } region E (16 MB)
static const size_t BO_QTL   = 42008576;
static const size_t BO_KTH   = 46202880;
static const size_t BO_KTL   = 50397184;
static const size_t BO_VH    = 54591488;   // region F (8 MB)
static const size_t BO_VL    = 58785792;
// MoE phase (aliases):
static const size_t BO_W1T   = 37814272;   // 12.58 MB (qT/kT dead after scores)
static const size_t BO_XMH   = 50397184;   // 4 MB (kT_l dead)
static const size_t BO_W3T   = 65536;      // 12.58 MB = region B+C (dead after apply/Wo)
static const size_t BO_GATE  = 12648448;   // 25.17 MB = region D
static const size_t BO_W2T   = 65536;      // 12.58 MB (overwrites W3T after ffn)
static const size_t BO_P     = 37814272;   // 16.78 MB fp32 (W1T+XMH dead after ffn)
// small buffers:
static const size_t BO_LOGI  = 62980096;
static const size_t BO_NRM   = 63111168;
static const size_t BO_WSEL  = 63242368;
static const size_t BO_INTS  = 63307904;   // ints: isel 8192|cnt 8|cnt2 8|offs 16|list 8192|inv 8192

extern "C" void kernel_launch(void* const* d_in, const int* in_sizes, int n_in,
                              void* d_out, int out_size, void* d_ws, size_t ws_size,
                              hipStream_t stream)
{
  const float* x    = (const float*)d_in[0];
  const float* c    = (const float*)d_in[1];
  const float* Wada = (const float*)d_in[2];
  const float* bada = (const float*)d_in[3];
  const float* Wq   = (const float*)d_in[4];
  const float* Wk   = (const float*)d_in[5];
  const float* Wv   = (const float*)d_in[6];
  const float* Wo   = (const float*)d_in[7];
  const float* qn_w = (const float*)d_in[8];
  const float* qn_b = (const float*)d_in[9];
  const float* kn_w = (const float*)d_in[10];
  const float* kn_b = (const float*)d_in[11];
  const float* an_w = (const float*)d_in[12];
  const float* an_b = (const float*)d_in[13];
  const float* fn_w = (const float*)d_in[14];
  const float* fn_b = (const float*)d_in[15];
  const float* Wr   = (const float*)d_in[16];
  const float* br   = (const float*)d_in[17];
  const float* W1   = (const float*)d_in[18];
  const float* W2   = (const float*)d_in[19];
  const float* W3   = (const float*)d_in[20];
  float* out = (float*)d_out;
  char*  ws8 = (char*)d_ws;
  float* MODS = (float*)(ws8 + BO_MODS);
  half_t* Hh = (half_t*)(ws8 + BO_HH),   *Hl = (half_t*)(ws8 + BO_HL2);
  half_t* Ph = (half_t*)(ws8 + BO_PH),   *Pl = (half_t*)(ws8 + BO_PL);
  half_t* WALLH = (half_t*)(ws8 + BO_WALLH), *WALLL = (half_t*)(ws8 + BO_WALLL);
  half_t* WoTh = WALLH + (size_t)1536 * ND,  *WoTl = WALLL + (size_t)1536 * ND;
  float* QKV = (float*)(ws8 + BO_QKV);
  half_t* A0h = (half_t*)(ws8 + BO_A0H), *A0l = (half_t*)(ws8 + BO_A0L);
  float* SC4 = (float*)(ws8 + BO_SC4);
  float* X2  = (float*)(ws8 + BO_X2);
  half_t* qTh = (half_t*)(ws8 + BO_QTH), *qTl = (half_t*)(ws8 + BO_QTL);
  half_t* kTh = (half_t*)(ws8 + BO_KTH), *kTl = (half_t*)(ws8 + BO_KTL);
  half_t* Vh  = (half_t*)(ws8 + BO_VH),  *Vl  = (half_t*)(ws8 + BO_VL);
  half_t* W1T = (half_t*)(ws8 + BO_W1T);
  half_t* W3T = (half_t*)(ws8 + BO_W3T);
  half_t* W2T = (half_t*)(ws8 + BO_W2T);
  half_t* XMH = (half_t*)(ws8 + BO_XMH);
  half_t* GATEH = (half_t*)(ws8 + BO_GATE);
  float* PBUF = (float*)(ws8 + BO_P);
  float* LOGI = (float*)(ws8 + BO_LOGI);
  float* NRM  = (float*)(ws8 + BO_NRM);
  float* WSEL = (float*)(ws8 + BO_WSEL);
  int* ib   = (int*)(ws8 + BO_INTS);
  int* offs = ib + 8208;
  int* list = ib + 8224;
  int* inv  = ib + 16416;

  k_ada<<<384, 256, 0, stream>>>(c, Wada, bada, MODS);
  k_wsplit4<<<dim3(16, 16, 4), 256, 0, stream>>>(Wq, Wk, Wv, Wo, WALLH, WALLL);
  // h = modulate(LN(x)) -> h/l planes
  k_lnmod<<<NT, 256, 0, stream>>>(x, ND, nullptr, Hh, Hl, ND, an_w, an_b, MODS, 0, 512,
                                  nullptr, nullptr, nullptr);
  // fused QKV: [4096][1536]; v columns written directly as Vh/Vl (MODE 3)
  k_gemm_hl<3><<<dim3(32, 12, 1), 256, 0, stream>>>(Hh, Hl, 0, WALLH, WALLL, 0,
      ND, ND, ND, QKV, nullptr, nullptr, 0, 1536, nullptr, nullptr, Vh, Vl);
  // fused LN + transpose + split of q,k halves (replaces k_lnqk + k_tsplit2)
  k_lnt<<<dim3(128, 2), 256, 0, stream>>>(QKV, qn_w, qn_b, kn_w, kn_b, qTh, qTl);
  // scores: split-K x4 (z = b*4+kh; A/B offset z*256 = b*1024+kh*256)
  k_gemm_hl<0><<<dim3(4, 4, 16), 256, 0, stream>>>(qTh, qTl, 256, kTh, kTl, 256,
      NT, NT, 256, SC4, nullptr, nullptr, 262144, ND, nullptr, nullptr, nullptr, nullptr);
  k_softmax512_sum4<<<2048, 256, 0, stream>>>(SC4, Ph, Pl);
  // apply: attn0[s][d] = sum_e v[s,e] P[d,e]
  k_gemm_hl<1><<<dim3(8, 4, 4), 256, 0, stream>>>(Vh, Vl, 524288, Ph, Pl, 262144,
      ND, ND, ND, nullptr, A0h, A0l, 524288, ND, nullptr, nullptr, nullptr, nullptr);
  // Wo + residual: X2 = x + g_msa * (attn0 @ Wo)
  k_gemm_hl<2><<<dim3(32, 4, 1), 256, 0, stream>>>(A0h, A0l, 0, WoTh, WoTl, 0,
      ND, ND, ND, X2, nullptr, nullptr, 0, ND, x, MODS, nullptr, nullptr);
  // xm = modulate(LN(X2)) -> fp16 (ffn) only; fused router logits (XM dead)
  k_lnmod<<<NT, 256, 0, stream>>>(X2, ND, nullptr, XMH, nullptr, ND, fn_w, fn_b, MODS, 1536, 2048,
                                  Wr, br, LOGI);
  // routing: colnorm -> fused atomic-free route (top2+scan+fill+aux)
  k_colnorm<<<32, 256, 0, stream>>>(LOGI, NRM);
  k_route<<<1, 1024, 0, stream>>>(LOGI, NRM, WSEL, offs, list, inv,
                                  out + (size_t)NT * ND);
  // MoE: exact-tiled gload_lds pipelines, atomic-free down-proj, combine
  k_tcast13<<<dim3(8, 24, 16), 256, 0, stream>>>(W1, W3, W1T, W3T);
  k_ffn_fused<<<TM_MAX * 12, 256, 0, stream>>>(XMH, W1T, W3T, list, offs, GATEH);
  k_tcastW2<<<dim3(24, 8, 8), 256, 0, stream>>>(W2, W2T);  // W3T dead now
  k_moe2_mfma<<<TM_MAX * 4, 256, 0, stream>>>(GATEH, W2T, offs, PBUF);
  k_moe_reduce<<<2048, 256, 0, stream>>>(PBUF, inv, WSEL, out);
}